// Round 2
// baseline (548.099 us; speedup 1.0000x reference)
//
#include <hip/hip_runtime.h>

typedef unsigned short u16;
typedef __attribute__((ext_vector_type(8))) short short8;
typedef __attribute__((ext_vector_type(4))) float floatx4;

#define MTOT    16384          // 4 * 64 * 64
#define PADIMG  (66 * 66)      // padded image pixels per batch
#define PADELEM (4 * PADIMG * 256)
#define PADB    ((size_t)PADELEM * 2)   // bytes, bf16 (multiple of 256 -> allocs contiguous)
#define WSTEP   (256 * 2304)

__device__ __forceinline__ float bf2f(u16 u) {
  union { unsigned int i; float f; } c; c.i = ((unsigned int)u) << 16; return c.f;
}
__device__ __forceinline__ u16 f2bf(float f) {
  union { float f; unsigned int i; } c; c.f = f;
  unsigned int r = c.i + 0x7FFFu + ((c.i >> 16) & 1u);
  return (u16)(r >> 16);
}

__device__ __forceinline__ void gl_lds16(const void* g, void* l) {
  __builtin_amdgcn_global_load_lds(
      (const __attribute__((address_space(1))) void*)g,
      (__attribute__((address_space(3))) void*)l, 16, 0, 0);
}

// BK=32 LDS slot (u16 units): 4 chunks/row, XOR with (row>>1)&3  [R4: 0 conflicts]
__device__ __forceinline__ int lds_slot32(int row, int q) {
  return row * 32 + ((q ^ ((row >> 1) & 3)) << 3);
}
// BK=64 LDS slot: 8 chunks/row, XOR with row&7  [R5: 0 conflicts]
__device__ __forceinline__ int lds_slot64(int row, int q) {
  return row * 64 + ((q ^ (row & 7)) << 3);
}

// ---------------------------------------------------------------------------
// merged setup kernel (all regions disjoint):
//   blk < 20736          : pack conv3x3 weights -> flat [w][o][(ky*3+kx)*256+c]
//   blk < 21120          : pack 1x1 weights -> [128 zero-pad][256] x3
//   blk < 22144 (1024)   : features NCHW fp32 -> bf16 padded NHWC interior
//   blk < 23444 (1300)   : zero halo rings of the 5 padded buffers
__global__ void setup_all(const float* __restrict__ cls_w, const float* __restrict__ reg_w,
                          const float* __restrict__ initw, const float* __restrict__ clsd,
                          const float* __restrict__ refd,
                          const float* __restrict__ iw, const float* __restrict__ cw,
                          const float* __restrict__ rw,
                          const float* __restrict__ features,
                          u16* __restrict__ dst3, u16* __restrict__ dst1,
                          u16* __restrict__ pads) {
  int blk = blockIdx.x;
  int t = threadIdx.x;
  if (blk < 20736) {
    int w = blk / 2304;
    const float* src = (w < 3) ? cls_w + (size_t)w * WSTEP
                     : (w < 6) ? reg_w + (size_t)(w - 3) * WSTEP
                     : (w == 6) ? initw : (w == 7) ? clsd : refd;
    int idx = (blk - w * 2304) * 256 + t;
    int o = idx / 2304, r = idx - o * 2304;
    int kk = r >> 8, c = r & 255;
    dst3[(size_t)w * WSTEP + idx] = f2bf(src[(o * 256 + c) * 9 + kk]);
  } else if (blk < 21120) {
    int bb = blk - 20736;                     // 0..383
    int wsel = bb >> 7;
    const float* src = wsel == 0 ? iw : wsel == 1 ? cw : rw;
    int nvalid = wsel == 1 ? 80 : 18;
    int idx = (bb & 127) * 256 + t;
    int o = idx >> 8, c = idx & 255;
    dst1[(size_t)wsel * 32768 + idx] = f2bf(o < nvalid ? src[o * 256 + c] : 0.f);
  } else if (blk < 22144) {
    __shared__ float tile[64][65];
    int bb = blk - 21120;                     // 0..1023
    int c0 = (bb & 3) * 64;
    int y  = (bb >> 2) & 63;
    int b  = bb >> 8;
    #pragma unroll
    for (int i = 0; i < 16; ++i) {
      int lin = t + i * 256; int c = lin >> 6, x = lin & 63;
      tile[c][x] = features[((b * 256 + c0 + c) * 64 + y) * 64 + x];
    }
    __syncthreads();
    #pragma unroll
    for (int i = 0; i < 16; ++i) {
      int lin = t + i * 256; int x = lin >> 6, c = lin & 63;
      pads[((b * 66 + y + 1) * 66 + (x + 1)) * 256 + c0 + c] = f2bf(tile[c][x]);
    }
  } else {
    int idx = (blk - 22144) * 256 + t;        // 0..332799 = 5*4*260*64
    int c4 = (idx & 63) << 2;
    int r = idx >> 6;
    int pix = r % 260;
    int ib = r / 260;                         // buf*4 + batch, 0..19
    int y, x;
    if (pix < 66)       { y = 0;  x = pix; }
    else if (pix < 132) { y = 65; x = pix - 66; }
    else if (pix < 196) { y = pix - 132 + 1; x = 0; }
    else                { y = pix - 196 + 1; x = 65; }
    size_t o = (((size_t)ib * PADIMG) + y * 66 + x) * 256 + c4;
    *(ushort4*)(pads + o) = (ushort4){0, 0, 0, 0};
  }
}

// ---------------------------------------------------------------------------
// paired GroupNorm apply: bf16 staging [2][M][256] + raw (s,s2) stats ->
// normalize+affine+relu -> padded bf16 NHWC per tower. grid 8192 x 256.
__global__ void __launch_bounds__(256)
gn_apply2(const u16* __restrict__ stage, const float2* __restrict__ st,
          const float* __restrict__ gwc, const float* __restrict__ gbc,
          const float* __restrict__ gwr, const float* __restrict__ gbr,
          u16* __restrict__ cdst, u16* __restrict__ rdst) {
  int tid = blockIdx.x * 256 + threadIdx.x;
  int tower = tid >> 20;
  int r = tid & 0xFFFFF;
  int m = r >> 6, c4 = (r & 63) << 2;
  ushort4 u = *(const ushort4*)(stage + ((size_t)tower << 22) + (size_t)m * 256 + c4);
  int b = m >> 12, p = m & 4095, y = p >> 6, x = p & 63;
  float2 ss = st[tower * 128 + b * 32 + (c4 >> 3)];
  float mu = ss.x * (1.f / 32768.f);
  float var = ss.y * (1.f / 32768.f) - mu * mu;
  float rinv = rsqrtf(var + 1e-5f);
  const float* gw = tower ? gwr : gwc;
  const float* gb = tower ? gbr : gbc;
  ushort4 o;
  o.x = f2bf(fmaxf((bf2f(u.x) - mu) * rinv * gw[c4 + 0] + gb[c4 + 0], 0.f));
  o.y = f2bf(fmaxf((bf2f(u.y) - mu) * rinv * gw[c4 + 1] + gb[c4 + 1], 0.f));
  o.z = f2bf(fmaxf((bf2f(u.z) - mu) * rinv * gw[c4 + 2] + gb[c4 + 2], 0.f));
  o.w = f2bf(fmaxf((bf2f(u.w) - mu) * rinv * gw[c4 + 3] + gb[c4 + 3], 0.f));
  u16* dst = tower ? rdst : cdst;
  *(ushort4*)(dst + ((size_t)((b * 66 + y + 1) * 66 + (x + 1)) * 256 + c4)) = o;
}

// ---------------------------------------------------------------------------
// bilinear sample, both towers. 16 lanes/pixel, 16 ch/lane (chunk c covers
// ch c*64 + l*4 -> every ld/st is 128 B contiguous per pixel-group).
// grid 2048: blk<1024 -> (featC,AC), else (featR,AR); 16 m per block.
__global__ void __launch_bounds__(256)
dcn_sample2(const u16* __restrict__ featC, const u16* __restrict__ featR,
            const float* __restrict__ pts,
            u16* __restrict__ AC, u16* __restrict__ AR) {
  int blk = blockIdx.x;
  const u16* featpad = blk < 1024 ? featC : featR;
  u16* A = blk < 1024 ? AC : AR;
  int mblk = blk & 1023;
  int t = threadIdx.x;
  int m = mblk * 16 + (t >> 4);
  int l = t & 15;
  int b = m >> 12, p = m & 4095, y = p >> 6, x = p & 63;
  const float* pp = pts + (size_t)m * 18;
  const u16* fb = featpad + (size_t)b * PADIMG * 256 + l * 4;
  u16* am = A + (size_t)m * 2304 + l * 4;
  #pragma unroll
  for (int kk = 0; kk < 9; ++kk) {
    float py = (float)y + pp[2 * kk];
    float px = (float)x + pp[2 * kk + 1];
    float fy = floorf(py), fx = floorf(px);
    int y0 = (int)fy, x0 = (int)fx;
    float wy = py - fy, wx = px - fx;
    float w00 = (1.f - wy) * (1.f - wx), w01 = (1.f - wy) * wx;
    float w10 = wy * (1.f - wx), w11 = wy * wx;
    bool yok0 = (unsigned)y0 < 64u, yok1 = (unsigned)(y0 + 1) < 64u;
    bool xok0 = (unsigned)x0 < 64u, xok1 = (unsigned)(x0 + 1) < 64u;
    const u16* base = fb + ((y0 + 1) * 66 + (x0 + 1)) * 256;
    float r[16];
    #pragma unroll
    for (int i = 0; i < 16; ++i) r[i] = 0.f;
    if (yok0 & xok0) {
      #pragma unroll
      for (int c = 0; c < 4; ++c) { ushort4 v = *(const ushort4*)(base + c * 64);
        r[c*4+0] += w00 * bf2f(v.x); r[c*4+1] += w00 * bf2f(v.y);
        r[c*4+2] += w00 * bf2f(v.z); r[c*4+3] += w00 * bf2f(v.w); } }
    if (yok0 & xok1) {
      #pragma unroll
      for (int c = 0; c < 4; ++c) { ushort4 v = *(const ushort4*)(base + 256 + c * 64);
        r[c*4+0] += w01 * bf2f(v.x); r[c*4+1] += w01 * bf2f(v.y);
        r[c*4+2] += w01 * bf2f(v.z); r[c*4+3] += w01 * bf2f(v.w); } }
    if (yok1 & xok0) {
      #pragma unroll
      for (int c = 0; c < 4; ++c) { ushort4 v = *(const ushort4*)(base + 66 * 256 + c * 64);
        r[c*4+0] += w10 * bf2f(v.x); r[c*4+1] += w10 * bf2f(v.y);
        r[c*4+2] += w10 * bf2f(v.z); r[c*4+3] += w10 * bf2f(v.w); } }
    if (yok1 & xok1) {
      #pragma unroll
      for (int c = 0; c < 4; ++c) { ushort4 v = *(const ushort4*)(base + 67 * 256 + c * 64);
        r[c*4+0] += w11 * bf2f(v.x); r[c*4+1] += w11 * bf2f(v.y);
        r[c*4+2] += w11 * bf2f(v.z); r[c*4+3] += w11 * bf2f(v.w); } }
    #pragma unroll
    for (int c = 0; c < 4; ++c) {
      ushort4 o;
      o.x = f2bf(r[c*4+0]); o.y = f2bf(r[c*4+1]);
      o.z = f2bf(r[c*4+2]); o.w = f2bf(r[c*4+3]);
      *(ushort4*)(am + kk * 256 + c * 64) = o;
    }
  }
}

// ---------------------------------------------------------------------------
// GEMM: C[M,N] = A[M,K] * W[N,K]^T.  128xBN tile, BK in {32,64}, 4 waves.
// [R6-verified source; R8: 2-phase double-buffered prefetch]
// Block decode: [NPAIR==2: pair=blk&1, blk>>=1]  bm=blk&127, bn=blk>>7.
// AMODE 0: flat A; AMODE 1: implicit conv3x3.
// K-loop structure (T3 minimum 2-phase): stage(s+1,buf^1) issued BEFORE
// compute(buf); single __syncthreads per K-step (its vmcnt(0) drain lands
// after ds_read+MFMA covered the load latency, and doubles as the
// read-done fence for buffer reuse). Unrolled x2 so buffer indices are
// compile-time constants.
// EP 0: bf16 staging + GN (s,s2) atomics; EP 1: +bias,relu; EP 2: relu;
// EP 3: +bias (+addpts) (+ptsout) -> fp32 NCHW d_out slice at cb, gn < nv.
template <int AMODE, int EP, int KSZ, int BN, int BK, int NPAIR>
__global__ void __launch_bounds__(256)
gemm_kernel(const u16* __restrict__ A0, const u16* __restrict__ A1,
            const u16* __restrict__ W0, const u16* __restrict__ W1,
            const float* __restrict__ bias0, const float* __restrict__ bias1,
            u16* __restrict__ outb0, u16* __restrict__ outb1,
            float2* __restrict__ st0, float2* __restrict__ st1,
            float* __restrict__ outf,
            const float* __restrict__ addpts0, const float* __restrict__ addpts1,
            float* __restrict__ ptsout0, float* __restrict__ ptsout1,
            int nv0, int nv1, int cb0, int cb1) {
  constexpr int NJ = BN / 32;                 // 16-col accum tiles per wave
  constexpr int ASZ = 128 * BK;               // u16 elements per A buffer
  constexpr int BSZ = BN * BK;
  __shared__ u16 As[2 * ASZ];
  __shared__ u16 Bs[2 * BSZ];
  int t = threadIdx.x;
  int blk = blockIdx.x;
  int pair = 0;
  if constexpr (NPAIR == 2) { pair = blk & 1; blk >>= 1; }
  const u16* A        = pair ? A1 : A0;
  const u16* Wp       = pair ? W1 : W0;
  const float* bias   = pair ? bias1 : bias0;
  u16* outb           = pair ? outb1 : outb0;
  float2* st          = pair ? st1 : st0;
  const float* addpts = pair ? addpts1 : addpts0;
  float* ptsout       = pair ? ptsout1 : ptsout0;
  int nv = pair ? nv1 : nv0;
  int cb = pair ? cb1 : cb0;

  int bm = blk & 127, bn = blk >> 7;
  int lane = t & 63, wave = t >> 6;
  int wm = (wave & 1) << 6;
  int wn = (wave >> 1) * (BN / 2);
  int quad = lane >> 4, r16 = lane & 15;

  floatx4 acc[4][NJ];
  #pragma unroll
  for (int i = 0; i < 4; ++i)
    #pragma unroll
    for (int j = 0; j < NJ; ++j)
      acc[i][j] = (floatx4){0.f, 0.f, 0.f, 0.f};

  if constexpr (BK == 64) {
    // staging: 8 chunks/row; thread t covers (row = 32k + t>>3, slot = t&7)
    int sub = t >> 3;                 // 0..31
    int cq = (t & 7) ^ (sub & 7);     // XOR-swizzled global chunk for this slot
    int abase[4];
    #pragma unroll
    for (int k = 0; k < 4; ++k) {
      int m = bm * 128 + k * 32 + sub;
      if constexpr (AMODE == 1) {
        int b = m >> 12, p = m & 4095;
        abase[k] = ((b * 66 + (p >> 6)) * 66 + (p & 63)) * 256 + cq * 8;
      } else {
        abase[k] = m * KSZ + cq * 8;
      }
    }
    const u16* wg = Wp + (size_t)(bn * BN + sub) * KSZ + cq * 8;
    constexpr int NS = KSZ / 64;      // 36 (conv) or 4 — even in all uses

    auto stage = [&](int s, int bsel) {
      int d;
      if constexpr (AMODE == 1) {
        int kk = s >> 2;                 // 0..8
        int c0 = (s & 3) << 6;           // 0..192
        int ky = kk / 3, kx = kk - ky * 3;
        d = ((ky * 66 + kx) << 8) + c0;
      } else {
        d = s * 64;
      }
      u16* ad = &As[bsel * ASZ + t * 8];
      u16* bd = &Bs[bsel * BSZ + t * 8];
      #pragma unroll
      for (int k = 0; k < 4; ++k)
        gl_lds16(A + abase[k] + d, ad + k * 2048);
      #pragma unroll
      for (int k = 0; k < BN / 32; ++k)
        gl_lds16(wg + (size_t)(k * 32) * KSZ + s * 64, bd + k * 2048);
    };

    auto compute = [&](int bsel) {
      const u16* Ac = &As[bsel * ASZ];
      const u16* Bc = &Bs[bsel * BSZ];
      short8 af[2][4], bfr[2][NJ];
      #pragma unroll
      for (int ks = 0; ks < 2; ++ks) {
        #pragma unroll
        for (int i = 0; i < 4; ++i)
          af[ks][i] = *(const short8*)&Ac[lds_slot64(wm + i * 16 + r16, ks * 4 + quad)];
        #pragma unroll
        for (int j = 0; j < NJ; ++j)
          bfr[ks][j] = *(const short8*)&Bc[lds_slot64(wn + j * 16 + r16, ks * 4 + quad)];
      }
      #pragma unroll
      for (int ks = 0; ks < 2; ++ks)
        #pragma unroll
        for (int i = 0; i < 4; ++i)
          #pragma unroll
          for (int j = 0; j < NJ; ++j)
            acc[i][j] = __builtin_amdgcn_mfma_f32_16x16x32_bf16(af[ks][i], bfr[ks][j], acc[i][j], 0, 0, 0);
    };

    stage(0, 0);
    __syncthreads();
    for (int s = 0; s < NS; s += 2) {
      stage(s + 1, 1);                 // NS even -> s+1 always valid
      compute(0);
      __syncthreads();
      if (s + 2 < NS) stage(s + 2, 0);
      compute(1);
      __syncthreads();
    }
  } else {
    // BK=32 path (R4-verified layout + 2-phase prefetch): 4 chunks/row
    int row = t >> 2;
    int chunkS = (t & 3) ^ ((t >> 3) & 3);
    int m0 = bm * 128 + row, m1 = m0 + 64;
    int abase0, abase1;
    if constexpr (AMODE == 1) {
      int b0 = m0 >> 12, p0 = m0 & 4095;
      int b1 = m1 >> 12, p1 = m1 & 4095;
      abase0 = ((b0 * 66 + (p0 >> 6)) * 66 + (p0 & 63)) * 256 + chunkS * 8;
      abase1 = ((b1 * 66 + (p1 >> 6)) * 66 + (p1 & 63)) * 256 + chunkS * 8;
    } else {
      abase0 = m0 * KSZ + chunkS * 8;
      abase1 = m1 * KSZ + chunkS * 8;
    }
    const u16* wg = Wp + (size_t)(bn * BN + row) * KSZ + chunkS * 8;
    constexpr int NS = KSZ / 32;      // 8 for heads — even

    auto stage = [&](int s, int bsel) {
      int d;
      if constexpr (AMODE == 1) {
        int kk = s >> 3;
        int c0 = (s & 7) << 5;
        int ky = kk / 3, kx = kk - ky * 3;
        d = ((ky * 66 + kx) << 8) + c0;
      } else {
        d = s * 32;
      }
      gl_lds16(A + abase0 + d, &As[bsel * ASZ + t * 8]);
      gl_lds16(A + abase1 + d, &As[bsel * ASZ + 2048 + t * 8]);
      gl_lds16(wg + s * 32, &Bs[bsel * BSZ + t * 8]);
      if constexpr (BN == 128)
        gl_lds16(wg + (size_t)64 * KSZ + s * 32, &Bs[bsel * BSZ + 2048 + t * 8]);
    };

    auto compute = [&](int bsel) {
      const u16* Ac = &As[bsel * ASZ];
      const u16* Bc = &Bs[bsel * BSZ];
      short8 af[4], bfr[NJ];
      #pragma unroll
      for (int i = 0; i < 4; ++i)
        af[i] = *(const short8*)&Ac[lds_slot32(wm + i * 16 + r16, quad)];
      #pragma unroll
      for (int j = 0; j < NJ; ++j)
        bfr[j] = *(const short8*)&Bc[lds_slot32(wn + j * 16 + r16, quad)];
      #pragma unroll
      for (int i = 0; i < 4; ++i)
        #pragma unroll
        for (int j = 0; j < NJ; ++j)
          acc[i][j] = __builtin_amdgcn_mfma_f32_16x16x32_bf16(af[i], bfr[j], acc[i][j], 0, 0, 0);
    };

    stage(0, 0);
    __syncthreads();
    for (int s = 0; s < NS; s += 2) {
      stage(s + 1, 1);                 // NS even -> s+1 always valid
      compute(0);
      __syncthreads();
      if (s + 2 < NS) stage(s + 2, 0);
      compute(1);
      __syncthreads();
    }
  }

  #pragma unroll
  for (int j = 0; j < NJ; ++j) {
    int gn = bn * BN + wn + j * 16 + r16;
    float s = 0.f, s2 = 0.f;
    #pragma unroll
    for (int i = 0; i < 4; ++i) {
      #pragma unroll
      for (int r = 0; r < 4; ++r) {
        int gm = bm * 128 + wm + i * 16 + quad * 4 + r;
        float v = acc[i][j][r];
        if constexpr (EP == 0) {
          outb[(size_t)gm * 256 + gn] = f2bf(v);
          s += v; s2 += v * v;
        } else if constexpr (EP == 1) {
          outb[(size_t)gm * 256 + gn] = f2bf(fmaxf(v + bias[gn], 0.f));
        } else if constexpr (EP == 2) {
          outb[(size_t)gm * 256 + gn] = f2bf(fmaxf(v, 0.f));
        } else {
          if (gn < nv) {
            v += bias[gn];
            if (addpts) v += addpts[(size_t)gm * 18 + gn];
            if (ptsout) ptsout[(size_t)gm * 18 + gn] = v;
            int bb = gm >> 12, p = gm & 4095;
            outf[(size_t)((bb * 116 + cb + gn) << 12) + p] = v;
          }
        }
      }
    }
    if constexpr (EP == 0) {
      // reduce lanes differing in bits {0,1,2,4,5}; keep bit3 (8-ch group)
      s += __shfl_xor(s, 1);  s2 += __shfl_xor(s2, 1);
      s += __shfl_xor(s, 2);  s2 += __shfl_xor(s2, 2);
      s += __shfl_xor(s, 4);  s2 += __shfl_xor(s2, 4);
      s += __shfl_xor(s, 16); s2 += __shfl_xor(s2, 16);
      s += __shfl_xor(s, 32); s2 += __shfl_xor(s2, 32);
      if ((lane & 55) == 0) {
        float2* sp = st + ((bm >> 5) * 32) + (gn >> 3);
        atomicAdd(&sp->x, s);
        atomicAdd(&sp->y, s2);
      }
    }
  }
}

// ---------------------------------------------------------------------------
extern "C" void kernel_launch(void* const* d_in, const int* in_sizes, int n_in,
                              void* d_out, int out_size, void* d_ws, size_t ws_size,
                              hipStream_t stream) {
  (void)in_sizes; (void)n_in; (void)out_size;
  const float* features    = (const float*)d_in[0];
  const float* cls_w       = (const float*)d_in[1];
  const float* reg_w       = (const float*)d_in[2];
  const float* cls_gn_w    = (const float*)d_in[3];
  const float* cls_gn_b    = (const float*)d_in[4];
  const float* reg_gn_w    = (const float*)d_in[5];
  const float* reg_gn_b    = (const float*)d_in[6];
  const float* init_conv_w = (const float*)d_in[7];
  const float* init_conv_b = (const float*)d_in[8];
  const float* init_out_w  = (const float*)d_in[9];
  const float* init_out_b  = (const float*)d_in[10];
  const float* cls_dcn_w   = (const float*)d_in[11];
  const float* cls_out_w   = (const float*)d_in[12];
  const float* cls_out_b   = (const float*)d_in[13];
  const float* ref_dcn_w   = (const float*)d_in[14];
  const float* ref_out_w   = (const float*)d_in[15];
  const float* ref_out_b   = (const float*)d_in[16];
  float* out = (float*)d_out;

  char* ws = (char*)d_ws;
  size_t off = 0;
  auto alloc = [&](size_t bytes) {
    char* p = ws + off;
    off += (bytes + 255) & ~(size_t)255;
    return p;
  };
  u16* wpack      = (u16*)alloc((size_t)9 * WSTEP * 2);
  u16* w1         = (u16*)alloc((size_t)3 * 32768 * 2);
  u16* xpad       = (u16*)alloc(PADB);     // 5 pads contiguous (PADB % 256 == 0)
  u16* cpadA      = (u16*)alloc(PADB);
  u16* cpadB      = (u16*)alloc(PADB);
  u16* rpadA      = (u16*)alloc(PADB);
  u16* rpadB      = (u16*)alloc(PADB);
  float* ptsbuf   = (float*)alloc((size_t)MTOT * 18 * 4);
  float2* statsAll= (float2*)alloc(3 * 256 * sizeof(float2));
  u16* initf      = (u16*)alloc((size_t)MTOT * 256 * 2);
  u16* dcnout     = (u16*)alloc((size_t)2 * MTOT * 256 * 2);
  // union region: cstage [2][M][256] bf16 (towers) then adcn [M][2304] bf16 (dcn)
  char* unionReg  = alloc((size_t)MTOT * 2304 * 2);
  u16* cstage     = (u16*)unionReg;
  u16* adcn       = (u16*)unionReg;
  u16* adcn2      = (u16*)alloc((size_t)MTOT * 2304 * 2);   // only used if ws allows
  bool paired_dcn = (off <= ws_size);

  (void)hipMemsetAsync(statsAll, 0, 3 * 256 * sizeof(float2), stream);
  setup_all<<<23444, 256, 0, stream>>>(cls_w, reg_w, init_conv_w, cls_dcn_w, ref_dcn_w,
                                       init_out_w, cls_out_w, ref_out_w, features,
                                       wpack, w1, xpad);

  // towers, paired (cls=pair0, reg=pair1): 3 layers of conv3x3+GN+relu
  // BN=64 (R7 regression at 128: grid 512 = 2 blk/CU starved the barrier overlap)
  const u16* curC = xpad; const u16* curR = xpad;
  u16* nxtC = cpadA; u16* altC = cpadB;
  u16* nxtR = rpadA; u16* altR = rpadB;
  for (int i = 0; i < 3; ++i) {
    gemm_kernel<1, 0, 2304, 64, 64, 2><<<1024, 256, 0, stream>>>(
        curC, curR, wpack + (size_t)i * WSTEP, wpack + (size_t)(3 + i) * WSTEP,
        nullptr, nullptr, cstage, cstage + (size_t)MTOT * 256,
        statsAll + i * 256, statsAll + i * 256 + 128,
        nullptr, nullptr, nullptr, nullptr, nullptr, 0, 0, 0, 0);
    gn_apply2<<<8192, 256, 0, stream>>>(cstage, statsAll + i * 256,
        cls_gn_w + i * 256, cls_gn_b + i * 256, reg_gn_w + i * 256, reg_gn_b + i * 256,
        nxtC, nxtR);
    curC = nxtC; { u16* tmp = nxtC; nxtC = altC; altC = tmp; }
    curR = nxtR; { u16* tmp = nxtR; nxtR = altR; altR = tmp; }
  }
  const u16* cls_feat = curC;   // cpadA
  const u16* reg_feat = curR;   // rpadA

  // init branch: relu(conv3x3 + b) -> initf; 1x1 -> pts_init (out ch 80..97 + ptsbuf)
  gemm_kernel<1, 1, 2304, 64, 64, 1><<<512, 256, 0, stream>>>(
      reg_feat, nullptr, wpack + (size_t)6 * WSTEP, nullptr,
      init_conv_b, nullptr, initf, nullptr, nullptr, nullptr,
      nullptr, nullptr, nullptr, nullptr, nullptr, 0, 0, 0, 0);
  gemm_kernel<0, 3, 256, 128, 32, 1><<<128, 256, 0, stream>>>(
      initf, nullptr, w1, nullptr, init_out_b, nullptr,
      nullptr, nullptr, nullptr, nullptr, out,
      nullptr, nullptr, ptsbuf, nullptr, 18, 0, 80, 0);

  if (paired_dcn) {
    dcn_sample2<<<2048, 256, 0, stream>>>(cls_feat, reg_feat, ptsbuf, adcn, adcn2);
    gemm_kernel<0, 2, 2304, 64, 64, 2><<<1024, 256, 0, stream>>>(
        adcn, adcn2, wpack + (size_t)7 * WSTEP, wpack + (size_t)8 * WSTEP,
        nullptr, nullptr, dcnout, dcnout + (size_t)MTOT * 256, nullptr, nullptr,
        nullptr, nullptr, nullptr, nullptr, nullptr, 0, 0, 0, 0);
  } else {
    dcn_sample2<<<1024, 256, 0, stream>>>(cls_feat, cls_feat, ptsbuf, adcn, adcn);
    gemm_kernel<0, 2, 2304, 64, 64, 1><<<512, 256, 0, stream>>>(
        adcn, nullptr, wpack + (size_t)7 * WSTEP, nullptr,
        nullptr, nullptr, dcnout, nullptr, nullptr, nullptr,
        nullptr, nullptr, nullptr, nullptr, nullptr, 0, 0, 0, 0);
    dcn_sample2<<<1024, 256, 0, stream>>>(reg_feat, reg_feat, ptsbuf, adcn, adcn);
    gemm_kernel<0, 2, 2304, 64, 64, 1><<<512, 256, 0, stream>>>(
        adcn, nullptr, wpack + (size_t)8 * WSTEP, nullptr,
        nullptr, nullptr, dcnout + (size_t)MTOT * 256, nullptr, nullptr, nullptr,
        nullptr, nullptr, nullptr, nullptr, nullptr, 0, 0, 0, 0);
  }

  // final heads, paired: cls (80 ch at 0), refine (18 ch at 98, + pts_init)
  gemm_kernel<0, 3, 256, 128, 32, 2><<<256, 256, 0, stream>>>(
      dcnout, dcnout + (size_t)MTOT * 256, w1 + 32768, w1 + 2 * 32768,
      cls_out_b, ref_out_b, nullptr, nullptr, nullptr, nullptr, out,
      nullptr, ptsbuf, nullptr, nullptr, 80, 18, 0, 98);
}

// Round 3
// 543.177 us; speedup vs baseline: 1.0091x; 1.0091x over previous
//
#include <hip/hip_runtime.h>

typedef unsigned short u16;
typedef __attribute__((ext_vector_type(8))) short short8;
typedef __attribute__((ext_vector_type(4))) float floatx4;

#define MTOT    16384          // 4 * 64 * 64
#define PADIMG  (66 * 66)      // padded image pixels per batch
#define PADELEM (4 * PADIMG * 256)
#define PADB    ((size_t)PADELEM * 2)   // bytes, bf16 (multiple of 256 -> allocs contiguous)
#define WSTEP   (256 * 2304)

__device__ __forceinline__ float bf2f(u16 u) {
  union { unsigned int i; float f; } c; c.i = ((unsigned int)u) << 16; return c.f;
}
__device__ __forceinline__ u16 f2bf(float f) {
  union { float f; unsigned int i; } c; c.f = f;
  unsigned int r = c.i + 0x7FFFu + ((c.i >> 16) & 1u);
  return (u16)(r >> 16);
}

__device__ __forceinline__ void gl_lds16(const void* g, void* l) {
  __builtin_amdgcn_global_load_lds(
      (const __attribute__((address_space(1))) void*)g,
      (__attribute__((address_space(3))) void*)l, 16, 0, 0);
}

// counted vmcnt wait (immediate must be compile-time)
template <int N> __device__ __forceinline__ void waitcnt_vm() {
  if constexpr (N == 0) asm volatile("s_waitcnt vmcnt(0)" ::: "memory");
  else if constexpr (N == 3) asm volatile("s_waitcnt vmcnt(3)" ::: "memory");
  else if constexpr (N == 4) asm volatile("s_waitcnt vmcnt(4)" ::: "memory");
  else if constexpr (N == 6) asm volatile("s_waitcnt vmcnt(6)" ::: "memory");
  else if constexpr (N == 8) asm volatile("s_waitcnt vmcnt(8)" ::: "memory");
}

// BK=32 LDS slot (u16 units): 4 chunks/row, XOR with (row>>1)&3  [R4: 0 conflicts]
__device__ __forceinline__ int lds_slot32(int row, int q) {
  return row * 32 + ((q ^ ((row >> 1) & 3)) << 3);
}
// BK=64 LDS slot: 8 chunks/row, XOR with row&7  [R5: 0 conflicts]
__device__ __forceinline__ int lds_slot64(int row, int q) {
  return row * 64 + ((q ^ (row & 7)) << 3);
}

// ---------------------------------------------------------------------------
// merged setup kernel (all regions disjoint):
//   blk < 20736          : pack conv3x3 weights -> flat [w][o][(ky*3+kx)*256+c]
//   blk < 21120          : pack 1x1 weights -> [128 zero-pad][256] x3
//   blk < 22144 (1024)   : features NCHW fp32 -> bf16 padded NHWC interior
//   blk < 23444 (1300)   : zero halo rings of the 5 padded buffers
__global__ void setup_all(const float* __restrict__ cls_w, const float* __restrict__ reg_w,
                          const float* __restrict__ initw, const float* __restrict__ clsd,
                          const float* __restrict__ refd,
                          const float* __restrict__ iw, const float* __restrict__ cw,
                          const float* __restrict__ rw,
                          const float* __restrict__ features,
                          u16* __restrict__ dst3, u16* __restrict__ dst1,
                          u16* __restrict__ pads) {
  int blk = blockIdx.x;
  int t = threadIdx.x;
  if (blk < 20736) {
    int w = blk / 2304;
    const float* src = (w < 3) ? cls_w + (size_t)w * WSTEP
                     : (w < 6) ? reg_w + (size_t)(w - 3) * WSTEP
                     : (w == 6) ? initw : (w == 7) ? clsd : refd;
    int idx = (blk - w * 2304) * 256 + t;
    int o = idx / 2304, r = idx - o * 2304;
    int kk = r >> 8, c = r & 255;
    dst3[(size_t)w * WSTEP + idx] = f2bf(src[(o * 256 + c) * 9 + kk]);
  } else if (blk < 21120) {
    int bb = blk - 20736;                     // 0..383
    int wsel = bb >> 7;
    const float* src = wsel == 0 ? iw : wsel == 1 ? cw : rw;
    int nvalid = wsel == 1 ? 80 : 18;
    int idx = (bb & 127) * 256 + t;
    int o = idx >> 8, c = idx & 255;
    dst1[(size_t)wsel * 32768 + idx] = f2bf(o < nvalid ? src[o * 256 + c] : 0.f);
  } else if (blk < 22144) {
    __shared__ float tile[64][65];
    int bb = blk - 21120;                     // 0..1023
    int c0 = (bb & 3) * 64;
    int y  = (bb >> 2) & 63;
    int b  = bb >> 8;
    #pragma unroll
    for (int i = 0; i < 16; ++i) {
      int lin = t + i * 256; int c = lin >> 6, x = lin & 63;
      tile[c][x] = features[((b * 256 + c0 + c) * 64 + y) * 64 + x];
    }
    __syncthreads();
    #pragma unroll
    for (int i = 0; i < 16; ++i) {
      int lin = t + i * 256; int x = lin >> 6, c = lin & 63;
      pads[((b * 66 + y + 1) * 66 + (x + 1)) * 256 + c0 + c] = f2bf(tile[c][x]);
    }
  } else {
    int idx = (blk - 22144) * 256 + t;        // 0..332799 = 5*4*260*64
    int c4 = (idx & 63) << 2;
    int r = idx >> 6;
    int pix = r % 260;
    int ib = r / 260;                         // buf*4 + batch, 0..19
    int y, x;
    if (pix < 66)       { y = 0;  x = pix; }
    else if (pix < 132) { y = 65; x = pix - 66; }
    else if (pix < 196) { y = pix - 132 + 1; x = 0; }
    else                { y = pix - 196 + 1; x = 65; }
    size_t o = (((size_t)ib * PADIMG) + y * 66 + x) * 256 + c4;
    *(ushort4*)(pads + o) = (ushort4){0, 0, 0, 0};
  }
}

// ---------------------------------------------------------------------------
// paired GroupNorm apply: bf16 staging [2][M][256] + raw (s,s2) stats ->
// normalize+affine+relu -> padded bf16 NHWC per tower. grid 8192 x 256.
__global__ void __launch_bounds__(256)
gn_apply2(const u16* __restrict__ stage, const float2* __restrict__ st,
          const float* __restrict__ gwc, const float* __restrict__ gbc,
          const float* __restrict__ gwr, const float* __restrict__ gbr,
          u16* __restrict__ cdst, u16* __restrict__ rdst) {
  int tid = blockIdx.x * 256 + threadIdx.x;
  int tower = tid >> 20;
  int r = tid & 0xFFFFF;
  int m = r >> 6, c4 = (r & 63) << 2;
  ushort4 u = *(const ushort4*)(stage + ((size_t)tower << 22) + (size_t)m * 256 + c4);
  int b = m >> 12, p = m & 4095, y = p >> 6, x = p & 63;
  float2 ss = st[tower * 128 + b * 32 + (c4 >> 3)];
  float mu = ss.x * (1.f / 32768.f);
  float var = ss.y * (1.f / 32768.f) - mu * mu;
  float rinv = rsqrtf(var + 1e-5f);
  const float* gw = tower ? gwr : gwc;
  const float* gb = tower ? gbr : gbc;
  ushort4 o;
  o.x = f2bf(fmaxf((bf2f(u.x) - mu) * rinv * gw[c4 + 0] + gb[c4 + 0], 0.f));
  o.y = f2bf(fmaxf((bf2f(u.y) - mu) * rinv * gw[c4 + 1] + gb[c4 + 1], 0.f));
  o.z = f2bf(fmaxf((bf2f(u.z) - mu) * rinv * gw[c4 + 2] + gb[c4 + 2], 0.f));
  o.w = f2bf(fmaxf((bf2f(u.w) - mu) * rinv * gw[c4 + 3] + gb[c4 + 3], 0.f));
  u16* dst = tower ? rdst : cdst;
  *(ushort4*)(dst + ((size_t)((b * 66 + y + 1) * 66 + (x + 1)) * 256 + c4)) = o;
}

// ---------------------------------------------------------------------------
// bilinear sample, both towers. 16 lanes/pixel, 16 ch/lane (chunk c covers
// ch c*64 + l*4 -> every ld/st is 128 B contiguous per pixel-group).
// grid 2048: blk<1024 -> (featC,AC), else (featR,AR); 16 m per block.
__global__ void __launch_bounds__(256)
dcn_sample2(const u16* __restrict__ featC, const u16* __restrict__ featR,
            const float* __restrict__ pts,
            u16* __restrict__ AC, u16* __restrict__ AR) {
  int blk = blockIdx.x;
  const u16* featpad = blk < 1024 ? featC : featR;
  u16* A = blk < 1024 ? AC : AR;
  int mblk = blk & 1023;
  int t = threadIdx.x;
  int m = mblk * 16 + (t >> 4);
  int l = t & 15;
  int b = m >> 12, p = m & 4095, y = p >> 6, x = p & 63;
  const float* pp = pts + (size_t)m * 18;
  const u16* fb = featpad + (size_t)b * PADIMG * 256 + l * 4;
  u16* am = A + (size_t)m * 2304 + l * 4;
  #pragma unroll
  for (int kk = 0; kk < 9; ++kk) {
    float py = (float)y + pp[2 * kk];
    float px = (float)x + pp[2 * kk + 1];
    float fy = floorf(py), fx = floorf(px);
    int y0 = (int)fy, x0 = (int)fx;
    float wy = py - fy, wx = px - fx;
    float w00 = (1.f - wy) * (1.f - wx), w01 = (1.f - wy) * wx;
    float w10 = wy * (1.f - wx), w11 = wy * wx;
    bool yok0 = (unsigned)y0 < 64u, yok1 = (unsigned)(y0 + 1) < 64u;
    bool xok0 = (unsigned)x0 < 64u, xok1 = (unsigned)(x0 + 1) < 64u;
    const u16* base = fb + ((y0 + 1) * 66 + (x0 + 1)) * 256;
    float r[16];
    #pragma unroll
    for (int i = 0; i < 16; ++i) r[i] = 0.f;
    if (yok0 & xok0) {
      #pragma unroll
      for (int c = 0; c < 4; ++c) { ushort4 v = *(const ushort4*)(base + c * 64);
        r[c*4+0] += w00 * bf2f(v.x); r[c*4+1] += w00 * bf2f(v.y);
        r[c*4+2] += w00 * bf2f(v.z); r[c*4+3] += w00 * bf2f(v.w); } }
    if (yok0 & xok1) {
      #pragma unroll
      for (int c = 0; c < 4; ++c) { ushort4 v = *(const ushort4*)(base + 256 + c * 64);
        r[c*4+0] += w01 * bf2f(v.x); r[c*4+1] += w01 * bf2f(v.y);
        r[c*4+2] += w01 * bf2f(v.z); r[c*4+3] += w01 * bf2f(v.w); } }
    if (yok1 & xok0) {
      #pragma unroll
      for (int c = 0; c < 4; ++c) { ushort4 v = *(const ushort4*)(base + 66 * 256 + c * 64);
        r[c*4+0] += w10 * bf2f(v.x); r[c*4+1] += w10 * bf2f(v.y);
        r[c*4+2] += w10 * bf2f(v.z); r[c*4+3] += w10 * bf2f(v.w); } }
    if (yok1 & xok1) {
      #pragma unroll
      for (int c = 0; c < 4; ++c) { ushort4 v = *(const ushort4*)(base + 67 * 256 + c * 64);
        r[c*4+0] += w11 * bf2f(v.x); r[c*4+1] += w11 * bf2f(v.y);
        r[c*4+2] += w11 * bf2f(v.z); r[c*4+3] += w11 * bf2f(v.w); } }
    #pragma unroll
    for (int c = 0; c < 4; ++c) {
      ushort4 o;
      o.x = f2bf(r[c*4+0]); o.y = f2bf(r[c*4+1]);
      o.z = f2bf(r[c*4+2]); o.w = f2bf(r[c*4+3]);
      *(ushort4*)(am + kk * 256 + c * 64) = o;
    }
  }
}

// ---------------------------------------------------------------------------
// GEMM: C[M,N] = A[M,K] * W[N,K]^T.  128xBN tile, BK in {32,64}, 4 waves.
// [R6-verified source; R9: counted-vmcnt double-buffered pipeline (T4)]
// Block decode: [NPAIR==2: pair=blk&1, blk>>=1]  bm=blk&127, bn=blk>>7.
// AMODE 0: flat A; AMODE 1: implicit conv3x3.
// K-loop: raw s_barrier (NO vmcnt drain) + s_waitcnt vmcnt(LPS) so the
// next stage's LPS loads stay in flight across barriers. stage(s+2) is
// issued at end of iter s -> a full K-step to land. sched_barrier(0)
// after each barrier (stops ds_read hoist above the all-staged fence)
// and before each post-compute barrier (pins lgkm waits+MFMAs so LDS
// reads complete before any wave's next-stage writes can land). vmem
// loads retire in order -> vmcnt(LPS) == oldest stage fully landed.
// EP 0: bf16 staging + GN (s,s2) atomics; EP 1: +bias,relu; EP 2: relu;
// EP 3: +bias (+addpts) (+ptsout) -> fp32 NCHW d_out slice at cb, gn < nv.
template <int AMODE, int EP, int KSZ, int BN, int BK, int NPAIR>
__global__ void __launch_bounds__(256)
gemm_kernel(const u16* __restrict__ A0, const u16* __restrict__ A1,
            const u16* __restrict__ W0, const u16* __restrict__ W1,
            const float* __restrict__ bias0, const float* __restrict__ bias1,
            u16* __restrict__ outb0, u16* __restrict__ outb1,
            float2* __restrict__ st0, float2* __restrict__ st1,
            float* __restrict__ outf,
            const float* __restrict__ addpts0, const float* __restrict__ addpts1,
            float* __restrict__ ptsout0, float* __restrict__ ptsout1,
            int nv0, int nv1, int cb0, int cb1) {
  constexpr int NJ = BN / 32;                 // 16-col accum tiles per wave
  constexpr int ASZ = 128 * BK;               // u16 elements per A buffer
  constexpr int BSZ = BN * BK;
  __shared__ u16 As[2 * ASZ];
  __shared__ u16 Bs[2 * BSZ];
  int t = threadIdx.x;
  int blk = blockIdx.x;
  int pair = 0;
  if constexpr (NPAIR == 2) { pair = blk & 1; blk >>= 1; }
  const u16* A        = pair ? A1 : A0;
  const u16* Wp       = pair ? W1 : W0;
  const float* bias   = pair ? bias1 : bias0;
  u16* outb           = pair ? outb1 : outb0;
  float2* st          = pair ? st1 : st0;
  const float* addpts = pair ? addpts1 : addpts0;
  float* ptsout       = pair ? ptsout1 : ptsout0;
  int nv = pair ? nv1 : nv0;
  int cb = pair ? cb1 : cb0;

  int bm = blk & 127, bn = blk >> 7;
  int lane = t & 63, wave = t >> 6;
  int wm = (wave & 1) << 6;
  int wn = (wave >> 1) * (BN / 2);
  int quad = lane >> 4, r16 = lane & 15;

  floatx4 acc[4][NJ];
  #pragma unroll
  for (int i = 0; i < 4; ++i)
    #pragma unroll
    for (int j = 0; j < NJ; ++j)
      acc[i][j] = (floatx4){0.f, 0.f, 0.f, 0.f};

  if constexpr (BK == 64) {
    constexpr int LPS = 4 + BN / 32;  // loads per stage per thread (6 @ BN=64)
    // staging: 8 chunks/row; thread t covers (row = 32k + t>>3, slot = t&7)
    int sub = t >> 3;                 // 0..31
    int cq = (t & 7) ^ (sub & 7);     // XOR-swizzled global chunk for this slot
    int abase[4];
    #pragma unroll
    for (int k = 0; k < 4; ++k) {
      int m = bm * 128 + k * 32 + sub;
      if constexpr (AMODE == 1) {
        int b = m >> 12, p = m & 4095;
        abase[k] = ((b * 66 + (p >> 6)) * 66 + (p & 63)) * 256 + cq * 8;
      } else {
        abase[k] = m * KSZ + cq * 8;
      }
    }
    const u16* wg = Wp + (size_t)(bn * BN + sub) * KSZ + cq * 8;
    constexpr int NS = KSZ / 64;      // 36 (conv) or 4 — even in all uses

    auto stage = [&](int s, int bsel) {
      int d;
      if constexpr (AMODE == 1) {
        int kk = s >> 2;                 // 0..8
        int c0 = (s & 3) << 6;           // 0..192
        int ky = kk / 3, kx = kk - ky * 3;
        d = ((ky * 66 + kx) << 8) + c0;
      } else {
        d = s * 64;
      }
      u16* ad = &As[bsel * ASZ + t * 8];
      u16* bd = &Bs[bsel * BSZ + t * 8];
      #pragma unroll
      for (int k = 0; k < 4; ++k)
        gl_lds16(A + abase[k] + d, ad + k * 2048);
      #pragma unroll
      for (int k = 0; k < BN / 32; ++k)
        gl_lds16(wg + (size_t)(k * 32) * KSZ + s * 64, bd + k * 2048);
    };

    auto compute = [&](int bsel) {
      const u16* Ac = &As[bsel * ASZ];
      const u16* Bc = &Bs[bsel * BSZ];
      short8 af[2][4], bfr[2][NJ];
      #pragma unroll
      for (int ks = 0; ks < 2; ++ks) {
        #pragma unroll
        for (int i = 0; i < 4; ++i)
          af[ks][i] = *(const short8*)&Ac[lds_slot64(wm + i * 16 + r16, ks * 4 + quad)];
        #pragma unroll
        for (int j = 0; j < NJ; ++j)
          bfr[ks][j] = *(const short8*)&Bc[lds_slot64(wn + j * 16 + r16, ks * 4 + quad)];
      }
      #pragma unroll
      for (int ks = 0; ks < 2; ++ks)
        #pragma unroll
        for (int i = 0; i < 4; ++i)
          #pragma unroll
          for (int j = 0; j < NJ; ++j)
            acc[i][j] = __builtin_amdgcn_mfma_f32_16x16x32_bf16(af[ks][i], bfr[ks][j], acc[i][j], 0, 0, 0);
    };

    stage(0, 0);
    stage(1, 1);
    int s = 0;
    for (; s + 2 < NS; s += 2) {
      waitcnt_vm<LPS>();                       // stage(s) landed (mine)
      __builtin_amdgcn_s_barrier();            // everyone's landed
      __builtin_amdgcn_sched_barrier(0);
      compute(0);
      __builtin_amdgcn_sched_barrier(0);       // LDS reads done before barrier
      __builtin_amdgcn_s_barrier();            // all waves done reading buf0
      stage(s + 2, 0);
      waitcnt_vm<LPS>();                       // stage(s+1) landed
      __builtin_amdgcn_s_barrier();
      __builtin_amdgcn_sched_barrier(0);
      compute(1);
      __builtin_amdgcn_sched_barrier(0);
      __builtin_amdgcn_s_barrier();
      if (s + 3 < NS) stage(s + 3, 1);
    }
    // epilogue: tiles NS-2 (buf0) and NS-1 (buf1) staged, no more staging
    waitcnt_vm<LPS>();
    __builtin_amdgcn_s_barrier();
    __builtin_amdgcn_sched_barrier(0);
    compute(0);
    waitcnt_vm<0>();
    __builtin_amdgcn_s_barrier();
    __builtin_amdgcn_sched_barrier(0);
    compute(1);
  } else {
    // BK=32 path (R4-verified layout + counted-vmcnt pipeline): 4 chunks/row
    constexpr int LPS = 2 + (BN == 128 ? 2 : 1);
    int row = t >> 2;
    int chunkS = (t & 3) ^ ((t >> 3) & 3);
    int m0 = bm * 128 + row, m1 = m0 + 64;
    int abase0, abase1;
    if constexpr (AMODE == 1) {
      int b0 = m0 >> 12, p0 = m0 & 4095;
      int b1 = m1 >> 12, p1 = m1 & 4095;
      abase0 = ((b0 * 66 + (p0 >> 6)) * 66 + (p0 & 63)) * 256 + chunkS * 8;
      abase1 = ((b1 * 66 + (p1 >> 6)) * 66 + (p1 & 63)) * 256 + chunkS * 8;
    } else {
      abase0 = m0 * KSZ + chunkS * 8;
      abase1 = m1 * KSZ + chunkS * 8;
    }
    const u16* wg = Wp + (size_t)(bn * BN + row) * KSZ + chunkS * 8;
    constexpr int NS = KSZ / 32;      // 8 for heads — even

    auto stage = [&](int s, int bsel) {
      int d;
      if constexpr (AMODE == 1) {
        int kk = s >> 3;
        int c0 = (s & 7) << 5;
        int ky = kk / 3, kx = kk - ky * 3;
        d = ((ky * 66 + kx) << 8) + c0;
      } else {
        d = s * 32;
      }
      gl_lds16(A + abase0 + d, &As[bsel * ASZ + t * 8]);
      gl_lds16(A + abase1 + d, &As[bsel * ASZ + 2048 + t * 8]);
      gl_lds16(wg + s * 32, &Bs[bsel * BSZ + t * 8]);
      if constexpr (BN == 128)
        gl_lds16(wg + (size_t)64 * KSZ + s * 32, &Bs[bsel * BSZ + 2048 + t * 8]);
    };

    auto compute = [&](int bsel) {
      const u16* Ac = &As[bsel * ASZ];
      const u16* Bc = &Bs[bsel * BSZ];
      short8 af[4], bfr[NJ];
      #pragma unroll
      for (int i = 0; i < 4; ++i)
        af[i] = *(const short8*)&Ac[lds_slot32(wm + i * 16 + r16, quad)];
      #pragma unroll
      for (int j = 0; j < NJ; ++j)
        bfr[j] = *(const short8*)&Bc[lds_slot32(wn + j * 16 + r16, quad)];
      #pragma unroll
      for (int i = 0; i < 4; ++i)
        #pragma unroll
        for (int j = 0; j < NJ; ++j)
          acc[i][j] = __builtin_amdgcn_mfma_f32_16x16x32_bf16(af[i], bfr[j], acc[i][j], 0, 0, 0);
    };

    stage(0, 0);
    stage(1, 1);
    int s = 0;
    for (; s + 2 < NS; s += 2) {
      waitcnt_vm<LPS>();
      __builtin_amdgcn_s_barrier();
      __builtin_amdgcn_sched_barrier(0);
      compute(0);
      __builtin_amdgcn_sched_barrier(0);
      __builtin_amdgcn_s_barrier();
      stage(s + 2, 0);
      waitcnt_vm<LPS>();
      __builtin_amdgcn_s_barrier();
      __builtin_amdgcn_sched_barrier(0);
      compute(1);
      __builtin_amdgcn_sched_barrier(0);
      __builtin_amdgcn_s_barrier();
      if (s + 3 < NS) stage(s + 3, 1);
    }
    waitcnt_vm<LPS>();
    __builtin_amdgcn_s_barrier();
    __builtin_amdgcn_sched_barrier(0);
    compute(0);
    waitcnt_vm<0>();
    __builtin_amdgcn_s_barrier();
    __builtin_amdgcn_sched_barrier(0);
    compute(1);
  }

  #pragma unroll
  for (int j = 0; j < NJ; ++j) {
    int gn = bn * BN + wn + j * 16 + r16;
    float s = 0.f, s2 = 0.f;
    #pragma unroll
    for (int i = 0; i < 4; ++i) {
      #pragma unroll
      for (int r = 0; r < 4; ++r) {
        int gm = bm * 128 + wm + i * 16 + quad * 4 + r;
        float v = acc[i][j][r];
        if constexpr (EP == 0) {
          outb[(size_t)gm * 256 + gn] = f2bf(v);
          s += v; s2 += v * v;
        } else if constexpr (EP == 1) {
          outb[(size_t)gm * 256 + gn] = f2bf(fmaxf(v + bias[gn], 0.f));
        } else if constexpr (EP == 2) {
          outb[(size_t)gm * 256 + gn] = f2bf(fmaxf(v, 0.f));
        } else {
          if (gn < nv) {
            v += bias[gn];
            if (addpts) v += addpts[(size_t)gm * 18 + gn];
            if (ptsout) ptsout[(size_t)gm * 18 + gn] = v;
            int bb = gm >> 12, p = gm & 4095;
            outf[(size_t)((bb * 116 + cb + gn) << 12) + p] = v;
          }
        }
      }
    }
    if constexpr (EP == 0) {
      // reduce lanes differing in bits {0,1,2,4,5}; keep bit3 (8-ch group)
      s += __shfl_xor(s, 1);  s2 += __shfl_xor(s2, 1);
      s += __shfl_xor(s, 2);  s2 += __shfl_xor(s2, 2);
      s += __shfl_xor(s, 4);  s2 += __shfl_xor(s2, 4);
      s += __shfl_xor(s, 16); s2 += __shfl_xor(s2, 16);
      s += __shfl_xor(s, 32); s2 += __shfl_xor(s2, 32);
      if ((lane & 55) == 0) {
        float2* sp = st + ((bm >> 5) * 32) + (gn >> 3);
        atomicAdd(&sp->x, s);
        atomicAdd(&sp->y, s2);
      }
    }
  }
}

// ---------------------------------------------------------------------------
extern "C" void kernel_launch(void* const* d_in, const int* in_sizes, int n_in,
                              void* d_out, int out_size, void* d_ws, size_t ws_size,
                              hipStream_t stream) {
  (void)in_sizes; (void)n_in; (void)out_size;
  const float* features    = (const float*)d_in[0];
  const float* cls_w       = (const float*)d_in[1];
  const float* reg_w       = (const float*)d_in[2];
  const float* cls_gn_w    = (const float*)d_in[3];
  const float* cls_gn_b    = (const float*)d_in[4];
  const float* reg_gn_w    = (const float*)d_in[5];
  const float* reg_gn_b    = (const float*)d_in[6];
  const float* init_conv_w = (const float*)d_in[7];
  const float* init_conv_b = (const float*)d_in[8];
  const float* init_out_w  = (const float*)d_in[9];
  const float* init_out_b  = (const float*)d_in[10];
  const float* cls_dcn_w   = (const float*)d_in[11];
  const float* cls_out_w   = (const float*)d_in[12];
  const float* cls_out_b   = (const float*)d_in[13];
  const float* ref_dcn_w   = (const float*)d_in[14];
  const float* ref_out_w   = (const float*)d_in[15];
  const float* ref_out_b   = (const float*)d_in[16];
  float* out = (float*)d_out;

  char* ws = (char*)d_ws;
  size_t off = 0;
  auto alloc = [&](size_t bytes) {
    char* p = ws + off;
    off += (bytes + 255) & ~(size_t)255;
    return p;
  };
  u16* wpack      = (u16*)alloc((size_t)9 * WSTEP * 2);
  u16* w1         = (u16*)alloc((size_t)3 * 32768 * 2);
  u16* xpad       = (u16*)alloc(PADB);     // 5 pads contiguous (PADB % 256 == 0)
  u16* cpadA      = (u16*)alloc(PADB);
  u16* cpadB      = (u16*)alloc(PADB);
  u16* rpadA      = (u16*)alloc(PADB);
  u16* rpadB      = (u16*)alloc(PADB);
  float* ptsbuf   = (float*)alloc((size_t)MTOT * 18 * 4);
  float2* statsAll= (float2*)alloc(3 * 256 * sizeof(float2));
  u16* initf      = (u16*)alloc((size_t)MTOT * 256 * 2);
  u16* dcnout     = (u16*)alloc((size_t)2 * MTOT * 256 * 2);
  // union region: cstage [2][M][256] bf16 (towers) then adcn [M][2304] bf16 (dcn)
  char* unionReg  = alloc((size_t)MTOT * 2304 * 2);
  u16* cstage     = (u16*)unionReg;
  u16* adcn       = (u16*)unionReg;
  u16* adcn2      = (u16*)alloc((size_t)MTOT * 2304 * 2);   // only used if ws allows
  bool paired_dcn = (off <= ws_size);

  (void)hipMemsetAsync(statsAll, 0, 3 * 256 * sizeof(float2), stream);
  setup_all<<<23444, 256, 0, stream>>>(cls_w, reg_w, init_conv_w, cls_dcn_w, ref_dcn_w,
                                       init_out_w, cls_out_w, ref_out_w, features,
                                       wpack, w1, xpad);

  // towers, paired (cls=pair0, reg=pair1): 3 layers of conv3x3+GN+relu
  // BN=64 (R7 regression at 128: grid 512 = 2 blk/CU starved the barrier overlap)
  const u16* curC = xpad; const u16* curR = xpad;
  u16* nxtC = cpadA; u16* altC = cpadB;
  u16* nxtR = rpadA; u16* altR = rpadB;
  for (int i = 0; i < 3; ++i) {
    gemm_kernel<1, 0, 2304, 64, 64, 2><<<1024, 256, 0, stream>>>(
        curC, curR, wpack + (size_t)i * WSTEP, wpack + (size_t)(3 + i) * WSTEP,
        nullptr, nullptr, cstage, cstage + (size_t)MTOT * 256,
        statsAll + i * 256, statsAll + i * 256 + 128,
        nullptr, nullptr, nullptr, nullptr, nullptr, 0, 0, 0, 0);
    gn_apply2<<<8192, 256, 0, stream>>>(cstage, statsAll + i * 256,
        cls_gn_w + i * 256, cls_gn_b + i * 256, reg_gn_w + i * 256, reg_gn_b + i * 256,
        nxtC, nxtR);
    curC = nxtC; { u16* tmp = nxtC; nxtC = altC; altC = tmp; }
    curR = nxtR; { u16* tmp = nxtR; nxtR = altR; altR = tmp; }
  }
  const u16* cls_feat = curC;   // cpadA
  const u16* reg_feat = curR;   // rpadA

  // init branch: relu(conv3x3 + b) -> initf; 1x1 -> pts_init (out ch 80..97 + ptsbuf)
  gemm_kernel<1, 1, 2304, 64, 64, 1><<<512, 256, 0, stream>>>(
      reg_feat, nullptr, wpack + (size_t)6 * WSTEP, nullptr,
      init_conv_b, nullptr, initf, nullptr, nullptr, nullptr,
      nullptr, nullptr, nullptr, nullptr, nullptr, 0, 0, 0, 0);
  gemm_kernel<0, 3, 256, 128, 32, 1><<<128, 256, 0, stream>>>(
      initf, nullptr, w1, nullptr, init_out_b, nullptr,
      nullptr, nullptr, nullptr, nullptr, out,
      nullptr, nullptr, ptsbuf, nullptr, 18, 0, 80, 0);

  if (paired_dcn) {
    dcn_sample2<<<2048, 256, 0, stream>>>(cls_feat, reg_feat, ptsbuf, adcn, adcn2);
    gemm_kernel<0, 2, 2304, 64, 64, 2><<<1024, 256, 0, stream>>>(
        adcn, adcn2, wpack + (size_t)7 * WSTEP, wpack + (size_t)8 * WSTEP,
        nullptr, nullptr, dcnout, dcnout + (size_t)MTOT * 256, nullptr, nullptr,
        nullptr, nullptr, nullptr, nullptr, nullptr, 0, 0, 0, 0);
  } else {
    dcn_sample2<<<1024, 256, 0, stream>>>(cls_feat, cls_feat, ptsbuf, adcn, adcn);
    gemm_kernel<0, 2, 2304, 64, 64, 1><<<512, 256, 0, stream>>>(
        adcn, nullptr, wpack + (size_t)7 * WSTEP, nullptr,
        nullptr, nullptr, dcnout, nullptr, nullptr, nullptr,
        nullptr, nullptr, nullptr, nullptr, nullptr, 0, 0, 0, 0);
    dcn_sample2<<<1024, 256, 0, stream>>>(reg_feat, reg_feat, ptsbuf, adcn, adcn);
    gemm_kernel<0, 2, 2304, 64, 64, 1><<<512, 256, 0, stream>>>(
        adcn, nullptr, wpack + (size_t)8 * WSTEP, nullptr,
        nullptr, nullptr, dcnout + (size_t)MTOT * 256, nullptr, nullptr, nullptr,
        nullptr, nullptr, nullptr, nullptr, nullptr, 0, 0, 0, 0);
  }

  // final heads, paired: cls (80 ch at 0), refine (18 ch at 98, + pts_init)
  gemm_kernel<0, 3, 256, 128, 32, 2><<<256, 256, 0, stream>>>(
      dcnout, dcnout + (size_t)MTOT * 256, w1 + 32768, w1 + 2 * 32768,
      cls_out_b, ref_out_b, nullptr, nullptr, nullptr, nullptr, out,
      nullptr, ptsbuf, nullptr, nullptr, 80, 18, 0, 98);
}

// Round 5
// 461.943 us; speedup vs baseline: 1.1865x; 1.1759x over previous
//
#include <hip/hip_runtime.h>

typedef unsigned short u16;
typedef __attribute__((ext_vector_type(8))) short short8;
typedef __attribute__((ext_vector_type(4))) float floatx4;

#define MTOT    16384          // 4 * 64 * 64
#define PADIMG  (66 * 66)      // padded image pixels per batch
#define PADELEM (4 * PADIMG * 256)
#define PADB    ((size_t)PADELEM * 2)   // bytes, bf16 (multiple of 256 -> allocs contiguous)
#define WSTEP   (256 * 2304)

__device__ __forceinline__ float bf2f(u16 u) {
  union { unsigned int i; float f; } c; c.i = ((unsigned int)u) << 16; return c.f;
}
__device__ __forceinline__ u16 f2bf(float f) {
  union { float f; unsigned int i; } c; c.f = f;
  unsigned int r = c.i + 0x7FFFu + ((c.i >> 16) & 1u);
  return (u16)(r >> 16);
}

__device__ __forceinline__ void gl_lds16(const void* g, void* l) {
  __builtin_amdgcn_global_load_lds(
      (const __attribute__((address_space(1))) void*)g,
      (__attribute__((address_space(3))) void*)l, 16, 0, 0);
}

// BK=32 LDS slot (u16 units): 4 chunks/row, XOR with (row>>1)&3  [R4: 0 conflicts]
__device__ __forceinline__ int lds_slot32(int row, int q) {
  return row * 32 + ((q ^ ((row >> 1) & 3)) << 3);
}
// BK=64 LDS slot: 8 chunks/row, XOR with row&7  [R5: 0 conflicts]
__device__ __forceinline__ int lds_slot64(int row, int q) {
  return row * 64 + ((q ^ (row & 7)) << 3);
}

// ---------------------------------------------------------------------------
// merged setup kernel (all regions disjoint):
//   blk < 2304          : pack conv3x3 weights via LDS transpose (coalesced):
//                         one block per (tensor w, out-ch o); read 2304 floats
//                         contiguous, write [kk*256+c] bf16. LDS read stride 9
//                         is conflict-free (gcd(9,32)=1).
//   blk < 2688 (384)    : pack 1x1 weights -> [128 zero-pad][256] x3
//   blk < 3712 (1024)   : features NCHW fp32 -> bf16 padded NHWC interior
//   blk < 5012 (1300)   : zero halo rings of the 5 padded buffers
__global__ void setup_all(const float* __restrict__ cls_w, const float* __restrict__ reg_w,
                          const float* __restrict__ initw, const float* __restrict__ clsd,
                          const float* __restrict__ refd,
                          const float* __restrict__ iw, const float* __restrict__ cw,
                          const float* __restrict__ rw,
                          const float* __restrict__ features,
                          u16* __restrict__ dst3, u16* __restrict__ dst1,
                          u16* __restrict__ pads) {
  int blk = blockIdx.x;
  int t = threadIdx.x;
  if (blk < 2304) {
    int w = blk >> 8;                         // 0..8
    int o = blk & 255;
    const float* src = (w < 3) ? cls_w + (size_t)w * WSTEP
                     : (w < 6) ? reg_w + (size_t)(w - 3) * WSTEP
                     : (w == 6) ? initw : (w == 7) ? clsd : refd;
    __shared__ float wl[2304];
    const float* so = src + (size_t)o * 2304;   // [c][kk] contiguous
    #pragma unroll
    for (int p = 0; p < 9; ++p) wl[p * 256 + t] = so[p * 256 + t];
    __syncthreads();
    u16* dw = dst3 + (size_t)w * WSTEP + (size_t)o * 2304;
    #pragma unroll
    for (int p = 0; p < 9; ++p)                 // write [kk=p][c=t]
      dw[p * 256 + t] = f2bf(wl[t * 9 + p]);
  } else if (blk < 2688) {
    int bb = blk - 2304;                      // 0..383
    int wsel = bb >> 7;
    const float* src = wsel == 0 ? iw : wsel == 1 ? cw : rw;
    int nvalid = wsel == 1 ? 80 : 18;
    int idx = (bb & 127) * 256 + t;
    int o = idx >> 8, c = idx & 255;
    dst1[(size_t)wsel * 32768 + idx] = f2bf(o < nvalid ? src[o * 256 + c] : 0.f);
  } else if (blk < 3712) {
    __shared__ float tile[64][65];
    int bb = blk - 2688;                      // 0..1023
    int c0 = (bb & 3) * 64;
    int y  = (bb >> 2) & 63;
    int b  = bb >> 8;
    #pragma unroll
    for (int i = 0; i < 16; ++i) {
      int lin = t + i * 256; int c = lin >> 6, x = lin & 63;
      tile[c][x] = features[((b * 256 + c0 + c) * 64 + y) * 64 + x];
    }
    __syncthreads();
    #pragma unroll
    for (int i = 0; i < 16; ++i) {
      int lin = t + i * 256; int x = lin >> 6, c = lin & 63;
      pads[((b * 66 + y + 1) * 66 + (x + 1)) * 256 + c0 + c] = f2bf(tile[c][x]);
    }
  } else {
    int idx = (blk - 3712) * 256 + t;         // 0..332799 = 5*4*260*64
    int c4 = (idx & 63) << 2;
    int r = idx >> 6;
    int pix = r % 260;
    int ib = r / 260;                         // buf*4 + batch, 0..19
    int y, x;
    if (pix < 66)       { y = 0;  x = pix; }
    else if (pix < 132) { y = 65; x = pix - 66; }
    else if (pix < 196) { y = pix - 132 + 1; x = 0; }
    else                { y = pix - 196 + 1; x = 65; }
    size_t o = (((size_t)ib * PADIMG) + y * 66 + x) * 256 + c4;
    *(ushort4*)(pads + o) = (ushort4){0, 0, 0, 0};
  }
}

// ---------------------------------------------------------------------------
// paired GroupNorm apply: bf16 staging [2][M][256] + raw (s,s2) stats ->
// normalize+affine+relu -> padded bf16 NHWC per tower. grid 8192 x 256.
__global__ void __launch_bounds__(256)
gn_apply2(const u16* __restrict__ stage, const float2* __restrict__ st,
          const float* __restrict__ gwc, const float* __restrict__ gbc,
          const float* __restrict__ gwr, const float* __restrict__ gbr,
          u16* __restrict__ cdst, u16* __restrict__ rdst) {
  int tid = blockIdx.x * 256 + threadIdx.x;
  int tower = tid >> 20;
  int r = tid & 0xFFFFF;
  int m = r >> 6, c4 = (r & 63) << 2;
  ushort4 u = *(const ushort4*)(stage + ((size_t)tower << 22) + (size_t)m * 256 + c4);
  int b = m >> 12, p = m & 4095, y = p >> 6, x = p & 63;
  float2 ss = st[tower * 128 + b * 32 + (c4 >> 3)];
  float mu = ss.x * (1.f / 32768.f);
  float var = ss.y * (1.f / 32768.f) - mu * mu;
  float rinv = rsqrtf(var + 1e-5f);
  const float* gw = tower ? gwr : gwc;
  const float* gb = tower ? gbr : gbc;
  ushort4 o;
  o.x = f2bf(fmaxf((bf2f(u.x) - mu) * rinv * gw[c4 + 0] + gb[c4 + 0], 0.f));
  o.y = f2bf(fmaxf((bf2f(u.y) - mu) * rinv * gw[c4 + 1] + gb[c4 + 1], 0.f));
  o.z = f2bf(fmaxf((bf2f(u.z) - mu) * rinv * gw[c4 + 2] + gb[c4 + 2], 0.f));
  o.w = f2bf(fmaxf((bf2f(u.w) - mu) * rinv * gw[c4 + 3] + gb[c4 + 3], 0.f));
  u16* dst = tower ? rdst : cdst;
  *(ushort4*)(dst + ((size_t)((b * 66 + y + 1) * 66 + (x + 1)) * 256 + c4)) = o;
}

// ---------------------------------------------------------------------------
// bilinear sample, both towers. 16 lanes/pixel, 16 ch/lane (chunk c covers
// ch c*64 + l*4 -> every ld/st is 128 B contiguous per pixel-group).
// grid 2048: blk<1024 -> (featC,AC), else (featR,AR); 16 m per block.
__global__ void __launch_bounds__(256)
dcn_sample2(const u16* __restrict__ featC, const u16* __restrict__ featR,
            const float* __restrict__ pts,
            u16* __restrict__ AC, u16* __restrict__ AR) {
  int blk = blockIdx.x;
  const u16* featpad = blk < 1024 ? featC : featR;
  u16* A = blk < 1024 ? AC : AR;
  int mblk = blk & 1023;
  int t = threadIdx.x;
  int m = mblk * 16 + (t >> 4);
  int l = t & 15;
  int b = m >> 12, p = m & 4095, y = p >> 6, x = p & 63;
  const float* pp = pts + (size_t)m * 18;
  const u16* fb = featpad + (size_t)b * PADIMG * 256 + l * 4;
  u16* am = A + (size_t)m * 2304 + l * 4;
  #pragma unroll
  for (int kk = 0; kk < 9; ++kk) {
    float py = (float)y + pp[2 * kk];
    float px = (float)x + pp[2 * kk + 1];
    float fy = floorf(py), fx = floorf(px);
    int y0 = (int)fy, x0 = (int)fx;
    float wy = py - fy, wx = px - fx;
    float w00 = (1.f - wy) * (1.f - wx), w01 = (1.f - wy) * wx;
    float w10 = wy * (1.f - wx), w11 = wy * wx;
    bool yok0 = (unsigned)y0 < 64u, yok1 = (unsigned)(y0 + 1) < 64u;
    bool xok0 = (unsigned)x0 < 64u, xok1 = (unsigned)(x0 + 1) < 64u;
    const u16* base = fb + ((y0 + 1) * 66 + (x0 + 1)) * 256;
    float r[16];
    #pragma unroll
    for (int i = 0; i < 16; ++i) r[i] = 0.f;
    if (yok0 & xok0) {
      #pragma unroll
      for (int c = 0; c < 4; ++c) { ushort4 v = *(const ushort4*)(base + c * 64);
        r[c*4+0] += w00 * bf2f(v.x); r[c*4+1] += w00 * bf2f(v.y);
        r[c*4+2] += w00 * bf2f(v.z); r[c*4+3] += w00 * bf2f(v.w); } }
    if (yok0 & xok1) {
      #pragma unroll
      for (int c = 0; c < 4; ++c) { ushort4 v = *(const ushort4*)(base + 256 + c * 64);
        r[c*4+0] += w01 * bf2f(v.x); r[c*4+1] += w01 * bf2f(v.y);
        r[c*4+2] += w01 * bf2f(v.z); r[c*4+3] += w01 * bf2f(v.w); } }
    if (yok1 & xok0) {
      #pragma unroll
      for (int c = 0; c < 4; ++c) { ushort4 v = *(const ushort4*)(base + 66 * 256 + c * 64);
        r[c*4+0] += w10 * bf2f(v.x); r[c*4+1] += w10 * bf2f(v.y);
        r[c*4+2] += w10 * bf2f(v.z); r[c*4+3] += w10 * bf2f(v.w); } }
    if (yok1 & xok1) {
      #pragma unroll
      for (int c = 0; c < 4; ++c) { ushort4 v = *(const ushort4*)(base + 67 * 256 + c * 64);
        r[c*4+0] += w11 * bf2f(v.x); r[c*4+1] += w11 * bf2f(v.y);
        r[c*4+2] += w11 * bf2f(v.z); r[c*4+3] += w11 * bf2f(v.w); } }
    #pragma unroll
    for (int c = 0; c < 4; ++c) {
      ushort4 o;
      o.x = f2bf(r[c*4+0]); o.y = f2bf(r[c*4+1]);
      o.z = f2bf(r[c*4+2]); o.w = f2bf(r[c*4+3]);
      *(ushort4*)(am + kk * 256 + c * 64) = o;
    }
  }
}

// ---------------------------------------------------------------------------
// GEMM: C[M,N] = A[M,K] * W[N,K]^T.  128xBN tile, BK in {32,64}, 4 waves.
// [R6-verified source, single-buffer K-loop. R7-R9 pipelining variants all
//  regressed or were neutral; R10 cooperative GN fusion raced — reverted.]
// Block decode: [NPAIR==2: pair=blk&1, blk>>=1]  bm=blk&127, bn=blk>>7.
// AMODE 0: flat A; AMODE 1: implicit conv3x3.
// EP 0: bf16 staging + GN (s,s2) atomics; EP 1: +bias,relu; EP 2: relu;
// EP 3: +bias (+addpts) (+ptsout) -> fp32 NCHW d_out slice at cb, gn < nv.
template <int AMODE, int EP, int KSZ, int BN, int BK, int NPAIR>
__global__ void __launch_bounds__(256)
gemm_kernel(const u16* __restrict__ A0, const u16* __restrict__ A1,
            const u16* __restrict__ W0, const u16* __restrict__ W1,
            const float* __restrict__ bias0, const float* __restrict__ bias1,
            u16* __restrict__ outb0, u16* __restrict__ outb1,
            float2* __restrict__ st0, float2* __restrict__ st1,
            float* __restrict__ outf,
            const float* __restrict__ addpts0, const float* __restrict__ addpts1,
            float* __restrict__ ptsout0, float* __restrict__ ptsout1,
            int nv0, int nv1, int cb0, int cb1) {
  constexpr int NJ = BN / 32;                 // 16-col accum tiles per wave
  __shared__ u16 As[128 * BK];
  __shared__ u16 Bs[BN * BK];
  int t = threadIdx.x;
  int blk = blockIdx.x;
  int pair = 0;
  if constexpr (NPAIR == 2) { pair = blk & 1; blk >>= 1; }
  const u16* A        = pair ? A1 : A0;
  const u16* Wp       = pair ? W1 : W0;
  const float* bias   = pair ? bias1 : bias0;
  u16* outb           = pair ? outb1 : outb0;
  float2* st          = pair ? st1 : st0;
  const float* addpts = pair ? addpts1 : addpts0;
  float* ptsout       = pair ? ptsout1 : ptsout0;
  int nv = pair ? nv1 : nv0;
  int cb = pair ? cb1 : cb0;

  int bm = blk & 127, bn = blk >> 7;
  int lane = t & 63, wave = t >> 6;
  int wm = (wave & 1) << 6;
  int wn = (wave >> 1) * (BN / 2);
  int quad = lane >> 4, r16 = lane & 15;

  floatx4 acc[4][NJ];
  #pragma unroll
  for (int i = 0; i < 4; ++i)
    #pragma unroll
    for (int j = 0; j < NJ; ++j)
      acc[i][j] = (floatx4){0.f, 0.f, 0.f, 0.f};

  if constexpr (BK == 64) {
    // staging: 8 chunks/row; thread t covers (row = 32k + t>>3, slot = t&7)
    int sub = t >> 3;                 // 0..31
    int cq = (t & 7) ^ (sub & 7);     // XOR-swizzled global chunk for this slot
    int abase[4];
    #pragma unroll
    for (int k = 0; k < 4; ++k) {
      int m = bm * 128 + k * 32 + sub;
      if constexpr (AMODE == 1) {
        int b = m >> 12, p = m & 4095;
        abase[k] = ((b * 66 + (p >> 6)) * 66 + (p & 63)) * 256 + cq * 8;
      } else {
        abase[k] = m * KSZ + cq * 8;
      }
    }
    const u16* wg = Wp + (size_t)(bn * BN + sub) * KSZ + cq * 8;

    for (int s = 0; s < KSZ / 64; ++s) {
      int d;
      if constexpr (AMODE == 1) {
        int kk = s >> 2;                 // 0..8
        int c0 = (s & 3) << 6;           // 0..192
        int ky = kk / 3, kx = kk - ky * 3;
        d = ((ky * 66 + kx) << 8) + c0;
      } else {
        d = s * 64;
      }
      #pragma unroll
      for (int k = 0; k < 4; ++k)
        gl_lds16(A + abase[k] + d, &As[k * 2048 + t * 8]);
      #pragma unroll
      for (int k = 0; k < BN / 32; ++k)
        gl_lds16(wg + (size_t)(k * 32) * KSZ + s * 64, &Bs[k * 2048 + t * 8]);
      __syncthreads();
      short8 af[2][4], bfr[2][NJ];
      #pragma unroll
      for (int ks = 0; ks < 2; ++ks) {
        #pragma unroll
        for (int i = 0; i < 4; ++i)
          af[ks][i] = *(const short8*)&As[lds_slot64(wm + i * 16 + r16, ks * 4 + quad)];
        #pragma unroll
        for (int j = 0; j < NJ; ++j)
          bfr[ks][j] = *(const short8*)&Bs[lds_slot64(wn + j * 16 + r16, ks * 4 + quad)];
      }
      #pragma unroll
      for (int ks = 0; ks < 2; ++ks)
        #pragma unroll
        for (int i = 0; i < 4; ++i)
          #pragma unroll
          for (int j = 0; j < NJ; ++j)
            acc[i][j] = __builtin_amdgcn_mfma_f32_16x16x32_bf16(af[ks][i], bfr[ks][j], acc[i][j], 0, 0, 0);
      __syncthreads();
    }
  } else {
    // BK=32 path (R4-verified): 4 chunks/row
    int row = t >> 2;
    int chunkS = (t & 3) ^ ((t >> 3) & 3);
    int m0 = bm * 128 + row, m1 = m0 + 64;
    int abase0, abase1;
    if constexpr (AMODE == 1) {
      int b0 = m0 >> 12, p0 = m0 & 4095;
      int b1 = m1 >> 12, p1 = m1 & 4095;
      abase0 = ((b0 * 66 + (p0 >> 6)) * 66 + (p0 & 63)) * 256 + chunkS * 8;
      abase1 = ((b1 * 66 + (p1 >> 6)) * 66 + (p1 & 63)) * 256 + chunkS * 8;
    } else {
      abase0 = m0 * KSZ + chunkS * 8;
      abase1 = m1 * KSZ + chunkS * 8;
    }
    const u16* wg = Wp + (size_t)(bn * BN + row) * KSZ + chunkS * 8;

    for (int s = 0; s < KSZ / 32; ++s) {
      int d;
      if constexpr (AMODE == 1) {
        int kk = s >> 3;
        int c0 = (s & 7) << 5;
        int ky = kk / 3, kx = kk - ky * 3;
        d = ((ky * 66 + kx) << 8) + c0;
      } else {
        d = s * 32;
      }
      gl_lds16(A + abase0 + d, &As[t * 8]);
      gl_lds16(A + abase1 + d, &As[2048 + t * 8]);
      gl_lds16(wg + s * 32, &Bs[t * 8]);
      if constexpr (BN == 128)
        gl_lds16(wg + (size_t)64 * KSZ + s * 32, &Bs[2048 + t * 8]);
      __syncthreads();
      short8 af[4], bfr[NJ];
      #pragma unroll
      for (int i = 0; i < 4; ++i)
        af[i] = *(const short8*)&As[lds_slot32(wm + i * 16 + r16, quad)];
      #pragma unroll
      for (int j = 0; j < NJ; ++j)
        bfr[j] = *(const short8*)&Bs[lds_slot32(wn + j * 16 + r16, quad)];
      #pragma unroll
      for (int i = 0; i < 4; ++i)
        #pragma unroll
        for (int j = 0; j < NJ; ++j)
          acc[i][j] = __builtin_amdgcn_mfma_f32_16x16x32_bf16(af[i], bfr[j], acc[i][j], 0, 0, 0);
      __syncthreads();
    }
  }

  #pragma unroll
  for (int j = 0; j < NJ; ++j) {
    int gn = bn * BN + wn + j * 16 + r16;
    float s = 0.f, s2 = 0.f;
    #pragma unroll
    for (int i = 0; i < 4; ++i) {
      #pragma unroll
      for (int r = 0; r < 4; ++r) {
        int gm = bm * 128 + wm + i * 16 + quad * 4 + r;
        float v = acc[i][j][r];
        if constexpr (EP == 0) {
          outb[(size_t)gm * 256 + gn] = f2bf(v);
          s += v; s2 += v * v;
        } else if constexpr (EP == 1) {
          outb[(size_t)gm * 256 + gn] = f2bf(fmaxf(v + bias[gn], 0.f));
        } else if constexpr (EP == 2) {
          outb[(size_t)gm * 256 + gn] = f2bf(fmaxf(v, 0.f));
        } else {
          if (gn < nv) {
            v += bias[gn];
            if (addpts) v += addpts[(size_t)gm * 18 + gn];
            if (ptsout) ptsout[(size_t)gm * 18 + gn] = v;
            int bb = gm >> 12, p = gm & 4095;
            outf[(size_t)((bb * 116 + cb + gn) << 12) + p] = v;
          }
        }
      }
    }
    if constexpr (EP == 0) {
      // reduce lanes differing in bits {0,1,2,4,5}; keep bit3 (8-ch group)
      s += __shfl_xor(s, 1);  s2 += __shfl_xor(s2, 1);
      s += __shfl_xor(s, 2);  s2 += __shfl_xor(s2, 2);
      s += __shfl_xor(s, 4);  s2 += __shfl_xor(s2, 4);
      s += __shfl_xor(s, 16); s2 += __shfl_xor(s2, 16);
      s += __shfl_xor(s, 32); s2 += __shfl_xor(s2, 32);
      if ((lane & 55) == 0) {
        float2* sp = st + ((bm >> 5) * 32) + (gn >> 3);
        atomicAdd(&sp->x, s);
        atomicAdd(&sp->y, s2);
      }
    }
  }
}

// ---------------------------------------------------------------------------
extern "C" void kernel_launch(void* const* d_in, const int* in_sizes, int n_in,
                              void* d_out, int out_size, void* d_ws, size_t ws_size,
                              hipStream_t stream) {
  (void)in_sizes; (void)n_in; (void)out_size;
  const float* features    = (const float*)d_in[0];
  const float* cls_w       = (const float*)d_in[1];
  const float* reg_w       = (const float*)d_in[2];
  const float* cls_gn_w    = (const float*)d_in[3];
  const float* cls_gn_b    = (const float*)d_in[4];
  const float* reg_gn_w    = (const float*)d_in[5];
  const float* reg_gn_b    = (const float*)d_in[6];
  const float* init_conv_w = (const float*)d_in[7];
  const float* init_conv_b = (const float*)d_in[8];
  const float* init_out_w  = (const float*)d_in[9];
  const float* init_out_b  = (const float*)d_in[10];
  const float* cls_dcn_w   = (const float*)d_in[11];
  const float* cls_out_w   = (const float*)d_in[12];
  const float* cls_out_b   = (const float*)d_in[13];
  const float* ref_dcn_w   = (const float*)d_in[14];
  const float* ref_out_w   = (const float*)d_in[15];
  const float* ref_out_b   = (const float*)d_in[16];
  float* out = (float*)d_out;

  char* ws = (char*)d_ws;
  size_t off = 0;
  auto alloc = [&](size_t bytes) {
    char* p = ws + off;
    off += (bytes + 255) & ~(size_t)255;
    return p;
  };
  u16* wpack      = (u16*)alloc((size_t)9 * WSTEP * 2);
  u16* w1         = (u16*)alloc((size_t)3 * 32768 * 2);
  u16* xpad       = (u16*)alloc(PADB);     // 5 pads contiguous (PADB % 256 == 0)
  u16* cpadA      = (u16*)alloc(PADB);
  u16* cpadB      = (u16*)alloc(PADB);
  u16* rpadA      = (u16*)alloc(PADB);
  u16* rpadB      = (u16*)alloc(PADB);
  float* ptsbuf   = (float*)alloc((size_t)MTOT * 18 * 4);
  float2* statsAll= (float2*)alloc(3 * 256 * sizeof(float2));
  u16* initf      = (u16*)alloc((size_t)MTOT * 256 * 2);
  u16* dcnout     = (u16*)alloc((size_t)2 * MTOT * 256 * 2);
  // union region: cstage [2][M][256] bf16 (towers) then adcn [M][2304] bf16 (dcn)
  char* unionReg  = alloc((size_t)MTOT * 2304 * 2);
  u16* cstage     = (u16*)unionReg;
  u16* adcn       = (u16*)unionReg;
  u16* adcn2      = (u16*)alloc((size_t)MTOT * 2304 * 2);   // only used if ws allows
  bool paired_dcn = (off <= ws_size);

  (void)hipMemsetAsync(statsAll, 0, 3 * 256 * sizeof(float2), stream);
  setup_all<<<5012, 256, 0, stream>>>(cls_w, reg_w, init_conv_w, cls_dcn_w, ref_dcn_w,
                                      init_out_w, cls_out_w, ref_out_w, features,
                                      wpack, w1, xpad);

  // towers, paired (cls=pair0, reg=pair1): 3 layers of conv3x3+GN+relu
  // (R0-verified two-kernel flow: EP0 staging+stats, then gn_apply2)
  const u16* curC = xpad; const u16* curR = xpad;
  u16* nxtC = cpadA; u16* altC = cpadB;
  u16* nxtR = rpadA; u16* altR = rpadB;
  for (int i = 0; i < 3; ++i) {
    gemm_kernel<1, 0, 2304, 64, 64, 2><<<1024, 256, 0, stream>>>(
        curC, curR, wpack + (size_t)i * WSTEP, wpack + (size_t)(3 + i) * WSTEP,
        nullptr, nullptr, cstage, cstage + (size_t)MTOT * 256,
        statsAll + i * 256, statsAll + i * 256 + 128,
        nullptr, nullptr, nullptr, nullptr, nullptr, 0, 0, 0, 0);
    gn_apply2<<<8192, 256, 0, stream>>>(cstage, statsAll + i * 256,
        cls_gn_w + i * 256, cls_gn_b + i * 256, reg_gn_w + i * 256, reg_gn_b + i * 256,
        nxtC, nxtR);
    curC = nxtC; { u16* tmp = nxtC; nxtC = altC; altC = tmp; }
    curR = nxtR; { u16* tmp = nxtR; nxtR = altR; altR = tmp; }
  }
  const u16* cls_feat = curC;   // cpadA
  const u16* reg_feat = curR;   // rpadA

  // init branch: relu(conv3x3 + b) -> initf.
  // BN=32 -> grid 1024 = 4 blk/CU (at 512 = 2/CU this dispatch took the same
  // 61.5us as a paired 1024-block one: per-block latency floor, half the CUs idle)
  gemm_kernel<1, 1, 2304, 32, 64, 1><<<1024, 256, 0, stream>>>(
      reg_feat, nullptr, wpack + (size_t)6 * WSTEP, nullptr,
      init_conv_b, nullptr, initf, nullptr, nullptr, nullptr,
      nullptr, nullptr, nullptr, nullptr, nullptr, 0, 0, 0, 0);
  // 1x1 -> pts_init (out ch 80..97 + ptsbuf). BN=64 -> 256 blocks (was 128)
  gemm_kernel<0, 3, 256, 64, 32, 1><<<256, 256, 0, stream>>>(
      initf, nullptr, w1, nullptr, init_out_b, nullptr,
      nullptr, nullptr, nullptr, nullptr, out,
      nullptr, nullptr, ptsbuf, nullptr, 18, 0, 80, 0);

  if (paired_dcn) {
    dcn_sample2<<<2048, 256, 0, stream>>>(cls_feat, reg_feat, ptsbuf, adcn, adcn2);
    gemm_kernel<0, 2, 2304, 64, 64, 2><<<1024, 256, 0, stream>>>(
        adcn, adcn2, wpack + (size_t)7 * WSTEP, wpack + (size_t)8 * WSTEP,
        nullptr, nullptr, dcnout, dcnout + (size_t)MTOT * 256, nullptr, nullptr,
        nullptr, nullptr, nullptr, nullptr, nullptr, 0, 0, 0, 0);
  } else {
    dcn_sample2<<<1024, 256, 0, stream>>>(cls_feat, cls_feat, ptsbuf, adcn, adcn);
    gemm_kernel<0, 2, 2304, 64, 64, 1><<<512, 256, 0, stream>>>(
        adcn, nullptr, wpack + (size_t)7 * WSTEP, nullptr,
        nullptr, nullptr, dcnout, nullptr, nullptr, nullptr,
        nullptr, nullptr, nullptr, nullptr, nullptr, 0, 0, 0, 0);
    dcn_sample2<<<1024, 256, 0, stream>>>(reg_feat, reg_feat, ptsbuf, adcn, adcn);
    gemm_kernel<0, 2, 2304, 64, 64, 1><<<512, 256, 0, stream>>>(
        adcn, nullptr, wpack + (size_t)8 * WSTEP, nullptr,
        nullptr, nullptr, dcnout + (size_t)MTOT * 256, nullptr, nullptr, nullptr,
        nullptr, nullptr, nullptr, nullptr, nullptr, 0, 0, 0, 0);
  }

  // final heads, paired: cls (80 ch at 0), refine (18 ch at 98, + pts_init)
  // BN=64 -> grid 512 (was 256 = 1 blk/CU)
  gemm_kernel<0, 3, 256, 64, 32, 2><<<512, 256, 0, stream>>>(
      dcnout, dcnout + (size_t)MTOT * 256, w1 + 32768, w1 + 2 * 32768,
      cls_out_b, ref_out_b, nullptr, nullptr, nullptr, nullptr, out,
      nullptr, ptsbuf, nullptr, nullptr, 80, 18, 0, 98);
}

// Round 6
// 437.648 us; speedup vs baseline: 1.2524x; 1.0555x over previous
//
#include <hip/hip_runtime.h>

typedef unsigned short u16;
typedef unsigned char u8;
typedef __attribute__((ext_vector_type(8))) short short8;
typedef __attribute__((ext_vector_type(4))) float floatx4;

#define MTOT    16384          // 4 * 64 * 64
#define PADIMG  (66 * 66)      // padded image pixels per batch
#define PADELEM (4 * PADIMG * 256)
#define PADB    ((size_t)PADELEM * 2)   // bytes, bf16 (multiple of 256 -> allocs contiguous)
#define WSTEP   (256 * 2304)

__device__ __forceinline__ float bf2f(u16 u) {
  union { unsigned int i; float f; } c; c.i = ((unsigned int)u) << 16; return c.f;
}
__device__ __forceinline__ u16 f2bf(float f) {
  union { float f; unsigned int i; } c; c.f = f;
  unsigned int r = c.i + 0x7FFFu + ((c.i >> 16) & 1u);
  return (u16)(r >> 16);
}

__device__ __forceinline__ void gl_lds16(const void* g, void* l) {
  __builtin_amdgcn_global_load_lds(
      (const __attribute__((address_space(1))) void*)g,
      (__attribute__((address_space(3))) void*)l, 16, 0, 0);
}

// BK=32 LDS slot (u16 units): 4 chunks/row, XOR with (row>>1)&3  [R4: 0 conflicts]
__device__ __forceinline__ int lds_slot32(int row, int q) {
  return row * 32 + ((q ^ ((row >> 1) & 3)) << 3);
}
// BK=64 LDS slot: 8 chunks/row, XOR with row&7  [R5: 0 conflicts]
__device__ __forceinline__ int lds_slot64(int row, int q) {
  return row * 64 + ((q ^ (row & 7)) << 3);
}
// fp8 BK=64 LDS byte slot: 64 B/row, 4x 16B chunks, XOR (row>>1)&3 (mirror of
// lds_slot32 geometry, byte units). quad&1 selects the 8B half of the chunk.
__device__ __forceinline__ int lds_slot8(int row, int ks, int quad) {
  return row * 64 + (((ks * 2 + (quad >> 1)) ^ ((row >> 1) & 3)) << 4) + (quad & 1) * 8;
}

// ---------------------------------------------------------------------------
// merged setup kernel (all regions disjoint):
//   blk < 2304          : pack conv3x3 weights via LDS transpose (coalesced).
//                         w 0..6 -> bf16 dst3; w 7,8 (dcn) -> fp8 x64 wf8.
//   blk < 2688 (384)    : pack 1x1 weights -> [128 zero-pad][256] x3
//                         (cls/ref heads pre-scaled by 1/64 for fp8 dcn)
//   blk < 3712 (1024)   : features NCHW fp32 -> bf16 padded NHWC interior
//   blk < 5012 (1300)   : zero halo rings of the 5 padded buffers
__global__ void setup_all(const float* __restrict__ cls_w, const float* __restrict__ reg_w,
                          const float* __restrict__ initw, const float* __restrict__ clsd,
                          const float* __restrict__ refd,
                          const float* __restrict__ iw, const float* __restrict__ cw,
                          const float* __restrict__ rw,
                          const float* __restrict__ features,
                          u16* __restrict__ dst3, u16* __restrict__ dst1,
                          u16* __restrict__ pads, u8* __restrict__ wf8) {
  int blk = blockIdx.x;
  int t = threadIdx.x;
  if (blk < 2304) {
    int w = blk >> 8;                         // 0..8
    int o = blk & 255;
    const float* src = (w < 3) ? cls_w + (size_t)w * WSTEP
                     : (w < 6) ? reg_w + (size_t)(w - 3) * WSTEP
                     : (w == 6) ? initw : (w == 7) ? clsd : refd;
    __shared__ float wl[2304];
    const float* so = src + (size_t)o * 2304;   // [c][kk] contiguous
    #pragma unroll
    for (int p = 0; p < 9; ++p) wl[p * 256 + t] = so[p * 256 + t];
    __syncthreads();
    if (w < 7) {
      u16* dw = dst3 + (size_t)w * WSTEP + (size_t)o * 2304;
      #pragma unroll
      for (int p = 0; p < 9; ++p)               // write [kk=p][c=t]
        dw[p * 256 + t] = f2bf(wl[t * 9 + p]);
    } else if (t < 128) {
      // dcn weights -> fp8 e4m3, scaled x64 (std 0.01 is subnormal in e4m3;
      // x64 restores normal range; heads are pre-divided by 64 below)
      u8* dw8 = wf8 + (size_t)(w - 7) * WSTEP + (size_t)o * 2304;
      #pragma unroll
      for (int p = 0; p < 9; ++p) {
        float f0 = wl[(2 * t) * 9 + p] * 64.f;
        float f1 = wl[(2 * t + 1) * 9 + p] * 64.f;
        int pk = __builtin_amdgcn_cvt_pk_fp8_f32(f0, f1, 0, false);
        *(u16*)(dw8 + p * 256 + 2 * t) = (u16)(pk & 0xFFFF);
      }
    }
  } else if (blk < 2688) {
    int bb = blk - 2304;                      // 0..383
    int wsel = bb >> 7;
    const float* src = wsel == 0 ? iw : wsel == 1 ? cw : rw;
    int nvalid = wsel == 1 ? 80 : 18;
    float scale = wsel == 0 ? 1.f : (1.f / 64.f);   // undo dcn fp8 x64
    int idx = (bb & 127) * 256 + t;
    int o = idx >> 8, c = idx & 255;
    dst1[(size_t)wsel * 32768 + idx] = f2bf(o < nvalid ? src[o * 256 + c] * scale : 0.f);
  } else if (blk < 3712) {
    __shared__ float tile[64][65];
    int bb = blk - 2688;                      // 0..1023
    int c0 = (bb & 3) * 64;
    int y  = (bb >> 2) & 63;
    int b  = bb >> 8;
    #pragma unroll
    for (int i = 0; i < 16; ++i) {
      int lin = t + i * 256; int c = lin >> 6, x = lin & 63;
      tile[c][x] = features[((b * 256 + c0 + c) * 64 + y) * 64 + x];
    }
    __syncthreads();
    #pragma unroll
    for (int i = 0; i < 16; ++i) {
      int lin = t + i * 256; int x = lin >> 6, c = lin & 63;
      pads[((b * 66 + y + 1) * 66 + (x + 1)) * 256 + c0 + c] = f2bf(tile[c][x]);
    }
  } else {
    int idx = (blk - 3712) * 256 + t;         // 0..332799 = 5*4*260*64
    int c4 = (idx & 63) << 2;
    int r = idx >> 6;
    int pix = r % 260;
    int ib = r / 260;                         // buf*4 + batch, 0..19
    int y, x;
    if (pix < 66)       { y = 0;  x = pix; }
    else if (pix < 132) { y = 65; x = pix - 66; }
    else if (pix < 196) { y = pix - 132 + 1; x = 0; }
    else                { y = pix - 196 + 1; x = 65; }
    size_t o = (((size_t)ib * PADIMG) + y * 66 + x) * 256 + c4;
    *(ushort4*)(pads + o) = (ushort4){0, 0, 0, 0};
  }
}

// ---------------------------------------------------------------------------
// paired GroupNorm apply: bf16 staging [2][M][256] + raw (s,s2) stats ->
// normalize+affine+relu -> padded bf16 NHWC per tower. grid 8192 x 256.
__global__ void __launch_bounds__(256)
gn_apply2(const u16* __restrict__ stage, const float2* __restrict__ st,
          const float* __restrict__ gwc, const float* __restrict__ gbc,
          const float* __restrict__ gwr, const float* __restrict__ gbr,
          u16* __restrict__ cdst, u16* __restrict__ rdst) {
  int tid = blockIdx.x * 256 + threadIdx.x;
  int tower = tid >> 20;
  int r = tid & 0xFFFFF;
  int m = r >> 6, c4 = (r & 63) << 2;
  ushort4 u = *(const ushort4*)(stage + ((size_t)tower << 22) + (size_t)m * 256 + c4);
  int b = m >> 12, p = m & 4095, y = p >> 6, x = p & 63;
  float2 ss = st[tower * 128 + b * 32 + (c4 >> 3)];
  float mu = ss.x * (1.f / 32768.f);
  float var = ss.y * (1.f / 32768.f) - mu * mu;
  float rinv = rsqrtf(var + 1e-5f);
  const float* gw = tower ? gwr : gwc;
  const float* gb = tower ? gbr : gbc;
  ushort4 o;
  o.x = f2bf(fmaxf((bf2f(u.x) - mu) * rinv * gw[c4 + 0] + gb[c4 + 0], 0.f));
  o.y = f2bf(fmaxf((bf2f(u.y) - mu) * rinv * gw[c4 + 1] + gb[c4 + 1], 0.f));
  o.z = f2bf(fmaxf((bf2f(u.z) - mu) * rinv * gw[c4 + 2] + gb[c4 + 2], 0.f));
  o.w = f2bf(fmaxf((bf2f(u.w) - mu) * rinv * gw[c4 + 3] + gb[c4 + 3], 0.f));
  u16* dst = tower ? rdst : cdst;
  *(ushort4*)(dst + ((size_t)((b * 66 + y + 1) * 66 + (x + 1)) * 256 + c4)) = o;
}

// ---------------------------------------------------------------------------
// bilinear sample, both towers -> fp8 adcn (A of the fp8 dcn GEMM).
// 16 lanes/pixel, 16 ch/lane. grid 2048: blk<1024 -> (featC,AC), else (featR,AR).
__global__ void __launch_bounds__(256)
dcn_sample2(const u16* __restrict__ featC, const u16* __restrict__ featR,
            const float* __restrict__ pts,
            u8* __restrict__ AC, u8* __restrict__ AR) {
  int blk = blockIdx.x;
  const u16* featpad = blk < 1024 ? featC : featR;
  u8* A = blk < 1024 ? AC : AR;
  int mblk = blk & 1023;
  int t = threadIdx.x;
  int m = mblk * 16 + (t >> 4);
  int l = t & 15;
  int b = m >> 12, p = m & 4095, y = p >> 6, x = p & 63;
  const float* pp = pts + (size_t)m * 18;
  const u16* fb = featpad + (size_t)b * PADIMG * 256 + l * 4;
  u8* am = A + (size_t)m * 2304 + l * 4;
  #pragma unroll
  for (int kk = 0; kk < 9; ++kk) {
    float py = (float)y + pp[2 * kk];
    float px = (float)x + pp[2 * kk + 1];
    float fy = floorf(py), fx = floorf(px);
    int y0 = (int)fy, x0 = (int)fx;
    float wy = py - fy, wx = px - fx;
    float w00 = (1.f - wy) * (1.f - wx), w01 = (1.f - wy) * wx;
    float w10 = wy * (1.f - wx), w11 = wy * wx;
    bool yok0 = (unsigned)y0 < 64u, yok1 = (unsigned)(y0 + 1) < 64u;
    bool xok0 = (unsigned)x0 < 64u, xok1 = (unsigned)(x0 + 1) < 64u;
    const u16* base = fb + ((y0 + 1) * 66 + (x0 + 1)) * 256;
    float r[16];
    #pragma unroll
    for (int i = 0; i < 16; ++i) r[i] = 0.f;
    if (yok0 & xok0) {
      #pragma unroll
      for (int c = 0; c < 4; ++c) { ushort4 v = *(const ushort4*)(base + c * 64);
        r[c*4+0] += w00 * bf2f(v.x); r[c*4+1] += w00 * bf2f(v.y);
        r[c*4+2] += w00 * bf2f(v.z); r[c*4+3] += w00 * bf2f(v.w); } }
    if (yok0 & xok1) {
      #pragma unroll
      for (int c = 0; c < 4; ++c) { ushort4 v = *(const ushort4*)(base + 256 + c * 64);
        r[c*4+0] += w01 * bf2f(v.x); r[c*4+1] += w01 * bf2f(v.y);
        r[c*4+2] += w01 * bf2f(v.z); r[c*4+3] += w01 * bf2f(v.w); } }
    if (yok1 & xok0) {
      #pragma unroll
      for (int c = 0; c < 4; ++c) { ushort4 v = *(const ushort4*)(base + 66 * 256 + c * 64);
        r[c*4+0] += w10 * bf2f(v.x); r[c*4+1] += w10 * bf2f(v.y);
        r[c*4+2] += w10 * bf2f(v.z); r[c*4+3] += w10 * bf2f(v.w); } }
    if (yok1 & xok1) {
      #pragma unroll
      for (int c = 0; c < 4; ++c) { ushort4 v = *(const ushort4*)(base + 67 * 256 + c * 64);
        r[c*4+0] += w11 * bf2f(v.x); r[c*4+1] += w11 * bf2f(v.y);
        r[c*4+2] += w11 * bf2f(v.z); r[c*4+3] += w11 * bf2f(v.w); } }
    #pragma unroll
    for (int c = 0; c < 4; ++c) {
      int pk = __builtin_amdgcn_cvt_pk_fp8_f32(r[c*4+0], r[c*4+1], 0, false);
      pk = __builtin_amdgcn_cvt_pk_fp8_f32(r[c*4+2], r[c*4+3], pk, true);
      *(int*)(am + kk * 256 + c * 64) = pk;
    }
  }
}

// ---------------------------------------------------------------------------
// GEMM: C[M,N] = A[M,K] * W[N,K]^T.  128xBN tile, BK in {32,64}, 4 waves.
// [R6-verified source, single-buffer K-loop. R7-R9 pipelining variants all
//  regressed or were neutral; R10 cooperative GN fusion raced — reverted.]
// Block decode: [NPAIR==2: pair=blk&1, blk>>=1]  bm=blk&127, bn=blk>>7.
// AMODE 0: flat A; AMODE 1: implicit conv3x3.
// FP8 1 (BK=64, AMODE0 only): A/W are fp8 e4m3 bytes, KSZ elems == bytes.
//   Staging mirrors the verified BK32 geometry in byte units; ds_read_b64
//   fragments; mfma_f32_16x16x32_fp8_fp8. Halves LDS traffic (the measured
//   binding resource: 12 b128/K-step vs 16 MFMA).
// EP 0: bf16 staging + GN (s,s2) atomics; EP 1: +bias,relu; EP 2: relu;
// EP 3: +bias (+addpts) (+ptsout) -> fp32 NCHW d_out slice at cb, gn < nv.
template <int AMODE, int EP, int KSZ, int BN, int BK, int NPAIR, int FP8 = 0>
__global__ void __launch_bounds__(256)
gemm_kernel(const u16* __restrict__ A0, const u16* __restrict__ A1,
            const u16* __restrict__ W0, const u16* __restrict__ W1,
            const float* __restrict__ bias0, const float* __restrict__ bias1,
            u16* __restrict__ outb0, u16* __restrict__ outb1,
            float2* __restrict__ st0, float2* __restrict__ st1,
            float* __restrict__ outf,
            const float* __restrict__ addpts0, const float* __restrict__ addpts1,
            float* __restrict__ ptsout0, float* __restrict__ ptsout1,
            int nv0, int nv1, int cb0, int cb1) {
  constexpr int NJ = BN / 32;                 // 16-col accum tiles per wave
  __shared__ u16 As[128 * BK];
  __shared__ u16 Bs[BN * BK];
  int t = threadIdx.x;
  int blk = blockIdx.x;
  int pair = 0;
  if constexpr (NPAIR == 2) { pair = blk & 1; blk >>= 1; }
  const u16* A        = pair ? A1 : A0;
  const u16* Wp       = pair ? W1 : W0;
  const float* bias   = pair ? bias1 : bias0;
  u16* outb           = pair ? outb1 : outb0;
  float2* st          = pair ? st1 : st0;
  const float* addpts = pair ? addpts1 : addpts0;
  float* ptsout       = pair ? ptsout1 : ptsout0;
  int nv = pair ? nv1 : nv0;
  int cb = pair ? cb1 : cb0;

  int bm = blk & 127, bn = blk >> 7;
  int lane = t & 63, wave = t >> 6;
  int wm = (wave & 1) << 6;
  int wn = (wave >> 1) * (BN / 2);
  int quad = lane >> 4, r16 = lane & 15;

  floatx4 acc[4][NJ];
  #pragma unroll
  for (int i = 0; i < 4; ++i)
    #pragma unroll
    for (int j = 0; j < NJ; ++j)
      acc[i][j] = (floatx4){0.f, 0.f, 0.f, 0.f};

  if constexpr (FP8 == 1) {
    // fp8 path (BK=64, AMODE0): rows of 64 B; 4x16B chunks XOR-swizzled like
    // the verified BK32 layout. A-tile 8 KB (2 halves of 64 rows), B 4 KB.
    u8* As8 = (u8*)As;
    u8* Bs8 = (u8*)Bs;
    const u8* A8 = (const u8*)A;
    const u8* W8 = (const u8*)Wp;
    int row = t >> 2;                     // 0..63
    int cq = (t & 3) ^ ((t >> 3) & 3);    // XOR-swizzled 16B chunk
    int m0 = bm * 128 + row, m1 = m0 + 64;
    int abase0 = m0 * KSZ + cq * 16;
    int abase1 = m1 * KSZ + cq * 16;
    const u8* wg8 = W8 + (size_t)(bn * BN + row) * KSZ + cq * 16;

    for (int s = 0; s < KSZ / 64; ++s) {
      int d = s * 64;
      gl_lds16(A8 + abase0 + d, As8 + t * 16);
      gl_lds16(A8 + abase1 + d, As8 + 4096 + t * 16);
      gl_lds16(wg8 + d, Bs8 + t * 16);
      __syncthreads();
      long af8[2][4], bf8[2][NJ];
      #pragma unroll
      for (int ks = 0; ks < 2; ++ks) {
        #pragma unroll
        for (int i = 0; i < 4; ++i)
          af8[ks][i] = *(const long*)&As8[lds_slot8(wm + i * 16 + r16, ks, quad)];
        #pragma unroll
        for (int j = 0; j < NJ; ++j)
          bf8[ks][j] = *(const long*)&Bs8[lds_slot8(wn + j * 16 + r16, ks, quad)];
      }
      #pragma unroll
      for (int ks = 0; ks < 2; ++ks)
        #pragma unroll
        for (int i = 0; i < 4; ++i)
          #pragma unroll
          for (int j = 0; j < NJ; ++j)
            acc[i][j] = __builtin_amdgcn_mfma_f32_16x16x32_fp8_fp8(af8[ks][i], bf8[ks][j], acc[i][j], 0, 0, 0);
      __syncthreads();
    }
  } else if constexpr (BK == 64) {
    // staging: 8 chunks/row; thread t covers (row = 32k + t>>3, slot = t&7)
    int sub = t >> 3;                 // 0..31
    int cq = (t & 7) ^ (sub & 7);     // XOR-swizzled global chunk for this slot
    int abase[4];
    #pragma unroll
    for (int k = 0; k < 4; ++k) {
      int m = bm * 128 + k * 32 + sub;
      if constexpr (AMODE == 1) {
        int b = m >> 12, p = m & 4095;
        abase[k] = ((b * 66 + (p >> 6)) * 66 + (p & 63)) * 256 + cq * 8;
      } else {
        abase[k] = m * KSZ + cq * 8;
      }
    }
    const u16* wg = Wp + (size_t)(bn * BN + sub) * KSZ + cq * 8;

    for (int s = 0; s < KSZ / 64; ++s) {
      int d;
      if constexpr (AMODE == 1) {
        int kk = s >> 2;                 // 0..8
        int c0 = (s & 3) << 6;           // 0..192
        int ky = kk / 3, kx = kk - ky * 3;
        d = ((ky * 66 + kx) << 8) + c0;
      } else {
        d = s * 64;
      }
      #pragma unroll
      for (int k = 0; k < 4; ++k)
        gl_lds16(A + abase[k] + d, &As[k * 2048 + t * 8]);
      #pragma unroll
      for (int k = 0; k < BN / 32; ++k)
        gl_lds16(wg + (size_t)(k * 32) * KSZ + s * 64, &Bs[k * 2048 + t * 8]);
      __syncthreads();
      short8 af[2][4], bfr[2][NJ];
      #pragma unroll
      for (int ks = 0; ks < 2; ++ks) {
        #pragma unroll
        for (int i = 0; i < 4; ++i)
          af[ks][i] = *(const short8*)&As[lds_slot64(wm + i * 16 + r16, ks * 4 + quad)];
        #pragma unroll
        for (int j = 0; j < NJ; ++j)
          bfr[ks][j] = *(const short8*)&Bs[lds_slot64(wn + j * 16 + r16, ks * 4 + quad)];
      }
      #pragma unroll
      for (int ks = 0; ks < 2; ++ks)
        #pragma unroll
        for (int i = 0; i < 4; ++i)
          #pragma unroll
          for (int j = 0; j < NJ; ++j)
            acc[i][j] = __builtin_amdgcn_mfma_f32_16x16x32_bf16(af[ks][i], bfr[ks][j], acc[i][j], 0, 0, 0);
      __syncthreads();
    }
  } else {
    // BK=32 path (R4-verified): 4 chunks/row
    int row = t >> 2;
    int chunkS = (t & 3) ^ ((t >> 3) & 3);
    int m0 = bm * 128 + row, m1 = m0 + 64;
    int abase0, abase1;
    if constexpr (AMODE == 1) {
      int b0 = m0 >> 12, p0 = m0 & 4095;
      int b1 = m1 >> 12, p1 = m1 & 4095;
      abase0 = ((b0 * 66 + (p0 >> 6)) * 66 + (p0 & 63)) * 256 + chunkS * 8;
      abase1 = ((b1 * 66 + (p1 >> 6)) * 66 + (p1 & 63)) * 256 + chunkS * 8;
    } else {
      abase0 = m0 * KSZ + chunkS * 8;
      abase1 = m1 * KSZ + chunkS * 8;
    }
    const u16* wg = Wp + (size_t)(bn * BN + row) * KSZ + chunkS * 8;

    for (int s = 0; s < KSZ / 32; ++s) {
      int d;
      if constexpr (AMODE == 1) {
        int kk = s >> 3;
        int c0 = (s & 7) << 5;
        int ky = kk / 3, kx = kk - ky * 3;
        d = ((ky * 66 + kx) << 8) + c0;
      } else {
        d = s * 32;
      }
      gl_lds16(A + abase0 + d, &As[t * 8]);
      gl_lds16(A + abase1 + d, &As[2048 + t * 8]);
      gl_lds16(wg + s * 32, &Bs[t * 8]);
      if constexpr (BN == 128)
        gl_lds16(wg + (size_t)64 * KSZ + s * 32, &Bs[2048 + t * 8]);
      __syncthreads();
      short8 af[4], bfr[NJ];
      #pragma unroll
      for (int i = 0; i < 4; ++i)
        af[i] = *(const short8*)&As[lds_slot32(wm + i * 16 + r16, quad)];
      #pragma unroll
      for (int j = 0; j < NJ; ++j)
        bfr[j] = *(const short8*)&Bs[lds_slot32(wn + j * 16 + r16, quad)];
      #pragma unroll
      for (int i = 0; i < 4; ++i)
        #pragma unroll
        for (int j = 0; j < NJ; ++j)
          acc[i][j] = __builtin_amdgcn_mfma_f32_16x16x32_bf16(af[i], bfr[j], acc[i][j], 0, 0, 0);
      __syncthreads();
    }
  }

  #pragma unroll
  for (int j = 0; j < NJ; ++j) {
    int gn = bn * BN + wn + j * 16 + r16;
    float s = 0.f, s2 = 0.f;
    #pragma unroll
    for (int i = 0; i < 4; ++i) {
      #pragma unroll
      for (int r = 0; r < 4; ++r) {
        int gm = bm * 128 + wm + i * 16 + quad * 4 + r;
        float v = acc[i][j][r];
        if constexpr (EP == 0) {
          outb[(size_t)gm * 256 + gn] = f2bf(v);
          s += v; s2 += v * v;
        } else if constexpr (EP == 1) {
          outb[(size_t)gm * 256 + gn] = f2bf(fmaxf(v + bias[gn], 0.f));
        } else if constexpr (EP == 2) {
          outb[(size_t)gm * 256 + gn] = f2bf(fmaxf(v, 0.f));
        } else {
          if (gn < nv) {
            v += bias[gn];
            if (addpts) v += addpts[(size_t)gm * 18 + gn];
            if (ptsout) ptsout[(size_t)gm * 18 + gn] = v;
            int bb = gm >> 12, p = gm & 4095;
            outf[(size_t)((bb * 116 + cb + gn) << 12) + p] = v;
          }
        }
      }
    }
    if constexpr (EP == 0) {
      // reduce lanes differing in bits {0,1,2,4,5}; keep bit3 (8-ch group)
      s += __shfl_xor(s, 1);  s2 += __shfl_xor(s2, 1);
      s += __shfl_xor(s, 2);  s2 += __shfl_xor(s2, 2);
      s += __shfl_xor(s, 4);  s2 += __shfl_xor(s2, 4);
      s += __shfl_xor(s, 16); s2 += __shfl_xor(s2, 16);
      s += __shfl_xor(s, 32); s2 += __shfl_xor(s2, 32);
      if ((lane & 55) == 0) {
        float2* sp = st + ((bm >> 5) * 32) + (gn >> 3);
        atomicAdd(&sp->x, s);
        atomicAdd(&sp->y, s2);
      }
    }
  }
}

// ---------------------------------------------------------------------------
extern "C" void kernel_launch(void* const* d_in, const int* in_sizes, int n_in,
                              void* d_out, int out_size, void* d_ws, size_t ws_size,
                              hipStream_t stream) {
  (void)in_sizes; (void)n_in; (void)out_size;
  const float* features    = (const float*)d_in[0];
  const float* cls_w       = (const float*)d_in[1];
  const float* reg_w       = (const float*)d_in[2];
  const float* cls_gn_w    = (const float*)d_in[3];
  const float* cls_gn_b    = (const float*)d_in[4];
  const float* reg_gn_w    = (const float*)d_in[5];
  const float* reg_gn_b    = (const float*)d_in[6];
  const float* init_conv_w = (const float*)d_in[7];
  const float* init_conv_b = (const float*)d_in[8];
  const float* init_out_w  = (const float*)d_in[9];
  const float* init_out_b  = (const float*)d_in[10];
  const float* cls_dcn_w   = (const float*)d_in[11];
  const float* cls_out_w   = (const float*)d_in[12];
  const float* cls_out_b   = (const float*)d_in[13];
  const float* ref_dcn_w   = (const float*)d_in[14];
  const float* ref_out_w   = (const float*)d_in[15];
  const float* ref_out_b   = (const float*)d_in[16];
  float* out = (float*)d_out;

  char* ws = (char*)d_ws;
  size_t off = 0;
  auto alloc = [&](size_t bytes) {
    char* p = ws + off;
    off += (bytes + 255) & ~(size_t)255;
    return p;
  };
  u16* wpack      = (u16*)alloc((size_t)9 * WSTEP * 2);
  u8*  wf8        = (u8*)alloc((size_t)2 * WSTEP);      // fp8 dcn weights x64
  u16* w1         = (u16*)alloc((size_t)3 * 32768 * 2);
  u16* xpad       = (u16*)alloc(PADB);     // 5 pads contiguous (PADB % 256 == 0)
  u16* cpadA      = (u16*)alloc(PADB);
  u16* cpadB      = (u16*)alloc(PADB);
  u16* rpadA      = (u16*)alloc(PADB);
  u16* rpadB      = (u16*)alloc(PADB);
  float* ptsbuf   = (float*)alloc((size_t)MTOT * 18 * 4);
  float2* statsAll= (float2*)alloc(3 * 256 * sizeof(float2));
  u16* initf      = (u16*)alloc((size_t)MTOT * 256 * 2);
  u16* dcnout     = (u16*)alloc((size_t)2 * MTOT * 256 * 2);
  // union region: cstage [2][M][256] bf16 (towers) then adcn [M][2304] fp8 (dcn)
  char* unionReg  = alloc((size_t)MTOT * 2304);
  u16* cstage     = (u16*)alloc(0);  // placed below; see note
  // cstage needs 2*M*256*2 = 16.8MB; unionReg is M*2304 = 37.7MB >= that.
  cstage          = (u16*)unionReg;
  u8* adcn        = (u8*)unionReg;
  u8* adcn2       = (u8*)alloc((size_t)MTOT * 2304);    // only used if ws allows
  bool paired_dcn = (off <= ws_size);

  (void)hipMemsetAsync(statsAll, 0, 3 * 256 * sizeof(float2), stream);
  setup_all<<<5012, 256, 0, stream>>>(cls_w, reg_w, init_conv_w, cls_dcn_w, ref_dcn_w,
                                      init_out_w, cls_out_w, ref_out_w, features,
                                      wpack, w1, xpad, wf8);

  // towers, paired (cls=pair0, reg=pair1): 3 layers of conv3x3+GN+relu
  // (R0-verified two-kernel flow: EP0 staging+stats, then gn_apply2)
  const u16* curC = xpad; const u16* curR = xpad;
  u16* nxtC = cpadA; u16* altC = cpadB;
  u16* nxtR = rpadA; u16* altR = rpadB;
  for (int i = 0; i < 3; ++i) {
    gemm_kernel<1, 0, 2304, 64, 64, 2><<<1024, 256, 0, stream>>>(
        curC, curR, wpack + (size_t)i * WSTEP, wpack + (size_t)(3 + i) * WSTEP,
        nullptr, nullptr, cstage, cstage + (size_t)MTOT * 256,
        statsAll + i * 256, statsAll + i * 256 + 128,
        nullptr, nullptr, nullptr, nullptr, nullptr, 0, 0, 0, 0);
    gn_apply2<<<8192, 256, 0, stream>>>(cstage, statsAll + i * 256,
        cls_gn_w + i * 256, cls_gn_b + i * 256, reg_gn_w + i * 256, reg_gn_b + i * 256,
        nxtC, nxtR);
    curC = nxtC; { u16* tmp = nxtC; nxtC = altC; altC = tmp; }
    curR = nxtR; { u16* tmp = nxtR; nxtR = altR; altR = tmp; }
  }
  const u16* cls_feat = curC;   // cpadA
  const u16* reg_feat = curR;   // rpadA

  // init branch: relu(conv3x3 + b) -> initf (bf16, accuracy-critical for pts_init).
  // BN=32 -> grid 1024 = 4 blk/CU (R5: fixed the 2 blk/CU latency floor)
  gemm_kernel<1, 1, 2304, 32, 64, 1><<<1024, 256, 0, stream>>>(
      reg_feat, nullptr, wpack + (size_t)6 * WSTEP, nullptr,
      init_conv_b, nullptr, initf, nullptr, nullptr, nullptr,
      nullptr, nullptr, nullptr, nullptr, nullptr, 0, 0, 0, 0);
  // 1x1 -> pts_init (out ch 80..97 + ptsbuf). BN=64 -> 256 blocks
  gemm_kernel<0, 3, 256, 64, 32, 1><<<256, 256, 0, stream>>>(
      initf, nullptr, w1, nullptr, init_out_b, nullptr,
      nullptr, nullptr, nullptr, nullptr, out,
      nullptr, nullptr, ptsbuf, nullptr, 18, 0, 80, 0);

  // dcn conv: fp8 A (sampled feats) x fp8 W (x64); heads pre-scaled 1/64.
  if (paired_dcn) {
    dcn_sample2<<<2048, 256, 0, stream>>>(cls_feat, reg_feat, ptsbuf, adcn, adcn2);
    gemm_kernel<0, 2, 2304, 64, 64, 2, 1><<<1024, 256, 0, stream>>>(
        (const u16*)adcn, (const u16*)adcn2, (const u16*)wf8, (const u16*)(wf8 + WSTEP),
        nullptr, nullptr, dcnout, dcnout + (size_t)MTOT * 256, nullptr, nullptr,
        nullptr, nullptr, nullptr, nullptr, nullptr, 0, 0, 0, 0);
  } else {
    dcn_sample2<<<1024, 256, 0, stream>>>(cls_feat, cls_feat, ptsbuf, adcn, adcn);
    gemm_kernel<0, 2, 2304, 64, 64, 1, 1><<<512, 256, 0, stream>>>(
        (const u16*)adcn, nullptr, (const u16*)wf8, nullptr,
        nullptr, nullptr, dcnout, nullptr, nullptr, nullptr,
        nullptr, nullptr, nullptr, nullptr, nullptr, 0, 0, 0, 0);
    dcn_sample2<<<1024, 256, 0, stream>>>(reg_feat, reg_feat, ptsbuf, adcn, adcn);
    gemm_kernel<0, 2, 2304, 64, 64, 1, 1><<<512, 256, 0, stream>>>(
        (const u16*)adcn, nullptr, (const u16*)(wf8 + WSTEP), nullptr,
        nullptr, nullptr, dcnout + (size_t)MTOT * 256, nullptr, nullptr, nullptr,
        nullptr, nullptr, nullptr, nullptr, nullptr, 0, 0, 0, 0);
  }

  // final heads, paired: cls (80 ch at 0), refine (18 ch at 98, + pts_init)
  gemm_kernel<0, 3, 256, 64, 32, 2><<<512, 256, 0, stream>>>(
      dcnout, dcnout + (size_t)MTOT * 256, w1 + 32768, w1 + 2 * 32768,
      cls_out_b, ref_out_b, nullptr, nullptr, nullptr, nullptr, out,
      nullptr, ptsbuf, nullptr, nullptr, 80, 18, 0, 98);
}

// Round 7
// 392.835 us; speedup vs baseline: 1.3952x; 1.1141x over previous
//
#include <hip/hip_runtime.h>

typedef unsigned short u16;
typedef unsigned char u8;
typedef __attribute__((ext_vector_type(8))) short short8;
typedef __attribute__((ext_vector_type(4))) float floatx4;
typedef __attribute__((ext_vector_type(2))) float floatx2;

#define MTOT    16384          // 4 * 64 * 64
#define PADIMG  (66 * 66)      // padded image pixels per batch
#define PADELEM (4 * PADIMG * 256)      // elems per pad buffer (bytes when fp8)
#define PADB    ((size_t)PADELEM * 2)   // bytes when bf16
#define WSTEP   (256 * 2304)

__device__ __forceinline__ float bf2f(u16 u) {
  union { unsigned int i; float f; } c; c.i = ((unsigned int)u) << 16; return c.f;
}
__device__ __forceinline__ u16 f2bf(float f) {
  union { float f; unsigned int i; } c; c.f = f;
  unsigned int r = c.i + 0x7FFFu + ((c.i >> 16) & 1u);
  return (u16)(r >> 16);
}

__device__ __forceinline__ void gl_lds16(const void* g, void* l) {
  __builtin_amdgcn_global_load_lds(
      (const __attribute__((address_space(1))) void*)g,
      (__attribute__((address_space(3))) void*)l, 16, 0, 0);
}

// BK=32 LDS slot (u16 units): 4 chunks/row, XOR with (row>>1)&3  [R4: 0 conflicts]
__device__ __forceinline__ int lds_slot32(int row, int q) {
  return row * 32 + ((q ^ ((row >> 1) & 3)) << 3);
}
// BK=64 LDS slot: 8 chunks/row, XOR with row&7  [R5: 0 conflicts]
__device__ __forceinline__ int lds_slot64(int row, int q) {
  return row * 64 + ((q ^ (row & 7)) << 3);
}
// fp8 BK=64 LDS byte slot: 64 B/row, 4x 16B chunks, XOR (row>>1)&3 (mirror of
// lds_slot32 geometry, byte units). quad&1 selects the 8B half of the chunk.
// [R6-verified on the fp8 dcn GEMM]
__device__ __forceinline__ int lds_slot8(int row, int ks, int quad) {
  return row * 64 + (((ks * 2 + (quad >> 1)) ^ ((row >> 1) & 3)) << 4) + (quad & 1) * 8;
}

// ---------------------------------------------------------------------------
// merged setup kernel (all regions disjoint):
//   blk < 2304          : pack conv3x3 weights via LDS transpose (coalesced).
//                         w==6 (init conv) -> bf16 dst3 (x1; pts-accuracy path);
//                         w 0..5 (towers) + 7,8 (dcn) -> fp8 x64 wf8
//                         (tower x64 absorbed by GN; dcn x64 undone in heads).
//   blk < 2688 (384)    : pack 1x1 weights -> [128 zero-pad][256] x3
//                         (cls/ref heads pre-scaled by 1/64 for fp8 dcn)
//   blk < 3712 (1024)   : features NCHW fp32 -> fp8 padded NHWC interior
//   blk < 5012 (1300)   : zero halo rings of the 5 fp8 padded buffers
//   blk < 5272 (260)    : zero halo ring of the bf16 reg pad (layer-2 copy)
__global__ void setup_all(const float* __restrict__ cls_w, const float* __restrict__ reg_w,
                          const float* __restrict__ initw, const float* __restrict__ clsd,
                          const float* __restrict__ refd,
                          const float* __restrict__ iw, const float* __restrict__ cw,
                          const float* __restrict__ rw,
                          const float* __restrict__ features,
                          u16* __restrict__ dst3, u16* __restrict__ dst1,
                          u8* __restrict__ pads8, u8* __restrict__ wf8,
                          u16* __restrict__ padbf) {
  int blk = blockIdx.x;
  int t = threadIdx.x;
  if (blk < 2304) {
    int w = blk >> 8;                         // 0..8
    int o = blk & 255;
    const float* src = (w < 3) ? cls_w + (size_t)w * WSTEP
                     : (w < 6) ? reg_w + (size_t)(w - 3) * WSTEP
                     : (w == 6) ? initw : (w == 7) ? clsd : refd;
    __shared__ float wl[2304];
    const float* so = src + (size_t)o * 2304;   // [c][kk] contiguous
    #pragma unroll
    for (int p = 0; p < 9; ++p) wl[p * 256 + t] = so[p * 256 + t];
    __syncthreads();
    if (w == 6) {
      u16* dw = dst3 + (size_t)o * 2304;
      #pragma unroll
      for (int p = 0; p < 9; ++p)               // write [kk=p][c=t]
        dw[p * 256 + t] = f2bf(wl[t * 9 + p]);
    } else if (t < 128) {
      // fp8 e4m3, scaled x64 (std 0.01 is subnormal in e4m3)
      int slot = (w < 6) ? w : (w - 1);         // towers 0..5, dcn 6,7
      u8* dw8 = wf8 + (size_t)slot * WSTEP + (size_t)o * 2304;
      #pragma unroll
      for (int p = 0; p < 9; ++p) {
        float f0 = wl[(2 * t) * 9 + p] * 64.f;
        float f1 = wl[(2 * t + 1) * 9 + p] * 64.f;
        int pk = __builtin_amdgcn_cvt_pk_fp8_f32(f0, f1, 0, false);
        *(u16*)(dw8 + p * 256 + 2 * t) = (u16)(pk & 0xFFFF);
      }
    }
  } else if (blk < 2688) {
    int bb = blk - 2304;                      // 0..383
    int wsel = bb >> 7;
    const float* src = wsel == 0 ? iw : wsel == 1 ? cw : rw;
    int nvalid = wsel == 1 ? 80 : 18;
    float scale = wsel == 0 ? 1.f : (1.f / 64.f);   // undo dcn fp8 x64
    int idx = (bb & 127) * 256 + t;
    int o = idx >> 8, c = idx & 255;
    dst1[(size_t)wsel * 32768 + idx] = f2bf(o < nvalid ? src[o * 256 + c] * scale : 0.f);
  } else if (blk < 3712) {
    __shared__ float tile[64][65];
    int bb = blk - 2688;                      // 0..1023
    int c0 = (bb & 3) * 64;
    int y  = (bb >> 2) & 63;
    int b  = bb >> 8;
    #pragma unroll
    for (int i = 0; i < 16; ++i) {
      int lin = t + i * 256; int c = lin >> 6, x = lin & 63;
      tile[c][x] = features[((b * 256 + c0 + c) * 64 + y) * 64 + x];
    }
    __syncthreads();
    #pragma unroll
    for (int i = 0; i < 8; ++i) {             // 2 fp8 per thread per iter
      int lin = t + i * 256;                  // 0..2047
      int x = lin >> 5, c2 = lin & 31;
      int pk = __builtin_amdgcn_cvt_pk_fp8_f32(tile[2 * c2][x], tile[2 * c2 + 1][x], 0, false);
      *(u16*)(pads8 + (size_t)((b * 66 + y + 1) * 66 + (x + 1)) * 256 + c0 + 2 * c2) = (u16)pk;
    }
  } else if (blk < 5012) {
    int idx = (blk - 3712) * 256 + t;         // 0..332799 = 5*4*260*64
    int c4 = (idx & 63) << 2;
    int r = idx >> 6;
    int pix = r % 260;
    int ib = r / 260;                         // buf*4 + batch, 0..19
    int y, x;
    if (pix < 66)       { y = 0;  x = pix; }
    else if (pix < 132) { y = 65; x = pix - 66; }
    else if (pix < 196) { y = pix - 132 + 1; x = 0; }
    else                { y = pix - 196 + 1; x = 65; }
    size_t o = (((size_t)ib * PADIMG) + y * 66 + x) * 256 + c4;
    *(unsigned int*)(pads8 + o) = 0u;
  } else {
    int idx = (blk - 5012) * 256 + t;         // 0..66559 = 4*260*64
    int c4 = (idx & 63) << 2;
    int r = idx >> 6;
    int pix = r % 260;
    int b = r / 260;                          // batch 0..3
    int y, x;
    if (pix < 66)       { y = 0;  x = pix; }
    else if (pix < 132) { y = 65; x = pix - 66; }
    else if (pix < 196) { y = pix - 132 + 1; x = 0; }
    else                { y = pix - 196 + 1; x = 65; }
    size_t o = (((size_t)b * PADIMG) + y * 66 + x) * 256 + c4;
    *(ushort4*)(padbf + o) = (ushort4){0, 0, 0, 0};
  }
}

// ---------------------------------------------------------------------------
// paired GroupNorm apply: bf16 staging [2][M][256] (values x64 from fp8 W;
// GN is scale-invariant) + raw (s,s2) stats -> normalize+affine+relu ->
// fp8 padded NHWC per tower; layer 2 also writes bf16 reg pad (rbf) for the
// bf16 init-conv (pts accuracy path). grid 8192 x 256.
__global__ void __launch_bounds__(256)
gn_apply2(const u16* __restrict__ stage, const float2* __restrict__ st,
          const float* __restrict__ gwc, const float* __restrict__ gbc,
          const float* __restrict__ gwr, const float* __restrict__ gbr,
          u8* __restrict__ cdst8, u8* __restrict__ rdst8, u16* __restrict__ rbf) {
  int tid = blockIdx.x * 256 + threadIdx.x;
  int tower = tid >> 20;
  int r = tid & 0xFFFFF;
  int m = r >> 6, c4 = (r & 63) << 2;
  ushort4 u = *(const ushort4*)(stage + ((size_t)tower << 22) + (size_t)m * 256 + c4);
  int b = m >> 12, p = m & 4095, y = p >> 6, x = p & 63;
  float2 ss = st[tower * 128 + b * 32 + (c4 >> 3)];
  float mu = ss.x * (1.f / 32768.f);
  float var = ss.y * (1.f / 32768.f) - mu * mu;
  float rinv = rsqrtf(var + 1e-5f);
  const float* gw = tower ? gwr : gwc;
  const float* gb = tower ? gbr : gbc;
  float v0 = fmaxf((bf2f(u.x) - mu) * rinv * gw[c4 + 0] + gb[c4 + 0], 0.f);
  float v1 = fmaxf((bf2f(u.y) - mu) * rinv * gw[c4 + 1] + gb[c4 + 1], 0.f);
  float v2 = fmaxf((bf2f(u.z) - mu) * rinv * gw[c4 + 2] + gb[c4 + 2], 0.f);
  float v3 = fmaxf((bf2f(u.w) - mu) * rinv * gw[c4 + 3] + gb[c4 + 3], 0.f);
  size_t pixo = (size_t)((b * 66 + y + 1) * 66 + (x + 1)) * 256 + c4;
  int pk = __builtin_amdgcn_cvt_pk_fp8_f32(v0, v1, 0, false);
  pk = __builtin_amdgcn_cvt_pk_fp8_f32(v2, v3, pk, true);
  *(int*)((tower ? rdst8 : cdst8) + pixo) = pk;
  if (tower && rbf) {
    ushort4 o;
    o.x = f2bf(v0); o.y = f2bf(v1); o.z = f2bf(v2); o.w = f2bf(v3);
    *(ushort4*)(rbf + pixo) = o;
  }
}

// ---------------------------------------------------------------------------
// bilinear sample, both towers: fp8 padded feats -> fp8 adcn.
// 16 lanes/pixel, 16 ch/lane. grid 2048: blk<1024 -> (featC,AC), else (featR,AR).
__global__ void __launch_bounds__(256)
dcn_sample2(const u8* __restrict__ featC, const u8* __restrict__ featR,
            const float* __restrict__ pts,
            u8* __restrict__ AC, u8* __restrict__ AR) {
  int blk = blockIdx.x;
  const u8* featpad = blk < 1024 ? featC : featR;
  u8* A = blk < 1024 ? AC : AR;
  int mblk = blk & 1023;
  int t = threadIdx.x;
  int m = mblk * 16 + (t >> 4);
  int l = t & 15;
  int b = m >> 12, p = m & 4095, y = p >> 6, x = p & 63;
  const float* pp = pts + (size_t)m * 18;
  const u8* fb = featpad + (size_t)b * PADIMG * 256 + l * 4;
  u8* am = A + (size_t)m * 2304 + l * 4;
  #pragma unroll
  for (int kk = 0; kk < 9; ++kk) {
    float py = (float)y + pp[2 * kk];
    float px = (float)x + pp[2 * kk + 1];
    float fy = floorf(py), fx = floorf(px);
    int y0 = (int)fy, x0 = (int)fx;
    float wy = py - fy, wx = px - fx;
    float w00 = (1.f - wy) * (1.f - wx), w01 = (1.f - wy) * wx;
    float w10 = wy * (1.f - wx), w11 = wy * wx;
    bool yok0 = (unsigned)y0 < 64u, yok1 = (unsigned)(y0 + 1) < 64u;
    bool xok0 = (unsigned)x0 < 64u, xok1 = (unsigned)(x0 + 1) < 64u;
    const u8* base = fb + ((y0 + 1) * 66 + (x0 + 1)) * 256;
    float r[16];
    #pragma unroll
    for (int i = 0; i < 16; ++i) r[i] = 0.f;
    #define ACCUM(OFF, W) { \
      _Pragma("unroll") \
      for (int c = 0; c < 4; ++c) { \
        unsigned int v = *(const unsigned int*)(base + (OFF) + c * 64); \
        floatx2 lo = __builtin_amdgcn_cvt_pk_f32_fp8(v, false); \
        floatx2 hi = __builtin_amdgcn_cvt_pk_f32_fp8(v, true); \
        r[c*4+0] += (W) * lo.x; r[c*4+1] += (W) * lo.y; \
        r[c*4+2] += (W) * hi.x; r[c*4+3] += (W) * hi.y; } }
    if (yok0 & xok0) ACCUM(0, w00)
    if (yok0 & xok1) ACCUM(256, w01)
    if (yok1 & xok0) ACCUM(66 * 256, w10)
    if (yok1 & xok1) ACCUM(67 * 256, w11)
    #undef ACCUM
    #pragma unroll
    for (int c = 0; c < 4; ++c) {
      int pk = __builtin_amdgcn_cvt_pk_fp8_f32(r[c*4+0], r[c*4+1], 0, false);
      pk = __builtin_amdgcn_cvt_pk_fp8_f32(r[c*4+2], r[c*4+3], pk, true);
      *(int*)(am + kk * 256 + c * 64) = pk;
    }
  }
}

// ---------------------------------------------------------------------------
// GEMM: C[M,N] = A[M,K] * W[N,K]^T.  128xBN tile, BK in {32,64}, 4 waves.
// [R6-verified source, single-buffer K-loop. R7-R9 pipelining variants all
//  regressed or were neutral; R10 cooperative GN fusion raced — reverted.]
// Block decode: [NPAIR==2: pair=blk&1, blk>>=1]  bm=blk&127, bn=blk>>7.
// AMODE 0: flat A; AMODE 1: implicit conv3x3 (pads NHWC).
// FP8 1 (BK=64): A/W fp8 e4m3 bytes, KSZ elems == bytes. Staging mirrors the
//   verified BK32 geometry in byte units; ds_read_b64 fragments;
//   mfma_f32_16x16x32_fp8_fp8 (bf16 rate, half the LDS bytes — the measured
//   binding resource). AMODE1 variant: pixel stride 256 B. [R6: fp8+AMODE0 ok]
// EP 0: bf16 staging + GN (s,s2) atomics; EP 1: +bias,relu; EP 2: relu;
// EP 3: +bias (+addpts) (+ptsout) -> fp32 NCHW d_out slice at cb, gn < nv.
template <int AMODE, int EP, int KSZ, int BN, int BK, int NPAIR, int FP8 = 0>
__global__ void __launch_bounds__(256)
gemm_kernel(const u16* __restrict__ A0, const u16* __restrict__ A1,
            const u16* __restrict__ W0, const u16* __restrict__ W1,
            const float* __restrict__ bias0, const float* __restrict__ bias1,
            u16* __restrict__ outb0, u16* __restrict__ outb1,
            float2* __restrict__ st0, float2* __restrict__ st1,
            float* __restrict__ outf,
            const float* __restrict__ addpts0, const float* __restrict__ addpts1,
            float* __restrict__ ptsout0, float* __restrict__ ptsout1,
            int nv0, int nv1, int cb0, int cb1) {
  constexpr int NJ = BN / 32;                 // 16-col accum tiles per wave
  __shared__ u16 As[128 * BK];
  __shared__ u16 Bs[BN * BK];
  int t = threadIdx.x;
  int blk = blockIdx.x;
  int pair = 0;
  if constexpr (NPAIR == 2) { pair = blk & 1; blk >>= 1; }
  const u16* A        = pair ? A1 : A0;
  const u16* Wp       = pair ? W1 : W0;
  const float* bias   = pair ? bias1 : bias0;
  u16* outb           = pair ? outb1 : outb0;
  float2* st          = pair ? st1 : st0;
  const float* addpts = pair ? addpts1 : addpts0;
  float* ptsout       = pair ? ptsout1 : ptsout0;
  int nv = pair ? nv1 : nv0;
  int cb = pair ? cb1 : cb0;

  int bm = blk & 127, bn = blk >> 7;
  int lane = t & 63, wave = t >> 6;
  int wm = (wave & 1) << 6;
  int wn = (wave >> 1) * (BN / 2);
  int quad = lane >> 4, r16 = lane & 15;

  floatx4 acc[4][NJ];
  #pragma unroll
  for (int i = 0; i < 4; ++i)
    #pragma unroll
    for (int j = 0; j < NJ; ++j)
      acc[i][j] = (floatx4){0.f, 0.f, 0.f, 0.f};

  if constexpr (FP8 == 1) {
    // fp8 path (BK=64): rows of 64 B; 4x16B chunks XOR-swizzled like the
    // verified BK32 layout. A-tile 8 KB (2 halves of 64 rows), B 4 KB.
    u8* As8 = (u8*)As;
    u8* Bs8 = (u8*)Bs;
    const u8* A8 = (const u8*)A;
    const u8* W8 = (const u8*)Wp;
    int row = t >> 2;                     // 0..63
    int cq = (t & 3) ^ ((t >> 3) & 3);    // XOR-swizzled 16B chunk
    int m0 = bm * 128 + row, m1 = m0 + 64;
    int abase0, abase1;
    if constexpr (AMODE == 1) {
      int b0 = m0 >> 12, p0 = m0 & 4095;
      int b1 = m1 >> 12, p1 = m1 & 4095;
      abase0 = ((b0 * 66 + (p0 >> 6)) * 66 + (p0 & 63)) * 256 + cq * 16;
      abase1 = ((b1 * 66 + (p1 >> 6)) * 66 + (p1 & 63)) * 256 + cq * 16;
    } else {
      abase0 = m0 * KSZ + cq * 16;
      abase1 = m1 * KSZ + cq * 16;
    }
    const u8* wg8 = W8 + (size_t)(bn * BN + row) * KSZ + cq * 16;

    for (int s = 0; s < KSZ / 64; ++s) {
      int d;
      if constexpr (AMODE == 1) {
        int kk = s >> 2;                 // tap 0..8 (4 steps of 64 ch each)
        int c0 = (s & 3) << 6;           // byte offset within pixel
        int ky = kk / 3, kx = kk - ky * 3;
        d = ((ky * 66 + kx) << 8) + c0;
      } else {
        d = s * 64;
      }
      gl_lds16(A8 + abase0 + d, As8 + t * 16);
      gl_lds16(A8 + abase1 + d, As8 + 4096 + t * 16);
      gl_lds16(wg8 + s * 64, Bs8 + t * 16);
      __syncthreads();
      long af8[2][4], bf8[2][NJ];
      #pragma unroll
      for (int ks = 0; ks < 2; ++ks) {
        #pragma unroll
        for (int i = 0; i < 4; ++i)
          af8[ks][i] = *(const long*)&As8[lds_slot8(wm + i * 16 + r16, ks, quad)];
        #pragma unroll
        for (int j = 0; j < NJ; ++j)
          bf8[ks][j] = *(const long*)&Bs8[lds_slot8(wn + j * 16 + r16, ks, quad)];
      }
      #pragma unroll
      for (int ks = 0; ks < 2; ++ks)
        #pragma unroll
        for (int i = 0; i < 4; ++i)
          #pragma unroll
          for (int j = 0; j < NJ; ++j)
            acc[i][j] = __builtin_amdgcn_mfma_f32_16x16x32_fp8_fp8(af8[ks][i], bf8[ks][j], acc[i][j], 0, 0, 0);
      __syncthreads();
    }
  } else if constexpr (BK == 64) {
    // staging: 8 chunks/row; thread t covers (row = 32k + t>>3, slot = t&7)
    int sub = t >> 3;                 // 0..31
    int cq = (t & 7) ^ (sub & 7);     // XOR-swizzled global chunk for this slot
    int abase[4];
    #pragma unroll
    for (int k = 0; k < 4; ++k) {
      int m = bm * 128 + k * 32 + sub;
      if constexpr (AMODE == 1) {
        int b = m >> 12, p = m & 4095;
        abase[k] = ((b * 66 + (p >> 6)) * 66 + (p & 63)) * 256 + cq * 8;
      } else {
        abase[k] = m * KSZ + cq * 8;
      }
    }
    const u16* wg = Wp + (size_t)(bn * BN + sub) * KSZ + cq * 8;

    for (int s = 0; s < KSZ / 64; ++s) {
      int d;
      if constexpr (AMODE == 1) {
        int kk = s >> 2;                 // 0..8
        int c0 = (s & 3) << 6;           // 0..192
        int ky = kk / 3, kx = kk - ky * 3;
        d = ((ky * 66 + kx) << 8) + c0;
      } else {
        d = s * 64;
      }
      #pragma unroll
      for (int k = 0; k < 4; ++k)
        gl_lds16(A + abase[k] + d, &As[k * 2048 + t * 8]);
      #pragma unroll
      for (int k = 0; k < BN / 32; ++k)
        gl_lds16(wg + (size_t)(k * 32) * KSZ + s * 64, &Bs[k * 2048 + t * 8]);
      __syncthreads();
      short8 af[2][4], bfr[2][NJ];
      #pragma unroll
      for (int ks = 0; ks < 2; ++ks) {
        #pragma unroll
        for (int i = 0; i < 4; ++i)
          af[ks][i] = *(const short8*)&As[lds_slot64(wm + i * 16 + r16, ks * 4 + quad)];
        #pragma unroll
        for (int j = 0; j < NJ; ++j)
          bfr[ks][j] = *(const short8*)&Bs[lds_slot64(wn + j * 16 + r16, ks * 4 + quad)];
      }
      #pragma unroll
      for (int ks = 0; ks < 2; ++ks)
        #pragma unroll
        for (int i = 0; i < 4; ++i)
          #pragma unroll
          for (int j = 0; j < NJ; ++j)
            acc[i][j] = __builtin_amdgcn_mfma_f32_16x16x32_bf16(af[ks][i], bfr[ks][j], acc[i][j], 0, 0, 0);
      __syncthreads();
    }
  } else {
    // BK=32 path (R4-verified): 4 chunks/row
    int row = t >> 2;
    int chunkS = (t & 3) ^ ((t >> 3) & 3);
    int m0 = bm * 128 + row, m1 = m0 + 64;
    int abase0, abase1;
    if constexpr (AMODE == 1) {
      int b0 = m0 >> 12, p0 = m0 & 4095;
      int b1 = m1 >> 12, p1 = m1 & 4095;
      abase0 = ((b0 * 66 + (p0 >> 6)) * 66 + (p0 & 63)) * 256 + chunkS * 8;
      abase1 = ((b1 * 66 + (p1 >> 6)) * 66 + (p1 & 63)) * 256 + chunkS * 8;
    } else {
      abase0 = m0 * KSZ + chunkS * 8;
      abase1 = m1 * KSZ + chunkS * 8;
    }
    const u16* wg = Wp + (size_t)(bn * BN + row) * KSZ + chunkS * 8;

    for (int s = 0; s < KSZ / 32; ++s) {
      int d;
      if constexpr (AMODE == 1) {
        int kk = s >> 3;
        int c0 = (s & 7) << 5;
        int ky = kk / 3, kx = kk - ky * 3;
        d = ((ky * 66 + kx) << 8) + c0;
      } else {
        d = s * 32;
      }
      gl_lds16(A + abase0 + d, &As[t * 8]);
      gl_lds16(A + abase1 + d, &As[2048 + t * 8]);
      gl_lds16(wg + s * 32, &Bs[t * 8]);
      if constexpr (BN == 128)
        gl_lds16(wg + (size_t)64 * KSZ + s * 32, &Bs[2048 + t * 8]);
      __syncthreads();
      short8 af[4], bfr[NJ];
      #pragma unroll
      for (int i = 0; i < 4; ++i)
        af[i] = *(const short8*)&As[lds_slot32(wm + i * 16 + r16, quad)];
      #pragma unroll
      for (int j = 0; j < NJ; ++j)
        bfr[j] = *(const short8*)&Bs[lds_slot32(wn + j * 16 + r16, quad)];
      #pragma unroll
      for (int i = 0; i < 4; ++i)
        #pragma unroll
        for (int j = 0; j < NJ; ++j)
          acc[i][j] = __builtin_amdgcn_mfma_f32_16x16x32_bf16(af[i], bfr[j], acc[i][j], 0, 0, 0);
      __syncthreads();
    }
  }

  #pragma unroll
  for (int j = 0; j < NJ; ++j) {
    int gn = bn * BN + wn + j * 16 + r16;
    float s = 0.f, s2 = 0.f;
    #pragma unroll
    for (int i = 0; i < 4; ++i) {
      #pragma unroll
      for (int r = 0; r < 4; ++r) {
        int gm = bm * 128 + wm + i * 16 + quad * 4 + r;
        float v = acc[i][j][r];
        if constexpr (EP == 0) {
          outb[(size_t)gm * 256 + gn] = f2bf(v);
          s += v; s2 += v * v;
        } else if constexpr (EP == 1) {
          outb[(size_t)gm * 256 + gn] = f2bf(fmaxf(v + bias[gn], 0.f));
        } else if constexpr (EP == 2) {
          outb[(size_t)gm * 256 + gn] = f2bf(fmaxf(v, 0.f));
        } else {
          if (gn < nv) {
            v += bias[gn];
            if (addpts) v += addpts[(size_t)gm * 18 + gn];
            if (ptsout) ptsout[(size_t)gm * 18 + gn] = v;
            int bb = gm >> 12, p = gm & 4095;
            outf[(size_t)((bb * 116 + cb + gn) << 12) + p] = v;
          }
        }
      }
    }
    if constexpr (EP == 0) {
      // reduce lanes differing in bits {0,1,2,4,5}; keep bit3 (8-ch group)
      s += __shfl_xor(s, 1);  s2 += __shfl_xor(s2, 1);
      s += __shfl_xor(s, 2);  s2 += __shfl_xor(s2, 2);
      s += __shfl_xor(s, 4);  s2 += __shfl_xor(s2, 4);
      s += __shfl_xor(s, 16); s2 += __shfl_xor(s2, 16);
      s += __shfl_xor(s, 32); s2 += __shfl_xor(s2, 32);
      if ((lane & 55) == 0) {
        float2* sp = st + ((bm >> 5) * 32) + (gn >> 3);
        atomicAdd(&sp->x, s);
        atomicAdd(&sp->y, s2);
      }
    }
  }
}

// ---------------------------------------------------------------------------
extern "C" void kernel_launch(void* const* d_in, const int* in_sizes, int n_in,
                              void* d_out, int out_size, void* d_ws, size_t ws_size,
                              hipStream_t stream) {
  (void)in_sizes; (void)n_in; (void)out_size;
  const float* features    = (const float*)d_in[0];
  const float* cls_w       = (const float*)d_in[1];
  const float* reg_w       = (const float*)d_in[2];
  const float* cls_gn_w    = (const float*)d_in[3];
  const float* cls_gn_b    = (const float*)d_in[4];
  const float* reg_gn_w    = (const float*)d_in[5];
  const float* reg_gn_b    = (const float*)d_in[6];
  const float* init_conv_w = (const float*)d_in[7];
  const float* init_conv_b = (const float*)d_in[8];
  const float* init_out_w  = (const float*)d_in[9];
  const float* init_out_b  = (const float*)d_in[10];
  const float* cls_dcn_w   = (const float*)d_in[11];
  const float* cls_out_w   = (const float*)d_in[12];
  const float* cls_out_b   = (const float*)d_in[13];
  const float* ref_dcn_w   = (const float*)d_in[14];
  const float* ref_out_w   = (const float*)d_in[15];
  const float* ref_out_b   = (const float*)d_in[16];
  float* out = (float*)d_out;

  char* ws = (char*)d_ws;
  size_t off = 0;
  auto alloc = [&](size_t bytes) {
    char* p = ws + off;
    off += (bytes + 255) & ~(size_t)255;
    return p;
  };
  u16* wbf        = (u16*)alloc((size_t)WSTEP * 2);     // bf16 init-conv weights
  u8*  wf8        = (u8*)alloc((size_t)8 * WSTEP);      // fp8 x64: towers 0..5, dcn 6,7
  u16* w1         = (u16*)alloc((size_t)3 * 32768 * 2);
  // 5 fp8 pads contiguous (halo zeroing indexes across them)
  u8* xpad8       = (u8*)alloc(PADELEM);
  u8* cpadA8      = (u8*)alloc(PADELEM);
  u8* cpadB8      = (u8*)alloc(PADELEM);
  u8* rpadA8      = (u8*)alloc(PADELEM);
  u8* rpadB8      = (u8*)alloc(PADELEM);
  u16* rpadBF     = (u16*)alloc(PADB);                  // bf16 copy of final reg feats
  float* ptsbuf   = (float*)alloc((size_t)MTOT * 18 * 4);
  float2* statsAll= (float2*)alloc(3 * 256 * sizeof(float2));
  u16* initf      = (u16*)alloc((size_t)MTOT * 256 * 2);
  u16* dcnout     = (u16*)alloc((size_t)2 * MTOT * 256 * 2);
  // union region: cstage [2][M][256] bf16 (16.8MB) then adcn [M][2304] fp8 (37.7MB)
  char* unionReg  = alloc((size_t)MTOT * 2304);
  u16* cstage     = (u16*)unionReg;
  u8* adcn        = (u8*)unionReg;
  u8* adcn2       = (u8*)alloc((size_t)MTOT * 2304);    // only used if ws allows
  bool paired_dcn = (off <= ws_size);

  (void)hipMemsetAsync(statsAll, 0, 3 * 256 * sizeof(float2), stream);
  setup_all<<<5272, 256, 0, stream>>>(cls_w, reg_w, init_conv_w, cls_dcn_w, ref_dcn_w,
                                      init_out_w, cls_out_w, ref_out_w, features,
                                      wbf, w1, xpad8, wf8, rpadBF);

  // towers, paired (cls=pair0, reg=pair1): 3 layers of fp8 conv3x3 (+GN+relu).
  // fp8 W x64 absorbed by GN scale-invariance; layer 2 also emits bf16 reg pad.
  const u8* curC = xpad8; const u8* curR = xpad8;
  u8* nxtC = cpadA8; u8* altC = cpadB8;
  u8* nxtR = rpadA8; u8* altR = rpadB8;
  for (int i = 0; i < 3; ++i) {
    gemm_kernel<1, 0, 2304, 64, 64, 2, 1><<<1024, 256, 0, stream>>>(
        (const u16*)curC, (const u16*)curR,
        (const u16*)(wf8 + (size_t)i * WSTEP), (const u16*)(wf8 + (size_t)(3 + i) * WSTEP),
        nullptr, nullptr, cstage, cstage + (size_t)MTOT * 256,
        statsAll + i * 256, statsAll + i * 256 + 128,
        nullptr, nullptr, nullptr, nullptr, nullptr, 0, 0, 0, 0);
    gn_apply2<<<8192, 256, 0, stream>>>(cstage, statsAll + i * 256,
        cls_gn_w + i * 256, cls_gn_b + i * 256, reg_gn_w + i * 256, reg_gn_b + i * 256,
        nxtC, nxtR, (i == 2) ? rpadBF : nullptr);
    curC = nxtC; { u8* tmp = nxtC; nxtC = altC; altC = tmp; }
    curR = nxtR; { u8* tmp = nxtR; nxtR = altR; altR = tmp; }
  }
  const u8* cls_feat8 = curC;
  const u8* reg_feat8 = curR;

  // init branch: relu(conv3x3 + b) -> initf. Fully bf16 (pts accuracy path);
  // A = bf16 reg pad. BN=32 -> grid 1024 = 4 blk/CU (R5).
  gemm_kernel<1, 1, 2304, 32, 64, 1><<<1024, 256, 0, stream>>>(
      rpadBF, nullptr, wbf, nullptr,
      init_conv_b, nullptr, initf, nullptr, nullptr, nullptr,
      nullptr, nullptr, nullptr, nullptr, nullptr, 0, 0, 0, 0);
  // 1x1 -> pts_init (out ch 80..97 + ptsbuf). BN=64 -> 256 blocks
  gemm_kernel<0, 3, 256, 64, 32, 1><<<256, 256, 0, stream>>>(
      initf, nullptr, w1, nullptr, init_out_b, nullptr,
      nullptr, nullptr, nullptr, nullptr, out,
      nullptr, nullptr, ptsbuf, nullptr, 18, 0, 80, 0);

  // dcn conv: fp8 A (sampled fp8 feats) x fp8 W (x64); heads pre-scaled 1/64.
  if (paired_dcn) {
    dcn_sample2<<<2048, 256, 0, stream>>>(cls_feat8, reg_feat8, ptsbuf, adcn, adcn2);
    gemm_kernel<0, 2, 2304, 64, 64, 2, 1><<<1024, 256, 0, stream>>>(
        (const u16*)adcn, (const u16*)adcn2,
        (const u16*)(wf8 + (size_t)6 * WSTEP), (const u16*)(wf8 + (size_t)7 * WSTEP),
        nullptr, nullptr, dcnout, dcnout + (size_t)MTOT * 256, nullptr, nullptr,
        nullptr, nullptr, nullptr, nullptr, nullptr, 0, 0, 0, 0);
  } else {
    dcn_sample2<<<1024, 256, 0, stream>>>(cls_feat8, cls_feat8, ptsbuf, adcn, adcn);
    gemm_kernel<0, 2, 2304, 64, 64, 1, 1><<<512, 256, 0, stream>>>(
        (const u16*)adcn, nullptr, (const u16*)(wf8 + (size_t)6 * WSTEP), nullptr,
        nullptr, nullptr, dcnout, nullptr, nullptr, nullptr,
        nullptr, nullptr, nullptr, nullptr, nullptr, 0, 0, 0, 0);
    dcn_sample2<<<1024, 256, 0, stream>>>(reg_feat8, reg_feat8, ptsbuf, adcn, adcn);
    gemm_kernel<0, 2, 2304, 64, 64, 1, 1><<<512, 256, 0, stream>>>(
        (const u16*)adcn, nullptr, (const u16*)(wf8 + (size_t)7 * WSTEP), nullptr,
        nullptr, nullptr, dcnout + (size_t)MTOT * 256, nullptr, nullptr, nullptr,
        nullptr, nullptr, nullptr, nullptr, nullptr, 0, 0, 0, 0);
  }

  // final heads, paired: cls (80 ch at 0), refine (18 ch at 98, + pts_init)
  gemm_kernel<0, 3, 256, 64, 32, 2><<<512, 256, 0, stream>>>(
      dcnout, dcnout + (size_t)MTOT * 256, w1 + 32768, w1 + 2 * 32768,
      cls_out_b, ref_out_b, nullptr, nullptr, nullptr, nullptr, out,
      nullptr, ptsbuf, nullptr, nullptr, 80, 18, 0, 98);
}

// Round 8
// 378.090 us; speedup vs baseline: 1.4497x; 1.0390x over previous
//
#include <hip/hip_runtime.h>

typedef unsigned short u16;
typedef unsigned char u8;
typedef __attribute__((ext_vector_type(8))) short short8;
typedef __attribute__((ext_vector_type(4))) float floatx4;
typedef __attribute__((ext_vector_type(2))) float floatx2;
typedef __attribute__((ext_vector_type(2))) long longx2;

#define MTOT    16384          // 4 * 64 * 64
#define PADIMG  (66 * 66)      // padded image pixels per batch
#define PADELEM (4 * PADIMG * 256)      // elems per pad buffer (bytes when fp8)
#define PADB    ((size_t)PADELEM * 2)   // bytes when bf16
#define WSTEP   (256 * 2304)

__device__ __forceinline__ float bf2f(u16 u) {
  union { unsigned int i; float f; } c; c.i = ((unsigned int)u) << 16; return c.f;
}
__device__ __forceinline__ u16 f2bf(float f) {
  union { float f; unsigned int i; } c; c.f = f;
  unsigned int r = c.i + 0x7FFFu + ((c.i >> 16) & 1u);
  return (u16)(r >> 16);
}

__device__ __forceinline__ void gl_lds16(const void* g, void* l) {
  __builtin_amdgcn_global_load_lds(
      (const __attribute__((address_space(1))) void*)g,
      (__attribute__((address_space(3))) void*)l, 16, 0, 0);
}

// BK=32 LDS slot (u16 units): 4 chunks/row, XOR with (row>>1)&3  [R4: 0 conflicts]
__device__ __forceinline__ int lds_slot32(int row, int q) {
  return row * 32 + ((q ^ ((row >> 1) & 3)) << 3);
}
// BK=64 LDS slot: 8 chunks/row, XOR with row&7  [R5: 0 conflicts]
__device__ __forceinline__ int lds_slot64(int row, int q) {
  return row * 64 + ((q ^ (row & 7)) << 3);
}
// fp8 K-permuted BK=64 byte slot: one 16B chunk per (row, quad) holding BOTH
// ks fragments; byte-identical geometry to the verified lds_slot32 pattern.
// [R13: replaces lds_slot8 b64 pairs — those cost 7.08M bank conflicts/dispatch]
__device__ __forceinline__ int lds_slot8r(int row, int quad) {
  return row * 64 + ((quad ^ ((row >> 1) & 3)) << 4);
}
// K-permutation within each 64-channel group: original w = ks*32 + q*8 + j
// stored at pos = q*16 + ks*8 + j (so chunk quad = both ks fragments of quad).
// Applied identically to ALL fp8 operands -> dot products invariant.
__device__ __forceinline__ int permw(int w) {
  return ((w >> 3) & 3) * 16 + ((w >> 5) & 1) * 8 + (w & 7);
}

// ---------------------------------------------------------------------------
// merged setup kernel (all regions disjoint):
//   blk < 2304          : pack conv3x3 weights via LDS transpose (coalesced).
//                         w==6 (init conv) -> bf16 dst3 (pts-accuracy path);
//                         w 0..5 (towers) + 7,8 (dcn) -> fp8 x64 wf8, K-permuted
//   blk < 2688 (384)    : pack 1x1 weights -> [128 zero-pad][256] x3
//                         (cls/ref heads pre-scaled by 1/64 for fp8 dcn)
//   blk < 3712 (1024)   : features NCHW fp32 -> fp8 K-permuted padded NHWC
//   blk < 5012 (1300)   : zero halo rings of the 5 fp8 padded buffers
//   blk < 5272 (260)    : zero halo ring of the bf16 reg pad (layer-2 copy)
__global__ void setup_all(const float* __restrict__ cls_w, const float* __restrict__ reg_w,
                          const float* __restrict__ initw, const float* __restrict__ clsd,
                          const float* __restrict__ refd,
                          const float* __restrict__ iw, const float* __restrict__ cw,
                          const float* __restrict__ rw,
                          const float* __restrict__ features,
                          u16* __restrict__ dst3, u16* __restrict__ dst1,
                          u8* __restrict__ pads8, u8* __restrict__ wf8,
                          u16* __restrict__ padbf) {
  int blk = blockIdx.x;
  int t = threadIdx.x;
  if (blk < 2304) {
    int w = blk >> 8;                         // 0..8
    int o = blk & 255;
    const float* src = (w < 3) ? cls_w + (size_t)w * WSTEP
                     : (w < 6) ? reg_w + (size_t)(w - 3) * WSTEP
                     : (w == 6) ? initw : (w == 7) ? clsd : refd;
    __shared__ float wl[2304];
    const float* so = src + (size_t)o * 2304;   // [c][kk] contiguous
    #pragma unroll
    for (int p = 0; p < 9; ++p) wl[p * 256 + t] = so[p * 256 + t];
    __syncthreads();
    if (w == 6) {
      u16* dw = dst3 + (size_t)o * 2304;
      #pragma unroll
      for (int p = 0; p < 9; ++p)               // write [kk=p][c=t]
        dw[p * 256 + t] = f2bf(wl[t * 9 + p]);
    } else if (t < 128) {
      // fp8 e4m3, scaled x64 (std 0.01 is subnormal in e4m3), K-permuted
      int slot = (w < 6) ? w : (w - 1);         // towers 0..5, dcn 6,7
      u8* dw8 = wf8 + (size_t)slot * WSTEP + (size_t)o * 2304;
      int c = 2 * t;                            // 0..254
      int pos = (c & 192) + permw(c & 63);      // pair stays contiguous (j even)
      #pragma unroll
      for (int p = 0; p < 9; ++p) {
        float f0 = wl[c * 9 + p] * 64.f;
        float f1 = wl[(c + 1) * 9 + p] * 64.f;
        int pk = __builtin_amdgcn_cvt_pk_fp8_f32(f0, f1, 0, false);
        *(u16*)(dw8 + p * 256 + pos) = (u16)(pk & 0xFFFF);
      }
    }
  } else if (blk < 2688) {
    int bb = blk - 2304;                      // 0..383
    int wsel = bb >> 7;
    const float* src = wsel == 0 ? iw : wsel == 1 ? cw : rw;
    int nvalid = wsel == 1 ? 80 : 18;
    float scale = wsel == 0 ? 1.f : (1.f / 64.f);   // undo dcn fp8 x64
    int idx = (bb & 127) * 256 + t;
    int o = idx >> 8, c = idx & 255;
    dst1[(size_t)wsel * 32768 + idx] = f2bf(o < nvalid ? src[o * 256 + c] * scale : 0.f);
  } else if (blk < 3712) {
    __shared__ float tile[64][65];
    int bb = blk - 2688;                      // 0..1023
    int c0 = (bb & 3) * 64;
    int y  = (bb >> 2) & 63;
    int b  = bb >> 8;
    #pragma unroll
    for (int i = 0; i < 16; ++i) {
      int lin = t + i * 256; int c = lin >> 6, x = lin & 63;
      tile[c][x] = features[((b * 256 + c0 + c) * 64 + y) * 64 + x];
    }
    __syncthreads();
    #pragma unroll
    for (int i = 0; i < 8; ++i) {             // 2 fp8 per thread per iter
      int lin = t + i * 256;                  // 0..2047
      int x = lin >> 5, c2 = lin & 31;
      int pk = __builtin_amdgcn_cvt_pk_fp8_f32(tile[2 * c2][x], tile[2 * c2 + 1][x], 0, false);
      *(u16*)(pads8 + (size_t)((b * 66 + y + 1) * 66 + (x + 1)) * 256
              + c0 + permw(2 * c2)) = (u16)pk;
    }
  } else if (blk < 5012) {
    int idx = (blk - 3712) * 256 + t;         // 0..332799 = 5*4*260*64
    int c4 = (idx & 63) << 2;
    int r = idx >> 6;
    int pix = r % 260;
    int ib = r / 260;                         // buf*4 + batch, 0..19
    int y, x;
    if (pix < 66)       { y = 0;  x = pix; }
    else if (pix < 132) { y = 65; x = pix - 66; }
    else if (pix < 196) { y = pix - 132 + 1; x = 0; }
    else                { y = pix - 196 + 1; x = 65; }
    size_t o = (((size_t)ib * PADIMG) + y * 66 + x) * 256 + c4;
    *(unsigned int*)(pads8 + o) = 0u;
  } else {
    int idx = (blk - 5012) * 256 + t;         // 0..66559 = 4*260*64
    int c4 = (idx & 63) << 2;
    int r = idx >> 6;
    int pix = r % 260;
    int b = r / 260;                          // batch 0..3
    int y, x;
    if (pix < 66)       { y = 0;  x = pix; }
    else if (pix < 132) { y = 65; x = pix - 66; }
    else if (pix < 196) { y = pix - 132 + 1; x = 0; }
    else                { y = pix - 196 + 1; x = 65; }
    size_t o = (((size_t)b * PADIMG) + y * 66 + x) * 256 + c4;
    *(ushort4*)(padbf + o) = (ushort4){0, 0, 0, 0};
  }
}

// ---------------------------------------------------------------------------
// paired GroupNorm apply: bf16 staging [2][M][256] (values x64 from fp8 W;
// GN is scale-invariant) + raw (s,s2) stats -> normalize+affine+relu ->
// fp8 K-permuted padded NHWC per tower; layer 2 also writes bf16 reg pad
// (rbf, ORIGINAL channel order) for the bf16 init-conv. grid 8192 x 256.
__global__ void __launch_bounds__(256)
gn_apply2(const u16* __restrict__ stage, const float2* __restrict__ st,
          const float* __restrict__ gwc, const float* __restrict__ gbc,
          const float* __restrict__ gwr, const float* __restrict__ gbr,
          u8* __restrict__ cdst8, u8* __restrict__ rdst8, u16* __restrict__ rbf) {
  int tid = blockIdx.x * 256 + threadIdx.x;
  int tower = tid >> 20;
  int r = tid & 0xFFFFF;
  int m = r >> 6, c4 = (r & 63) << 2;
  ushort4 u = *(const ushort4*)(stage + ((size_t)tower << 22) + (size_t)m * 256 + c4);
  int b = m >> 12, p = m & 4095, y = p >> 6, x = p & 63;
  float2 ss = st[tower * 128 + b * 32 + (c4 >> 3)];
  float mu = ss.x * (1.f / 32768.f);
  float var = ss.y * (1.f / 32768.f) - mu * mu;
  float rinv = rsqrtf(var + 1e-5f);
  const float* gw = tower ? gwr : gwc;
  const float* gb = tower ? gbr : gbc;
  float v0 = fmaxf((bf2f(u.x) - mu) * rinv * gw[c4 + 0] + gb[c4 + 0], 0.f);
  float v1 = fmaxf((bf2f(u.y) - mu) * rinv * gw[c4 + 1] + gb[c4 + 1], 0.f);
  float v2 = fmaxf((bf2f(u.z) - mu) * rinv * gw[c4 + 2] + gb[c4 + 2], 0.f);
  float v3 = fmaxf((bf2f(u.w) - mu) * rinv * gw[c4 + 3] + gb[c4 + 3], 0.f);
  size_t pixbase = (size_t)((b * 66 + y + 1) * 66 + (x + 1)) * 256;
  int pk = __builtin_amdgcn_cvt_pk_fp8_f32(v0, v1, 0, false);
  pk = __builtin_amdgcn_cvt_pk_fp8_f32(v2, v3, pk, true);
  *(int*)((tower ? rdst8 : cdst8) + pixbase + (c4 & 192) + permw(c4 & 63)) = pk;
  if (tower && rbf) {
    ushort4 o;
    o.x = f2bf(v0); o.y = f2bf(v1); o.z = f2bf(v2); o.w = f2bf(v3);
    *(ushort4*)(rbf + pixbase + c4) = o;
  }
}

// ---------------------------------------------------------------------------
// bilinear sample, both towers: fp8 K-permuted feats -> fp8 adcn (position-
// preserving; bilinear is channel-agnostic, dcn weights use the same perm).
// 16 lanes/pixel, 16 ch/lane. grid 2048: blk<1024 -> (featC,AC), else (featR,AR).
__global__ void __launch_bounds__(256)
dcn_sample2(const u8* __restrict__ featC, const u8* __restrict__ featR,
            const float* __restrict__ pts,
            u8* __restrict__ AC, u8* __restrict__ AR) {
  int blk = blockIdx.x;
  const u8* featpad = blk < 1024 ? featC : featR;
  u8* A = blk < 1024 ? AC : AR;
  int mblk = blk & 1023;
  int t = threadIdx.x;
  int m = mblk * 16 + (t >> 4);
  int l = t & 15;
  int b = m >> 12, p = m & 4095, y = p >> 6, x = p & 63;
  const float* pp = pts + (size_t)m * 18;
  const u8* fb = featpad + (size_t)b * PADIMG * 256 + l * 4;
  u8* am = A + (size_t)m * 2304 + l * 4;
  #pragma unroll
  for (int kk = 0; kk < 9; ++kk) {
    float py = (float)y + pp[2 * kk];
    float px = (float)x + pp[2 * kk + 1];
    float fy = floorf(py), fx = floorf(px);
    int y0 = (int)fy, x0 = (int)fx;
    float wy = py - fy, wx = px - fx;
    float w00 = (1.f - wy) * (1.f - wx), w01 = (1.f - wy) * wx;
    float w10 = wy * (1.f - wx), w11 = wy * wx;
    bool yok0 = (unsigned)y0 < 64u, yok1 = (unsigned)(y0 + 1) < 64u;
    bool xok0 = (unsigned)x0 < 64u, xok1 = (unsigned)(x0 + 1) < 64u;
    const u8* base = fb + ((y0 + 1) * 66 + (x0 + 1)) * 256;
    float r[16];
    #pragma unroll
    for (int i = 0; i < 16; ++i) r[i] = 0.f;
    #define ACCUM(OFF, W) { \
      _Pragma("unroll") \
      for (int c = 0; c < 4; ++c) { \
        unsigned int v = *(const unsigned int*)(base + (OFF) + c * 64); \
        floatx2 lo = __builtin_amdgcn_cvt_pk_f32_fp8(v, false); \
        floatx2 hi = __builtin_amdgcn_cvt_pk_f32_fp8(v, true); \
        r[c*4+0] += (W) * lo.x; r[c*4+1] += (W) * lo.y; \
        r[c*4+2] += (W) * hi.x; r[c*4+3] += (W) * hi.y; } }
    if (yok0 & xok0) ACCUM(0, w00)
    if (yok0 & xok1) ACCUM(256, w01)
    if (yok1 & xok0) ACCUM(66 * 256, w10)
    if (yok1 & xok1) ACCUM(67 * 256, w11)
    #undef ACCUM
    #pragma unroll
    for (int c = 0; c < 4; ++c) {
      int pk = __builtin_amdgcn_cvt_pk_fp8_f32(r[c*4+0], r[c*4+1], 0, false);
      pk = __builtin_amdgcn_cvt_pk_fp8_f32(r[c*4+2], r[c*4+3], pk, true);
      *(int*)(am + kk * 256 + c * 64) = pk;
    }
  }
}

// ---------------------------------------------------------------------------
// GEMM: C[M,N] = A[M,K] * W[N,K]^T.  128xBN tile, BK in {32,64}, 4 waves.
// [R6-verified source, single-buffer K-loop. R7-R9 pipelining variants all
//  regressed or were neutral; R10 cooperative GN fusion raced — reverted.]
// Block decode: [NPAIR==2: pair=blk&1, blk>>=1]  bm=blk&127, bn=blk>>7.
// AMODE 0: flat A; AMODE 1: implicit conv3x3 (pads NHWC).
// FP8 1 (BK=64): A/W fp8 e4m3 bytes, K-PERMUTED per 64-group (permw), KSZ
//   elems == bytes. One ds_read_b128 per (row,quad) at the verified
//   lds_slot32 byte geometry delivers both ks fragments -> 0 bank conflicts
//   (the R7 lds_slot8 b64 pairs cost 7.08M conflicts/dispatch).
//   mfma_f32_16x16x32_fp8_fp8 (bf16 rate, half the LDS bytes).
// EP 0: bf16 staging + GN (s,s2) atomics; EP 1: +bias,relu; EP 2: relu;
// EP 3: +bias (+addpts) (+ptsout) -> fp32 NCHW d_out slice at cb, gn < nv.
template <int AMODE, int EP, int KSZ, int BN, int BK, int NPAIR, int FP8 = 0>
__global__ void __launch_bounds__(256)
gemm_kernel(const u16* __restrict__ A0, const u16* __restrict__ A1,
            const u16* __restrict__ W0, const u16* __restrict__ W1,
            const float* __restrict__ bias0, const float* __restrict__ bias1,
            u16* __restrict__ outb0, u16* __restrict__ outb1,
            float2* __restrict__ st0, float2* __restrict__ st1,
            float* __restrict__ outf,
            const float* __restrict__ addpts0, const float* __restrict__ addpts1,
            float* __restrict__ ptsout0, float* __restrict__ ptsout1,
            int nv0, int nv1, int cb0, int cb1) {
  constexpr int NJ = BN / 32;                 // 16-col accum tiles per wave
  __shared__ __align__(16) u16 As[128 * BK];
  __shared__ __align__(16) u16 Bs[BN * BK];
  int t = threadIdx.x;
  int blk = blockIdx.x;
  int pair = 0;
  if constexpr (NPAIR == 2) { pair = blk & 1; blk >>= 1; }
  const u16* A        = pair ? A1 : A0;
  const u16* Wp       = pair ? W1 : W0;
  const float* bias   = pair ? bias1 : bias0;
  u16* outb           = pair ? outb1 : outb0;
  float2* st          = pair ? st1 : st0;
  const float* addpts = pair ? addpts1 : addpts0;
  float* ptsout       = pair ? ptsout1 : ptsout0;
  int nv = pair ? nv1 : nv0;
  int cb = pair ? cb1 : cb0;

  int bm = blk & 127, bn = blk >> 7;
  int lane = t & 63, wave = t >> 6;
  int wm = (wave & 1) << 6;
  int wn = (wave >> 1) * (BN / 2);
  int quad = lane >> 4, r16 = lane & 15;

  floatx4 acc[4][NJ];
  #pragma unroll
  for (int i = 0; i < 4; ++i)
    #pragma unroll
    for (int j = 0; j < NJ; ++j)
      acc[i][j] = (floatx4){0.f, 0.f, 0.f, 0.f};

  if constexpr (FP8 == 1) {
    // fp8 path (BK=64): rows of 64 B; 4x16B chunks XOR-swizzled (verified
    // lds_slot32 geometry). A-tile 8 KB (2 halves of 64 rows), B 4 KB.
    u8* As8 = (u8*)As;
    u8* Bs8 = (u8*)Bs;
    const u8* A8 = (const u8*)A;
    const u8* W8 = (const u8*)Wp;
    int row = t >> 2;                     // 0..63
    int cq = (t & 3) ^ ((t >> 3) & 3);    // XOR-swizzled 16B chunk
    int m0 = bm * 128 + row, m1 = m0 + 64;
    int abase0, abase1;
    if constexpr (AMODE == 1) {
      int b0 = m0 >> 12, p0 = m0 & 4095;
      int b1 = m1 >> 12, p1 = m1 & 4095;
      abase0 = ((b0 * 66 + (p0 >> 6)) * 66 + (p0 & 63)) * 256 + cq * 16;
      abase1 = ((b1 * 66 + (p1 >> 6)) * 66 + (p1 & 63)) * 256 + cq * 16;
    } else {
      abase0 = m0 * KSZ + cq * 16;
      abase1 = m1 * KSZ + cq * 16;
    }
    const u8* wg8 = W8 + (size_t)(bn * BN + row) * KSZ + cq * 16;

    for (int s = 0; s < KSZ / 64; ++s) {
      int d;
      if constexpr (AMODE == 1) {
        int kk = s >> 2;                 // tap 0..8 (4 steps of 64 ch each)
        int c0 = (s & 3) << 6;           // byte offset within pixel (64-aligned:
        int ky = kk / 3, kx = kk - ky * 3;   //  matches the permw 64-groups)
        d = ((ky * 66 + kx) << 8) + c0;
      } else {
        d = s * 64;
      }
      gl_lds16(A8 + abase0 + d, As8 + t * 16);
      gl_lds16(A8 + abase1 + d, As8 + 4096 + t * 16);
      gl_lds16(wg8 + s * 64, Bs8 + t * 16);
      __syncthreads();
      long af8[2][4], bf8[2][NJ];
      #pragma unroll
      for (int i = 0; i < 4; ++i) {
        longx2 v = *(const longx2*)&As8[lds_slot8r(wm + i * 16 + r16, quad)];
        af8[0][i] = v.x; af8[1][i] = v.y;
      }
      #pragma unroll
      for (int j = 0; j < NJ; ++j) {
        longx2 v = *(const longx2*)&Bs8[lds_slot8r(wn + j * 16 + r16, quad)];
        bf8[0][j] = v.x; bf8[1][j] = v.y;
      }
      #pragma unroll
      for (int ks = 0; ks < 2; ++ks)
        #pragma unroll
        for (int i = 0; i < 4; ++i)
          #pragma unroll
          for (int j = 0; j < NJ; ++j)
            acc[i][j] = __builtin_amdgcn_mfma_f32_16x16x32_fp8_fp8(af8[ks][i], bf8[ks][j], acc[i][j], 0, 0, 0);
      __syncthreads();
    }
  } else if constexpr (BK == 64) {
    // staging: 8 chunks/row; thread t covers (row = 32k + t>>3, slot = t&7)
    int sub = t >> 3;                 // 0..31
    int cq = (t & 7) ^ (sub & 7);     // XOR-swizzled global chunk for this slot
    int abase[4];
    #pragma unroll
    for (int k = 0; k < 4; ++k) {
      int m = bm * 128 + k * 32 + sub;
      if constexpr (AMODE == 1) {
        int b = m >> 12, p = m & 4095;
        abase[k] = ((b * 66 + (p >> 6)) * 66 + (p & 63)) * 256 + cq * 8;
      } else {
        abase[k] = m * KSZ + cq * 8;
      }
    }
    const u16* wg = Wp + (size_t)(bn * BN + sub) * KSZ + cq * 8;

    for (int s = 0; s < KSZ / 64; ++s) {
      int d;
      if constexpr (AMODE == 1) {
        int kk = s >> 2;                 // 0..8
        int c0 = (s & 3) << 6;           // 0..192
        int ky = kk / 3, kx = kk - ky * 3;
        d = ((ky * 66 + kx) << 8) + c0;
      } else {
        d = s * 64;
      }
      #pragma unroll
      for (int k = 0; k < 4; ++k)
        gl_lds16(A + abase[k] + d, &As[k * 2048 + t * 8]);
      #pragma unroll
      for (int k = 0; k < BN / 32; ++k)
        gl_lds16(wg + (size_t)(k * 32) * KSZ + s * 64, &Bs[k * 2048 + t * 8]);
      __syncthreads();
      short8 af[2][4], bfr[2][NJ];
      #pragma unroll
      for (int ks = 0; ks < 2; ++ks) {
        #pragma unroll
        for (int i = 0; i < 4; ++i)
          af[ks][i] = *(const short8*)&As[lds_slot64(wm + i * 16 + r16, ks * 4 + quad)];
        #pragma unroll
        for (int j = 0; j < NJ; ++j)
          bfr[ks][j] = *(const short8*)&Bs[lds_slot64(wn + j * 16 + r16, ks * 4 + quad)];
      }
      #pragma unroll
      for (int ks = 0; ks < 2; ++ks)
        #pragma unroll
        for (int i = 0; i < 4; ++i)
          #pragma unroll
          for (int j = 0; j < NJ; ++j)
            acc[i][j] = __builtin_amdgcn_mfma_f32_16x16x32_bf16(af[ks][i], bfr[ks][j], acc[i][j], 0, 0, 0);
      __syncthreads();
    }
  } else {
    // BK=32 path (R4-verified): 4 chunks/row
    int row = t >> 2;
    int chunkS = (t & 3) ^ ((t >> 3) & 3);
    int m0 = bm * 128 + row, m1 = m0 + 64;
    int abase0, abase1;
    if constexpr (AMODE == 1) {
      int b0 = m0 >> 12, p0 = m0 & 4095;
      int b1 = m1 >> 12, p1 = m1 & 4095;
      abase0 = ((b0 * 66 + (p0 >> 6)) * 66 + (p0 & 63)) * 256 + chunkS * 8;
      abase1 = ((b1 * 66 + (p1 >> 6)) * 66 + (p1 & 63)) * 256 + chunkS * 8;
    } else {
      abase0 = m0 * KSZ + chunkS * 8;
      abase1 = m1 * KSZ + chunkS * 8;
    }
    const u16* wg = Wp + (size_t)(bn * BN + row) * KSZ + chunkS * 8;

    for (int s = 0; s < KSZ / 32; ++s) {
      int d;
      if constexpr (AMODE == 1) {
        int kk = s >> 3;
        int c0 = (s & 7) << 5;
        int ky = kk / 3, kx = kk - ky * 3;
        d = ((ky * 66 + kx) << 8) + c0;
      } else {
        d = s * 32;
      }
      gl_lds16(A + abase0 + d, &As[t * 8]);
      gl_lds16(A + abase1 + d, &As[2048 + t * 8]);
      gl_lds16(wg + s * 32, &Bs[t * 8]);
      if constexpr (BN == 128)
        gl_lds16(wg + (size_t)64 * KSZ + s * 32, &Bs[2048 + t * 8]);
      __syncthreads();
      short8 af[4], bfr[NJ];
      #pragma unroll
      for (int i = 0; i < 4; ++i)
        af[i] = *(const short8*)&As[lds_slot32(wm + i * 16 + r16, quad)];
      #pragma unroll
      for (int j = 0; j < NJ; ++j)
        bfr[j] = *(const short8*)&Bs[lds_slot32(wn + j * 16 + r16, quad)];
      #pragma unroll
      for (int i = 0; i < 4; ++i)
        #pragma unroll
        for (int j = 0; j < NJ; ++j)
          acc[i][j] = __builtin_amdgcn_mfma_f32_16x16x32_bf16(af[i], bfr[j], acc[i][j], 0, 0, 0);
      __syncthreads();
    }
  }

  #pragma unroll
  for (int j = 0; j < NJ; ++j) {
    int gn = bn * BN + wn + j * 16 + r16;
    float s = 0.f, s2 = 0.f;
    #pragma unroll
    for (int i = 0; i < 4; ++i) {
      #pragma unroll
      for (int r = 0; r < 4; ++r) {
        int gm = bm * 128 + wm + i * 16 + quad * 4 + r;
        float v = acc[i][j][r];
        if constexpr (EP == 0) {
          outb[(size_t)gm * 256 + gn] = f2bf(v);
          s += v; s2 += v * v;
        } else if constexpr (EP == 1) {
          outb[(size_t)gm * 256 + gn] = f2bf(fmaxf(v + bias[gn], 0.f));
        } else if constexpr (EP == 2) {
          outb[(size_t)gm * 256 + gn] = f2bf(fmaxf(v, 0.f));
        } else {
          if (gn < nv) {
            v += bias[gn];
            if (addpts) v += addpts[(size_t)gm * 18 + gn];
            if (ptsout) ptsout[(size_t)gm * 18 + gn] = v;
            int bb = gm >> 12, p = gm & 4095;
            outf[(size_t)((bb * 116 + cb + gn) << 12) + p] = v;
          }
        }
      }
    }
    if constexpr (EP == 0) {
      // reduce lanes differing in bits {0,1,2,4,5}; keep bit3 (8-ch group)
      s += __shfl_xor(s, 1);  s2 += __shfl_xor(s2, 1);
      s += __shfl_xor(s, 2);  s2 += __shfl_xor(s2, 2);
      s += __shfl_xor(s, 4);  s2 += __shfl_xor(s2, 4);
      s += __shfl_xor(s, 16); s2 += __shfl_xor(s2, 16);
      s += __shfl_xor(s, 32); s2 += __shfl_xor(s2, 32);
      if ((lane & 55) == 0) {
        float2* sp = st + ((bm >> 5) * 32) + (gn >> 3);
        atomicAdd(&sp->x, s);
        atomicAdd(&sp->y, s2);
      }
    }
  }
}

// ---------------------------------------------------------------------------
extern "C" void kernel_launch(void* const* d_in, const int* in_sizes, int n_in,
                              void* d_out, int out_size, void* d_ws, size_t ws_size,
                              hipStream_t stream) {
  (void)in_sizes; (void)n_in; (void)out_size;
  const float* features    = (const float*)d_in[0];
  const float* cls_w       = (const float*)d_in[1];
  const float* reg_w       = (const float*)d_in[2];
  const float* cls_gn_w    = (const float*)d_in[3];
  const float* cls_gn_b    = (const float*)d_in[4];
  const float* reg_gn_w    = (const float*)d_in[5];
  const float* reg_gn_b    = (const float*)d_in[6];
  const float* init_conv_w = (const float*)d_in[7];
  const float* init_conv_b = (const float*)d_in[8];
  const float* init_out_w  = (const float*)d_in[9];
  const float* init_out_b  = (const float*)d_in[10];
  const float* cls_dcn_w   = (const float*)d_in[11];
  const float* cls_out_w   = (const float*)d_in[12];
  const float* cls_out_b   = (const float*)d_in[13];
  const float* ref_dcn_w   = (const float*)d_in[14];
  const float* ref_out_w   = (const float*)d_in[15];
  const float* ref_out_b   = (const float*)d_in[16];
  float* out = (float*)d_out;

  char* ws = (char*)d_ws;
  size_t off = 0;
  auto alloc = [&](size_t bytes) {
    char* p = ws + off;
    off += (bytes + 255) & ~(size_t)255;
    return p;
  };
  u16* wbf        = (u16*)alloc((size_t)WSTEP * 2);     // bf16 init-conv weights
  u8*  wf8        = (u8*)alloc((size_t)8 * WSTEP);      // fp8 x64: towers 0..5, dcn 6,7
  u16* w1         = (u16*)alloc((size_t)3 * 32768 * 2);
  // 5 fp8 pads contiguous (halo zeroing indexes across them)
  u8* xpad8       = (u8*)alloc(PADELEM);
  u8* cpadA8      = (u8*)alloc(PADELEM);
  u8* cpadB8      = (u8*)alloc(PADELEM);
  u8* rpadA8      = (u8*)alloc(PADELEM);
  u8* rpadB8      = (u8*)alloc(PADELEM);
  u16* rpadBF     = (u16*)alloc(PADB);                  // bf16 copy of final reg feats
  float* ptsbuf   = (float*)alloc((size_t)MTOT * 18 * 4);
  float2* statsAll= (float2*)alloc(3 * 256 * sizeof(float2));
  u16* initf      = (u16*)alloc((size_t)MTOT * 256 * 2);
  u16* dcnout     = (u16*)alloc((size_t)2 * MTOT * 256 * 2);
  // union region: cstage [2][M][256] bf16 (16.8MB) then adcn [M][2304] fp8 (37.7MB)
  char* unionReg  = alloc((size_t)MTOT * 2304);
  u16* cstage     = (u16*)unionReg;
  u8* adcn        = (u8*)unionReg;
  u8* adcn2       = (u8*)alloc((size_t)MTOT * 2304);    // only used if ws allows
  bool paired_dcn = (off <= ws_size);

  (void)hipMemsetAsync(statsAll, 0, 3 * 256 * sizeof(float2), stream);
  setup_all<<<5272, 256, 0, stream>>>(cls_w, reg_w, init_conv_w, cls_dcn_w, ref_dcn_w,
                                      init_out_w, cls_out_w, ref_out_w, features,
                                      wbf, w1, xpad8, wf8, rpadBF);

  // towers, paired (cls=pair0, reg=pair1): 3 layers of fp8 conv3x3 (+GN+relu).
  // fp8 W x64 absorbed by GN scale-invariance; layer 2 also emits bf16 reg pad.
  const u8* curC = xpad8; const u8* curR = xpad8;
  u8* nxtC = cpadA8; u8* altC = cpadB8;
  u8* nxtR = rpadA8; u8* altR = rpadB8;
  for (int i = 0; i < 3; ++i) {
    gemm_kernel<1, 0, 2304, 64, 64, 2, 1><<<1024, 256, 0, stream>>>(
        (const u16*)curC, (const u16*)curR,
        (const u16*)(wf8 + (size_t)i * WSTEP), (const u16*)(wf8 + (size_t)(3 + i) * WSTEP),
        nullptr, nullptr, cstage, cstage + (size_t)MTOT * 256,
        statsAll + i * 256, statsAll + i * 256 + 128,
        nullptr, nullptr, nullptr, nullptr, nullptr, 0, 0, 0, 0);
    gn_apply2<<<8192, 256, 0, stream>>>(cstage, statsAll + i * 256,
        cls_gn_w + i * 256, cls_gn_b + i * 256, reg_gn_w + i * 256, reg_gn_b + i * 256,
        nxtC, nxtR, (i == 2) ? rpadBF : nullptr);
    curC = nxtC; { u8* tmp = nxtC; nxtC = altC; altC = tmp; }
    curR = nxtR; { u8* tmp = nxtR; nxtR = altR; altR = tmp; }
  }
  const u8* cls_feat8 = curC;
  const u8* reg_feat8 = curR;

  // init branch: relu(conv3x3 + b) -> initf. Fully bf16 (pts accuracy path);
  // A = bf16 reg pad. BN=32 -> grid 1024 = 4 blk/CU (R5).
  gemm_kernel<1, 1, 2304, 32, 64, 1><<<1024, 256, 0, stream>>>(
      rpadBF, nullptr, wbf, nullptr,
      init_conv_b, nullptr, initf, nullptr, nullptr, nullptr,
      nullptr, nullptr, nullptr, nullptr, nullptr, 0, 0, 0, 0);
  // 1x1 -> pts_init (out ch 80..97 + ptsbuf). BN=64 -> 256 blocks
  gemm_kernel<0, 3, 256, 64, 32, 1><<<256, 256, 0, stream>>>(
      initf, nullptr, w1, nullptr, init_out_b, nullptr,
      nullptr, nullptr, nullptr, nullptr, out,
      nullptr, nullptr, ptsbuf, nullptr, 18, 0, 80, 0);

  // dcn conv: fp8 A (sampled fp8 feats) x fp8 W (x64); heads pre-scaled 1/64.
  if (paired_dcn) {
    dcn_sample2<<<2048, 256, 0, stream>>>(cls_feat8, reg_feat8, ptsbuf, adcn, adcn2);
    gemm_kernel<0, 2, 2304, 64, 64, 2, 1><<<1024, 256, 0, stream>>>(
        (const u16*)adcn, (const u16*)adcn2,
        (const u16*)(wf8 + (size_t)6 * WSTEP), (const u16*)(wf8 + (size_t)7 * WSTEP),
        nullptr, nullptr, dcnout, dcnout + (size_t)MTOT * 256, nullptr, nullptr,
        nullptr, nullptr, nullptr, nullptr, nullptr, 0, 0, 0, 0);
  } else {
    dcn_sample2<<<1024, 256, 0, stream>>>(cls_feat8, cls_feat8, ptsbuf, adcn, adcn);
    gemm_kernel<0, 2, 2304, 64, 64, 1, 1><<<512, 256, 0, stream>>>(
        (const u16*)adcn, nullptr, (const u16*)(wf8 + (size_t)6 * WSTEP), nullptr,
        nullptr, nullptr, dcnout, nullptr, nullptr, nullptr,
        nullptr, nullptr, nullptr, nullptr, nullptr, 0, 0, 0, 0);
    dcn_sample2<<<1024, 256, 0, stream>>>(reg_feat8, reg_feat8, ptsbuf, adcn, adcn);
    gemm_kernel<0, 2, 2304, 64, 64, 1, 1><<<512, 256, 0, stream>>>(
        (const u16*)adcn, nullptr, (const u16*)(wf8 + (size_t)7 * WSTEP), nullptr,
        nullptr, nullptr, dcnout + (size_t)MTOT * 256, nullptr, nullptr, nullptr,
        nullptr, nullptr, nullptr, nullptr, nullptr, 0, 0, 0, 0);
  }

  // final heads, paired: cls (80 ch at 0), refine (18 ch at 98, + pts_init)
  gemm_kernel<0, 3, 256, 64, 32, 2><<<512, 256, 0, stream>>>(
      dcnout, dcnout + (size_t)MTOT * 256, w1 + 32768, w1 + 2 * 32768,
      cls_out_b, ref_out_b, nullptr, nullptr, nullptr, nullptr, out,
      nullptr, ptsbuf, nullptr, nullptr, 80, 18, 0, 98);
}

// Round 9
// 375.235 us; speedup vs baseline: 1.4607x; 1.0076x over previous
//
#include <hip/hip_runtime.h>

typedef unsigned short u16;
typedef unsigned char u8;
typedef __attribute__((ext_vector_type(8))) short short8;
typedef __attribute__((ext_vector_type(4))) float floatx4;
typedef __attribute__((ext_vector_type(2))) float floatx2;
typedef __attribute__((ext_vector_type(2))) long longx2;

#define MTOT    16384          // 4 * 64 * 64
#define PADIMG  (66 * 66)      // padded image pixels per batch
#define PADELEM (4 * PADIMG * 256)      // elems per pad buffer (bytes when fp8)
#define WSTEP   (256 * 2304)

__device__ __forceinline__ float bf2f(u16 u) {
  union { unsigned int i; float f; } c; c.i = ((unsigned int)u) << 16; return c.f;
}
__device__ __forceinline__ u16 f2bf(float f) {
  union { float f; unsigned int i; } c; c.f = f;
  unsigned int r = c.i + 0x7FFFu + ((c.i >> 16) & 1u);
  return (u16)(r >> 16);
}
__device__ __forceinline__ u8 f2fp8(float f) {
  return (u8)(__builtin_amdgcn_cvt_pk_fp8_f32(f, f, 0, false) & 0xFF);
}

__device__ __forceinline__ void gl_lds16(const void* g, void* l) {
  __builtin_amdgcn_global_load_lds(
      (const __attribute__((address_space(1))) void*)g,
      (__attribute__((address_space(3))) void*)l, 16, 0, 0);
}

// BK=32 LDS slot (u16 units): 4 chunks/row, XOR with (row>>1)&3  [R4: 0 conflicts]
__device__ __forceinline__ int lds_slot32(int row, int q) {
  return row * 32 + ((q ^ ((row >> 1) & 3)) << 3);
}
// BK=64 LDS slot: 8 chunks/row, XOR with row&7  [R5: 0 conflicts]
__device__ __forceinline__ int lds_slot64(int row, int q) {
  return row * 64 + ((q ^ (row & 7)) << 3);
}
// fp8 K-permuted BK=64 byte slot: one 16B chunk per (row, quad) holding BOTH
// ks fragments; byte-identical geometry to the verified lds_slot32 pattern.
// [R8-verified: 0 bank conflicts]
__device__ __forceinline__ int lds_slot8r(int row, int quad) {
  return row * 64 + ((quad ^ ((row >> 1) & 3)) << 4);
}
// K-permutation within each 64-channel group: original w = ks*32 + q*8 + j
// stored at pos = q*16 + ks*8 + j (so chunk quad = both ks fragments of quad).
// Applied identically to ALL fp8 operands -> dot products invariant.
__device__ __forceinline__ int permw(int w) {
  return ((w >> 3) & 3) * 16 + ((w >> 5) & 1) * 8 + (w & 7);
}

// ---------------------------------------------------------------------------
// merged setup kernel (all regions disjoint):
//   blk < 2304          : pack ALL conv3x3 weights -> fp8 x64, K-permuted.
//                         slots: towers 0..5, dcn 6..7, init-conv 8.
//   blk < 2688 (384)    : pack 1x1 weights -> [128 zero-pad][256] x3
//                         (cls/ref heads pre-scaled by 1/64 for fp8 dcn)
//   blk < 3712 (1024)   : features NCHW fp32 -> fp8 K-permuted padded NHWC
//   blk < 5012 (1300)   : zero halo rings of the 5 fp8 padded buffers
__global__ void setup_all(const float* __restrict__ cls_w, const float* __restrict__ reg_w,
                          const float* __restrict__ initw, const float* __restrict__ clsd,
                          const float* __restrict__ refd,
                          const float* __restrict__ iw, const float* __restrict__ cw,
                          const float* __restrict__ rw,
                          const float* __restrict__ features,
                          u16* __restrict__ dst1,
                          u8* __restrict__ pads8, u8* __restrict__ wf8) {
  int blk = blockIdx.x;
  int t = threadIdx.x;
  if (blk < 2304) {
    int w = blk >> 8;                         // 0..8
    int o = blk & 255;
    const float* src = (w < 3) ? cls_w + (size_t)w * WSTEP
                     : (w < 6) ? reg_w + (size_t)(w - 3) * WSTEP
                     : (w == 6) ? initw : (w == 7) ? clsd : refd;
    __shared__ float wl[2304];
    const float* so = src + (size_t)o * 2304;   // [c][kk] contiguous
    #pragma unroll
    for (int p = 0; p < 9; ++p) wl[p * 256 + t] = so[p * 256 + t];
    __syncthreads();
    if (t < 128) {
      // fp8 e4m3, scaled x64 (std 0.01 is subnormal in e4m3), K-permuted.
      // x64 absorbed by: GN (towers), 1/64 heads (dcn), 1/64 EP1 (init).
      int slot = (w < 6) ? w : (w == 6) ? 8 : (w - 1);
      u8* dw8 = wf8 + (size_t)slot * WSTEP + (size_t)o * 2304;
      int c = 2 * t;                            // 0..254
      int pos = (c & 192) + permw(c & 63);      // pair stays contiguous (j even)
      #pragma unroll
      for (int p = 0; p < 9; ++p) {
        float f0 = wl[c * 9 + p] * 64.f;
        float f1 = wl[(c + 1) * 9 + p] * 64.f;
        int pk = __builtin_amdgcn_cvt_pk_fp8_f32(f0, f1, 0, false);
        *(u16*)(dw8 + p * 256 + pos) = (u16)(pk & 0xFFFF);
      }
    }
  } else if (blk < 2688) {
    int bb = blk - 2304;                      // 0..383
    int wsel = bb >> 7;
    const float* src = wsel == 0 ? iw : wsel == 1 ? cw : rw;
    int nvalid = wsel == 1 ? 80 : 18;
    float scale = wsel == 0 ? 1.f : (1.f / 64.f);   // undo dcn fp8 x64
    int idx = (bb & 127) * 256 + t;
    int o = idx >> 8, c = idx & 255;
    dst1[(size_t)wsel * 32768 + idx] = f2bf(o < nvalid ? src[o * 256 + c] * scale : 0.f);
  } else if (blk < 3712) {
    __shared__ float tile[64][65];
    int bb = blk - 2688;                      // 0..1023
    int c0 = (bb & 3) * 64;
    int y  = (bb >> 2) & 63;
    int b  = bb >> 8;
    #pragma unroll
    for (int i = 0; i < 16; ++i) {
      int lin = t + i * 256; int c = lin >> 6, x = lin & 63;
      tile[c][x] = features[((b * 256 + c0 + c) * 64 + y) * 64 + x];
    }
    __syncthreads();
    #pragma unroll
    for (int i = 0; i < 8; ++i) {             // 2 fp8 per thread per iter
      int lin = t + i * 256;                  // 0..2047
      int x = lin >> 5, c2 = lin & 31;
      int pk = __builtin_amdgcn_cvt_pk_fp8_f32(tile[2 * c2][x], tile[2 * c2 + 1][x], 0, false);
      *(u16*)(pads8 + (size_t)((b * 66 + y + 1) * 66 + (x + 1)) * 256
              + c0 + permw(2 * c2)) = (u16)pk;
    }
  } else {
    int idx = (blk - 3712) * 256 + t;         // 0..332799 = 5*4*260*64
    int c4 = (idx & 63) << 2;
    int r = idx >> 6;
    int pix = r % 260;
    int ib = r / 260;                         // buf*4 + batch, 0..19
    int y, x;
    if (pix < 66)       { y = 0;  x = pix; }
    else if (pix < 132) { y = 65; x = pix - 66; }
    else if (pix < 196) { y = pix - 132 + 1; x = 0; }
    else                { y = pix - 196 + 1; x = 65; }
    size_t o = (((size_t)ib * PADIMG) + y * 66 + x) * 256 + c4;
    *(unsigned int*)(pads8 + o) = 0u;
  }
}

// ---------------------------------------------------------------------------
// paired GroupNorm apply: fp8 staging [2][M][256] bytes (values x64 from fp8
// W; GN is scale-invariant, stats computed fp32-exact in the GEMM) ->
// normalize+affine+relu -> fp8 K-permuted padded NHWC per tower. grid 8192.
__global__ void __launch_bounds__(256)
gn_apply2(const u8* __restrict__ stage, const float2* __restrict__ st,
          const float* __restrict__ gwc, const float* __restrict__ gbc,
          const float* __restrict__ gwr, const float* __restrict__ gbr,
          u8* __restrict__ cdst8, u8* __restrict__ rdst8) {
  int tid = blockIdx.x * 256 + threadIdx.x;
  int tower = tid >> 20;
  int r = tid & 0xFFFFF;
  int m = r >> 6, c4 = (r & 63) << 2;
  unsigned int v = *(const unsigned int*)(stage + ((size_t)tower << 22)
                                          + (size_t)m * 256 + c4);
  floatx2 lo = __builtin_amdgcn_cvt_pk_f32_fp8(v, false);
  floatx2 hi = __builtin_amdgcn_cvt_pk_f32_fp8(v, true);
  int b = m >> 12, p = m & 4095, y = p >> 6, x = p & 63;
  float2 ss = st[tower * 128 + b * 32 + (c4 >> 3)];
  float mu = ss.x * (1.f / 32768.f);
  float var = ss.y * (1.f / 32768.f) - mu * mu;
  float rinv = rsqrtf(var + 1e-5f);
  const float* gw = tower ? gwr : gwc;
  const float* gb = tower ? gbr : gbc;
  float v0 = fmaxf((lo.x - mu) * rinv * gw[c4 + 0] + gb[c4 + 0], 0.f);
  float v1 = fmaxf((lo.y - mu) * rinv * gw[c4 + 1] + gb[c4 + 1], 0.f);
  float v2 = fmaxf((hi.x - mu) * rinv * gw[c4 + 2] + gb[c4 + 2], 0.f);
  float v3 = fmaxf((hi.y - mu) * rinv * gw[c4 + 3] + gb[c4 + 3], 0.f);
  size_t pixbase = (size_t)((b * 66 + y + 1) * 66 + (x + 1)) * 256;
  int pk = __builtin_amdgcn_cvt_pk_fp8_f32(v0, v1, 0, false);
  pk = __builtin_amdgcn_cvt_pk_fp8_f32(v2, v3, pk, true);
  *(int*)((tower ? rdst8 : cdst8) + pixbase + (c4 & 192) + permw(c4 & 63)) = pk;
}

// ---------------------------------------------------------------------------
// bilinear sample, both towers: fp8 K-permuted feats -> fp8 adcn (position-
// preserving; bilinear is channel-agnostic, dcn weights use the same perm).
// 16 lanes/pixel, 16 ch/lane. grid 2048: blk<1024 -> (featC,AC), else (featR,AR).
__global__ void __launch_bounds__(256)
dcn_sample2(const u8* __restrict__ featC, const u8* __restrict__ featR,
            const float* __restrict__ pts,
            u8* __restrict__ AC, u8* __restrict__ AR) {
  int blk = blockIdx.x;
  const u8* featpad = blk < 1024 ? featC : featR;
  u8* A = blk < 1024 ? AC : AR;
  int mblk = blk & 1023;
  int t = threadIdx.x;
  int m = mblk * 16 + (t >> 4);
  int l = t & 15;
  int b = m >> 12, p = m & 4095, y = p >> 6, x = p & 63;
  const float* pp = pts + (size_t)m * 18;
  const u8* fb = featpad + (size_t)b * PADIMG * 256 + l * 4;
  u8* am = A + (size_t)m * 2304 + l * 4;
  #pragma unroll
  for (int kk = 0; kk < 9; ++kk) {
    float py = (float)y + pp[2 * kk];
    float px = (float)x + pp[2 * kk + 1];
    float fy = floorf(py), fx = floorf(px);
    int y0 = (int)fy, x0 = (int)fx;
    float wy = py - fy, wx = px - fx;
    float w00 = (1.f - wy) * (1.f - wx), w01 = (1.f - wy) * wx;
    float w10 = wy * (1.f - wx), w11 = wy * wx;
    bool yok0 = (unsigned)y0 < 64u, yok1 = (unsigned)(y0 + 1) < 64u;
    bool xok0 = (unsigned)x0 < 64u, xok1 = (unsigned)(x0 + 1) < 64u;
    const u8* base = fb + ((y0 + 1) * 66 + (x0 + 1)) * 256;
    float r[16];
    #pragma unroll
    for (int i = 0; i < 16; ++i) r[i] = 0.f;
    #define ACCUM(OFF, W) { \
      _Pragma("unroll") \
      for (int c = 0; c < 4; ++c) { \
        unsigned int v = *(const unsigned int*)(base + (OFF) + c * 64); \
        floatx2 lo = __builtin_amdgcn_cvt_pk_f32_fp8(v, false); \
        floatx2 hi = __builtin_amdgcn_cvt_pk_f32_fp8(v, true); \
        r[c*4+0] += (W) * lo.x; r[c*4+1] += (W) * lo.y; \
        r[c*4+2] += (W) * hi.x; r[c*4+3] += (W) * hi.y; } }
    if (yok0 & xok0) ACCUM(0, w00)
    if (yok0 & xok1) ACCUM(256, w01)
    if (yok1 & xok0) ACCUM(66 * 256, w10)
    if (yok1 & xok1) ACCUM(67 * 256, w11)
    #undef ACCUM
    #pragma unroll
    for (int c = 0; c < 4; ++c) {
      int pk = __builtin_amdgcn_cvt_pk_fp8_f32(r[c*4+0], r[c*4+1], 0, false);
      pk = __builtin_amdgcn_cvt_pk_fp8_f32(r[c*4+2], r[c*4+3], pk, true);
      *(int*)(am + kk * 256 + c * 64) = pk;
    }
  }
}

// ---------------------------------------------------------------------------
// GEMM: C[M,N] = A[M,K] * W[N,K]^T.  128xBN tile, BK in {32,64}, 4 waves.
// [R6-verified source, single-buffer K-loop; R8-verified fp8 K-perm path.]
// Block decode: [NPAIR==2: pair=blk&1, blk>>=1]  bm=blk&127, bn=blk>>7.
// AMODE 0: flat A; AMODE 1: implicit conv3x3 (pads NHWC).
// FP8 1 (BK=64): A/W fp8 e4m3 bytes, K-PERMUTED per 64-group (permw).
//   One ds_read_b128 per (row,quad) at the verified lds_slot32 byte geometry
//   -> 0 bank conflicts. mfma_f32_16x16x32_fp8_fp8 (bf16 rate, half bytes).
//   BN=32 supported (B staged by t<128 only; guards OOB weight reads).
// EP 0: fp8 staging + GN (s,s2) atomics (stats fp32-exact from acc);
// EP 1: +bias,relu -> bf16 (FP8: v/64 first, undoing weight x64);
// EP 2: relu -> bf16;
// EP 3: +bias (+addpts) (+ptsout) -> fp32 NCHW d_out slice at cb, gn < nv.
template <int AMODE, int EP, int KSZ, int BN, int BK, int NPAIR, int FP8 = 0>
__global__ void __launch_bounds__(256)
gemm_kernel(const u16* __restrict__ A0, const u16* __restrict__ A1,
            const u16* __restrict__ W0, const u16* __restrict__ W1,
            const float* __restrict__ bias0, const float* __restrict__ bias1,
            u16* __restrict__ outb0, u16* __restrict__ outb1,
            float2* __restrict__ st0, float2* __restrict__ st1,
            float* __restrict__ outf,
            const float* __restrict__ addpts0, const float* __restrict__ addpts1,
            float* __restrict__ ptsout0, float* __restrict__ ptsout1,
            int nv0, int nv1, int cb0, int cb1) {
  constexpr int NJ = BN / 32;                 // 16-col accum tiles per wave
  __shared__ __align__(16) u16 As[128 * BK];
  __shared__ __align__(16) u16 Bs[BN * BK];
  int t = threadIdx.x;
  int blk = blockIdx.x;
  int pair = 0;
  if constexpr (NPAIR == 2) { pair = blk & 1; blk >>= 1; }
  const u16* A        = pair ? A1 : A0;
  const u16* Wp       = pair ? W1 : W0;
  const float* bias   = pair ? bias1 : bias0;
  u16* outb           = pair ? outb1 : outb0;
  float2* st          = pair ? st1 : st0;
  const float* addpts = pair ? addpts1 : addpts0;
  float* ptsout       = pair ? ptsout1 : ptsout0;
  int nv = pair ? nv1 : nv0;
  int cb = pair ? cb1 : cb0;

  int bm = blk & 127, bn = blk >> 7;
  int lane = t & 63, wave = t >> 6;
  int wm = (wave & 1) << 6;
  int wn = (wave >> 1) * (BN / 2);
  int quad = lane >> 4, r16 = lane & 15;

  floatx4 acc[4][NJ];
  #pragma unroll
  for (int i = 0; i < 4; ++i)
    #pragma unroll
    for (int j = 0; j < NJ; ++j)
      acc[i][j] = (floatx4){0.f, 0.f, 0.f, 0.f};

  if constexpr (FP8 == 1) {
    // fp8 path (BK=64): rows of 64 B; 4x16B chunks XOR-swizzled (verified
    // lds_slot32 geometry). A-tile 8 KB (2 halves of 64 rows), B BN*64 B.
    u8* As8 = (u8*)As;
    u8* Bs8 = (u8*)Bs;
    const u8* A8 = (const u8*)A;
    const u8* W8 = (const u8*)Wp;
    int row = t >> 2;                     // 0..63
    int cq = (t & 3) ^ ((t >> 3) & 3);    // XOR-swizzled 16B chunk
    int m0 = bm * 128 + row, m1 = m0 + 64;
    int abase0, abase1;
    if constexpr (AMODE == 1) {
      int b0 = m0 >> 12, p0 = m0 & 4095;
      int b1 = m1 >> 12, p1 = m1 & 4095;
      abase0 = ((b0 * 66 + (p0 >> 6)) * 66 + (p0 & 63)) * 256 + cq * 16;
      abase1 = ((b1 * 66 + (p1 >> 6)) * 66 + (p1 & 63)) * 256 + cq * 16;
    } else {
      abase0 = m0 * KSZ + cq * 16;
      abase1 = m1 * KSZ + cq * 16;
    }
    const u8* wg8 = W8 + (size_t)(bn * BN + row) * KSZ + cq * 16;

    for (int s = 0; s < KSZ / 64; ++s) {
      int d;
      if constexpr (AMODE == 1) {
        int kk = s >> 2;                 // tap 0..8 (4 steps of 64 ch each)
        int c0 = (s & 3) << 6;           // byte offset within pixel (64-aligned:
        int ky = kk / 3, kx = kk - ky * 3;   //  matches the permw 64-groups)
        d = ((ky * 66 + kx) << 8) + c0;
      } else {
        d = s * 64;
      }
      gl_lds16(A8 + abase0 + d, As8 + t * 16);
      gl_lds16(A8 + abase1 + d, As8 + 4096 + t * 16);
      if (BN == 64 || t < 4 * BN)        // BN=32: rows 0..31 only (no OOB W)
        gl_lds16(wg8 + s * 64, Bs8 + t * 16);
      __syncthreads();
      long af8[2][4], bf8[2][NJ];
      #pragma unroll
      for (int i = 0; i < 4; ++i) {
        longx2 v = *(const longx2*)&As8[lds_slot8r(wm + i * 16 + r16, quad)];
        af8[0][i] = v.x; af8[1][i] = v.y;
      }
      #pragma unroll
      for (int j = 0; j < NJ; ++j) {
        longx2 v = *(const longx2*)&Bs8[lds_slot8r(wn + j * 16 + r16, quad)];
        bf8[0][j] = v.x; bf8[1][j] = v.y;
      }
      #pragma unroll
      for (int ks = 0; ks < 2; ++ks)
        #pragma unroll
        for (int i = 0; i < 4; ++i)
          #pragma unroll
          for (int j = 0; j < NJ; ++j)
            acc[i][j] = __builtin_amdgcn_mfma_f32_16x16x32_fp8_fp8(af8[ks][i], bf8[ks][j], acc[i][j], 0, 0, 0);
      __syncthreads();
    }
  } else if constexpr (BK == 64) {
    // staging: 8 chunks/row; thread t covers (row = 32k + t>>3, slot = t&7)
    int sub = t >> 3;                 // 0..31
    int cq = (t & 7) ^ (sub & 7);     // XOR-swizzled global chunk for this slot
    int abase[4];
    #pragma unroll
    for (int k = 0; k < 4; ++k) {
      int m = bm * 128 + k * 32 + sub;
      if constexpr (AMODE == 1) {
        int b = m >> 12, p = m & 4095;
        abase[k] = ((b * 66 + (p >> 6)) * 66 + (p & 63)) * 256 + cq * 8;
      } else {
        abase[k] = m * KSZ + cq * 8;
      }
    }
    const u16* wg = Wp + (size_t)(bn * BN + sub) * KSZ + cq * 8;

    for (int s = 0; s < KSZ / 64; ++s) {
      int d;
      if constexpr (AMODE == 1) {
        int kk = s >> 2;                 // 0..8
        int c0 = (s & 3) << 6;           // 0..192
        int ky = kk / 3, kx = kk - ky * 3;
        d = ((ky * 66 + kx) << 8) + c0;
      } else {
        d = s * 64;
      }
      #pragma unroll
      for (int k = 0; k < 4; ++k)
        gl_lds16(A + abase[k] + d, &As[k * 2048 + t * 8]);
      #pragma unroll
      for (int k = 0; k < BN / 32; ++k)
        gl_lds16(wg + (size_t)(k * 32) * KSZ + s * 64, &Bs[k * 2048 + t * 8]);
      __syncthreads();
      short8 af[2][4], bfr[2][NJ];
      #pragma unroll
      for (int ks = 0; ks < 2; ++ks) {
        #pragma unroll
        for (int i = 0; i < 4; ++i)
          af[ks][i] = *(const short8*)&As[lds_slot64(wm + i * 16 + r16, ks * 4 + quad)];
        #pragma unroll
        for (int j = 0; j < NJ; ++j)
          bfr[ks][j] = *(const short8*)&Bs[lds_slot64(wn + j * 16 + r16, ks * 4 + quad)];
      }
      #pragma unroll
      for (int ks = 0; ks < 2; ++ks)
        #pragma unroll
        for (int i = 0; i < 4; ++i)
          #pragma unroll
          for (int j = 0; j < NJ; ++j)
            acc[i][j] = __builtin_amdgcn_mfma_f32_16x16x32_bf16(af[ks][i], bfr[ks][j], acc[i][j], 0, 0, 0);
      __syncthreads();
    }
  } else {
    // BK=32 path (R4-verified): 4 chunks/row
    int row = t >> 2;
    int chunkS = (t & 3) ^ ((t >> 3) & 3);
    int m0 = bm * 128 + row, m1 = m0 + 64;
    int abase0, abase1;
    if constexpr (AMODE == 1) {
      int b0 = m0 >> 12, p0 = m0 & 4095;
      int b1 = m1 >> 12, p1 = m1 & 4095;
      abase0 = ((b0 * 66 + (p0 >> 6)) * 66 + (p0 & 63)) * 256 + chunkS * 8;
      abase1 = ((b1 * 66 + (p1 >> 6)) * 66 + (p1 & 63)) * 256 + chunkS * 8;
    } else {
      abase0 = m0 * KSZ + chunkS * 8;
      abase1 = m1 * KSZ + chunkS * 8;
    }
    const u16* wg = Wp + (size_t)(bn * BN + row) * KSZ + chunkS * 8;

    for (int s = 0; s < KSZ / 32; ++s) {
      int d;
      if constexpr (AMODE == 1) {
        int kk = s >> 3;
        int c0 = (s & 7) << 5;
        int ky = kk / 3, kx = kk - ky * 3;
        d = ((ky * 66 + kx) << 8) + c0;
      } else {
        d = s * 32;
      }
      gl_lds16(A + abase0 + d, &As[t * 8]);
      gl_lds16(A + abase1 + d, &As[2048 + t * 8]);
      gl_lds16(wg + s * 32, &Bs[t * 8]);
      if constexpr (BN == 128)
        gl_lds16(wg + (size_t)64 * KSZ + s * 32, &Bs[2048 + t * 8]);
      __syncthreads();
      short8 af[4], bfr[NJ];
      #pragma unroll
      for (int i = 0; i < 4; ++i)
        af[i] = *(const short8*)&As[lds_slot32(wm + i * 16 + r16, quad)];
      #pragma unroll
      for (int j = 0; j < NJ; ++j)
        bfr[j] = *(const short8*)&Bs[lds_slot32(wn + j * 16 + r16, quad)];
      #pragma unroll
      for (int i = 0; i < 4; ++i)
        #pragma unroll
        for (int j = 0; j < NJ; ++j)
          acc[i][j] = __builtin_amdgcn_mfma_f32_16x16x32_bf16(af[i], bfr[j], acc[i][j], 0, 0, 0);
      __syncthreads();
    }
  }

  #pragma unroll
  for (int j = 0; j < NJ; ++j) {
    int gn = bn * BN + wn + j * 16 + r16;
    float s = 0.f, s2 = 0.f;
    #pragma unroll
    for (int i = 0; i < 4; ++i) {
      #pragma unroll
      for (int r = 0; r < 4; ++r) {
        int gm = bm * 128 + wm + i * 16 + quad * 4 + r;
        float v = acc[i][j][r];
        if constexpr (EP == 0) {
          ((u8*)outb)[(size_t)gm * 256 + gn] = f2fp8(v);   // fp8 staging
          s += v; s2 += v * v;                             // stats stay exact
        } else if constexpr (EP == 1) {
          if constexpr (FP8 == 1) v *= (1.f / 64.f);       // undo weight x64
          outb[(size_t)gm * 256 + gn] = f2bf(fmaxf(v + bias[gn], 0.f));
        } else if constexpr (EP == 2) {
          outb[(size_t)gm * 256 + gn] = f2bf(fmaxf(v, 0.f));
        } else {
          if (gn < nv) {
            v += bias[gn];
            if (addpts) v += addpts[(size_t)gm * 18 + gn];
            if (ptsout) ptsout[(size_t)gm * 18 + gn] = v;
            int bb = gm >> 12, p = gm & 4095;
            outf[(size_t)((bb * 116 + cb + gn) << 12) + p] = v;
          }
        }
      }
    }
    if constexpr (EP == 0) {
      // reduce lanes differing in bits {0,1,2,4,5}; keep bit3 (8-ch group)
      s += __shfl_xor(s, 1);  s2 += __shfl_xor(s2, 1);
      s += __shfl_xor(s, 2);  s2 += __shfl_xor(s2, 2);
      s += __shfl_xor(s, 4);  s2 += __shfl_xor(s2, 4);
      s += __shfl_xor(s, 16); s2 += __shfl_xor(s2, 16);
      s += __shfl_xor(s, 32); s2 += __shfl_xor(s2, 32);
      if ((lane & 55) == 0) {
        float2* sp = st + ((bm >> 5) * 32) + (gn >> 3);
        atomicAdd(&sp->x, s);
        atomicAdd(&sp->y, s2);
      }
    }
  }
}

// ---------------------------------------------------------------------------
extern "C" void kernel_launch(void* const* d_in, const int* in_sizes, int n_in,
                              void* d_out, int out_size, void* d_ws, size_t ws_size,
                              hipStream_t stream) {
  (void)in_sizes; (void)n_in; (void)out_size;
  const float* features    = (const float*)d_in[0];
  const float* cls_w       = (const float*)d_in[1];
  const float* reg_w       = (const float*)d_in[2];
  const float* cls_gn_w    = (const float*)d_in[3];
  const float* cls_gn_b    = (const float*)d_in[4];
  const float* reg_gn_w    = (const float*)d_in[5];
  const float* reg_gn_b    = (const float*)d_in[6];
  const float* init_conv_w = (const float*)d_in[7];
  const float* init_conv_b = (const float*)d_in[8];
  const float* init_out_w  = (const float*)d_in[9];
  const float* init_out_b  = (const float*)d_in[10];
  const float* cls_dcn_w   = (const float*)d_in[11];
  const float* cls_out_w   = (const float*)d_in[12];
  const float* cls_out_b   = (const float*)d_in[13];
  const float* ref_dcn_w   = (const float*)d_in[14];
  const float* ref_out_w   = (const float*)d_in[15];
  const float* ref_out_b   = (const float*)d_in[16];
  float* out = (float*)d_out;

  char* ws = (char*)d_ws;
  size_t off = 0;
  auto alloc = [&](size_t bytes) {
    char* p = ws + off;
    off += (bytes + 255) & ~(size_t)255;
    return p;
  };
  u8*  wf8        = (u8*)alloc((size_t)9 * WSTEP);      // fp8 x64: towers 0..5, dcn 6..7, init 8
  u16* w1         = (u16*)alloc((size_t)3 * 32768 * 2);
  // 5 fp8 pads contiguous (halo zeroing indexes across them)
  u8* xpad8       = (u8*)alloc(PADELEM);
  u8* cpadA8      = (u8*)alloc(PADELEM);
  u8* cpadB8      = (u8*)alloc(PADELEM);
  u8* rpadA8      = (u8*)alloc(PADELEM);
  u8* rpadB8      = (u8*)alloc(PADELEM);
  float* ptsbuf   = (float*)alloc((size_t)MTOT * 18 * 4);
  float2* statsAll= (float2*)alloc(3 * 256 * sizeof(float2));
  u16* initf      = (u16*)alloc((size_t)MTOT * 256 * 2);
  u16* dcnout     = (u16*)alloc((size_t)2 * MTOT * 256 * 2);
  // union region: cstage [2][M][256] fp8 (8.4MB) then adcn [M][2304] fp8 (37.7MB)
  char* unionReg  = alloc((size_t)MTOT * 2304);
  u8* cstage8     = (u8*)unionReg;
  u8* adcn        = (u8*)unionReg;
  u8* adcn2       = (u8*)alloc((size_t)MTOT * 2304);    // only used if ws allows
  bool paired_dcn = (off <= ws_size);

  (void)hipMemsetAsync(statsAll, 0, 3 * 256 * sizeof(float2), stream);
  setup_all<<<5012, 256, 0, stream>>>(cls_w, reg_w, init_conv_w, cls_dcn_w, ref_dcn_w,
                                      init_out_w, cls_out_w, ref_out_w, features,
                                      w1, xpad8, wf8);

  // towers, paired (cls=pair0, reg=pair1): 3 layers of fp8 conv3x3 (+GN+relu).
  // fp8 W x64 absorbed by GN scale-invariance; staging is fp8 (stats exact).
  const u8* curC = xpad8; const u8* curR = xpad8;
  u8* nxtC = cpadA8; u8* altC = cpadB8;
  u8* nxtR = rpadA8; u8* altR = rpadB8;
  for (int i = 0; i < 3; ++i) {
    gemm_kernel<1, 0, 2304, 64, 64, 2, 1><<<1024, 256, 0, stream>>>(
        (const u16*)curC, (const u16*)curR,
        (const u16*)(wf8 + (size_t)i * WSTEP), (const u16*)(wf8 + (size_t)(3 + i) * WSTEP),
        nullptr, nullptr, (u16*)cstage8, (u16*)(cstage8 + (size_t)MTOT * 256),
        statsAll + i * 256, statsAll + i * 256 + 128,
        nullptr, nullptr, nullptr, nullptr, nullptr, 0, 0, 0, 0);
    gn_apply2<<<8192, 256, 0, stream>>>(cstage8, statsAll + i * 256,
        cls_gn_w + i * 256, cls_gn_b + i * 256, reg_gn_w + i * 256, reg_gn_b + i * 256,
        nxtC, nxtR);
    curC = nxtC; { u8* tmp = nxtC; nxtC = altC; altC = tmp; }
    curR = nxtR; { u8* tmp = nxtR; nxtR = altR; altR = tmp; }
  }
  const u8* cls_feat8 = curC;   // cpadA8
  const u8* reg_feat8 = curR;   // rpadA8

  // init branch: relu(conv3x3/64 + b) -> initf bf16. fp8 path (weights x64
  // in slot 8; EP1+FP8 rescales). BN=32 -> grid 1024 = 4 blk/CU (R5).
  gemm_kernel<1, 1, 2304, 32, 64, 1, 1><<<1024, 256, 0, stream>>>(
      (const u16*)reg_feat8, nullptr, (const u16*)(wf8 + (size_t)8 * WSTEP), nullptr,
      init_conv_b, nullptr, initf, nullptr, nullptr, nullptr,
      nullptr, nullptr, nullptr, nullptr, nullptr, 0, 0, 0, 0);
  // 1x1 -> pts_init (out ch 80..97 + ptsbuf). BN=64 -> 256 blocks
  gemm_kernel<0, 3, 256, 64, 32, 1><<<256, 256, 0, stream>>>(
      initf, nullptr, w1, nullptr, init_out_b, nullptr,
      nullptr, nullptr, nullptr, nullptr, out,
      nullptr, nullptr, ptsbuf, nullptr, 18, 0, 80, 0);

  // dcn conv: fp8 A (sampled fp8 feats) x fp8 W (x64); heads pre-scaled 1/64.
  if (paired_dcn) {
    dcn_sample2<<<2048, 256, 0, stream>>>(cls_feat8, reg_feat8, ptsbuf, adcn, adcn2);
    gemm_kernel<0, 2, 2304, 64, 64, 2, 1><<<1024, 256, 0, stream>>>(
        (const u16*)adcn, (const u16*)adcn2,
        (const u16*)(wf8 + (size_t)6 * WSTEP), (const u16*)(wf8 + (size_t)7 * WSTEP),
        nullptr, nullptr, dcnout, dcnout + (size_t)MTOT * 256, nullptr, nullptr,
        nullptr, nullptr, nullptr, nullptr, nullptr, 0, 0, 0, 0);
  } else {
    dcn_sample2<<<1024, 256, 0, stream>>>(cls_feat8, cls_feat8, ptsbuf, adcn, adcn);
    gemm_kernel<0, 2, 2304, 64, 64, 1, 1><<<512, 256, 0, stream>>>(
        (const u16*)adcn, nullptr, (const u16*)(wf8 + (size_t)6 * WSTEP), nullptr,
        nullptr, nullptr, dcnout, nullptr, nullptr, nullptr,
        nullptr, nullptr, nullptr, nullptr, nullptr, 0, 0, 0, 0);
    dcn_sample2<<<1024, 256, 0, stream>>>(reg_feat8, reg_feat8, ptsbuf, adcn, adcn);
    gemm_kernel<0, 2, 2304, 64, 64, 1, 1><<<512, 256, 0, stream>>>(
        (const u16*)adcn, nullptr, (const u16*)(wf8 + (size_t)7 * WSTEP), nullptr,
        nullptr, nullptr, dcnout + (size_t)MTOT * 256, nullptr, nullptr, nullptr,
        nullptr, nullptr, nullptr, nullptr, nullptr, 0, 0, 0, 0);
  }

  // final heads, paired: cls (80 ch at 0), refine (18 ch at 98, + pts_init)
  gemm_kernel<0, 3, 256, 64, 32, 2><<<512, 256, 0, stream>>>(
      dcnout, dcnout + (size_t)MTOT * 256, w1 + 32768, w1 + 2 * 32768,
      cls_out_b, ref_out_b, nullptr, nullptr, nullptr, nullptr, out,
      nullptr, ptsbuf, nullptr, nullptr, 80, 18, 0, 98);
}

// Round 10
// 352.749 us; speedup vs baseline: 1.5538x; 1.0637x over previous
//
#include <hip/hip_runtime.h>

typedef unsigned short u16;
typedef unsigned char u8;
typedef __attribute__((ext_vector_type(8))) short short8;
typedef __attribute__((ext_vector_type(4))) float floatx4;
typedef __attribute__((ext_vector_type(2))) float floatx2;
typedef __attribute__((ext_vector_type(2))) long longx2;

#define MTOT    16384          // 4 * 64 * 64
#define PADIMG  (66 * 66)      // padded image pixels per batch
#define PADELEM (4 * PADIMG * 256)      // elems per pad buffer (bytes when fp8)
#define WSTEP   (256 * 2304)

__device__ __forceinline__ float bf2f(u16 u) {
  union { unsigned int i; float f; } c; c.i = ((unsigned int)u) << 16; return c.f;
}
__device__ __forceinline__ u16 f2bf(float f) {
  union { float f; unsigned int i; } c; c.f = f;
  unsigned int r = c.i + 0x7FFFu + ((c.i >> 16) & 1u);
  return (u16)(r >> 16);
}
__device__ __forceinline__ u8 f2fp8(float f) {
  return (u8)(__builtin_amdgcn_cvt_pk_fp8_f32(f, f, 0, false) & 0xFF);
}

__device__ __forceinline__ void gl_lds16(const void* g, void* l) {
  __builtin_amdgcn_global_load_lds(
      (const __attribute__((address_space(1))) void*)g,
      (__attribute__((address_space(3))) void*)l, 16, 0, 0);
}

// BK=32 LDS slot (u16 units): 4 chunks/row, XOR with (row>>1)&3  [R4: 0 conflicts]
__device__ __forceinline__ int lds_slot32(int row, int q) {
  return row * 32 + ((q ^ ((row >> 1) & 3)) << 3);
}
// K-permutation within each 64-channel group: original w = ks*32 + q*8 + j
// stored at pos = q*16 + ks*8 + j (so chunk quad = both ks fragments of quad).
// Applied identically to ALL fp8 operands -> dot products invariant.
__device__ __forceinline__ int permw(int w) {
  return ((w >> 3) & 3) * 16 + ((w >> 5) & 1) * 8 + (w & 7);
}

// ---------------------------------------------------------------------------
// merged setup kernel (all regions disjoint):
//   blk < 2304          : pack ALL conv3x3 weights -> fp8 x64, K-permuted.
//                         slots: towers 0..5, dcn 6..7, init-conv 8.
//   blk < 2688 (384)    : pack 1x1 weights -> [128 zero-pad][256] x3
//                         (cls/ref heads pre-scaled by 1/64 for fp8 dcn)
//   blk < 3712 (1024)   : features NCHW fp32 -> fp8 K-permuted padded NHWC
//   blk < 5012 (1300)   : zero halo rings of the 5 fp8 padded buffers
__global__ void setup_all(const float* __restrict__ cls_w, const float* __restrict__ reg_w,
                          const float* __restrict__ initw, const float* __restrict__ clsd,
                          const float* __restrict__ refd,
                          const float* __restrict__ iw, const float* __restrict__ cw,
                          const float* __restrict__ rw,
                          const float* __restrict__ features,
                          u16* __restrict__ dst1,
                          u8* __restrict__ pads8, u8* __restrict__ wf8) {
  int blk = blockIdx.x;
  int t = threadIdx.x;
  if (blk < 2304) {
    int w = blk >> 8;                         // 0..8
    int o = blk & 255;
    const float* src = (w < 3) ? cls_w + (size_t)w * WSTEP
                     : (w < 6) ? reg_w + (size_t)(w - 3) * WSTEP
                     : (w == 6) ? initw : (w == 7) ? clsd : refd;
    __shared__ float wl[2304];
    const float* so = src + (size_t)o * 2304;   // [c][kk] contiguous
    #pragma unroll
    for (int p = 0; p < 9; ++p) wl[p * 256 + t] = so[p * 256 + t];
    __syncthreads();
    if (t < 128) {
      // fp8 e4m3, scaled x64 (std 0.01 is subnormal in e4m3), K-permuted.
      // x64 absorbed by: GN (towers), 1/64 heads (dcn), 1/64 EP1 (init).
      int slot = (w < 6) ? w : (w == 6) ? 8 : (w - 1);
      u8* dw8 = wf8 + (size_t)slot * WSTEP + (size_t)o * 2304;
      int c = 2 * t;                            // 0..254
      int pos = (c & 192) + permw(c & 63);      // pair stays contiguous (j even)
      #pragma unroll
      for (int p = 0; p < 9; ++p) {
        float f0 = wl[c * 9 + p] * 64.f;
        float f1 = wl[(c + 1) * 9 + p] * 64.f;
        int pk = __builtin_amdgcn_cvt_pk_fp8_f32(f0, f1, 0, false);
        *(u16*)(dw8 + p * 256 + pos) = (u16)(pk & 0xFFFF);
      }
    }
  } else if (blk < 2688) {
    int bb = blk - 2304;                      // 0..383
    int wsel = bb >> 7;
    const float* src = wsel == 0 ? iw : wsel == 1 ? cw : rw;
    int nvalid = wsel == 1 ? 80 : 18;
    float scale = wsel == 0 ? 1.f : (1.f / 64.f);   // undo dcn fp8 x64
    int idx = (bb & 127) * 256 + t;
    int o = idx >> 8, c = idx & 255;
    dst1[(size_t)wsel * 32768 + idx] = f2bf(o < nvalid ? src[o * 256 + c] * scale : 0.f);
  } else if (blk < 3712) {
    __shared__ float tile[64][65];
    int bb = blk - 2688;                      // 0..1023
    int c0 = (bb & 3) * 64;
    int y  = (bb >> 2) & 63;
    int b  = bb >> 8;
    #pragma unroll
    for (int i = 0; i < 16; ++i) {
      int lin = t + i * 256; int c = lin >> 6, x = lin & 63;
      tile[c][x] = features[((b * 256 + c0 + c) * 64 + y) * 64 + x];
    }
    __syncthreads();
    #pragma unroll
    for (int i = 0; i < 8; ++i) {             // 2 fp8 per thread per iter
      int lin = t + i * 256;                  // 0..2047
      int x = lin >> 5, c2 = lin & 31;
      int pk = __builtin_amdgcn_cvt_pk_fp8_f32(tile[2 * c2][x], tile[2 * c2 + 1][x], 0, false);
      *(u16*)(pads8 + (size_t)((b * 66 + y + 1) * 66 + (x + 1)) * 256
              + c0 + permw(2 * c2)) = (u16)pk;
    }
  } else {
    int idx = (blk - 3712) * 256 + t;         // 0..332799 = 5*4*260*64
    int c4 = (idx & 63) << 2;
    int r = idx >> 6;
    int pix = r % 260;
    int ib = r / 260;                         // buf*4 + batch, 0..19
    int y, x;
    if (pix < 66)       { y = 0;  x = pix; }
    else if (pix < 132) { y = 65; x = pix - 66; }
    else if (pix < 196) { y = pix - 132 + 1; x = 0; }
    else                { y = pix - 196 + 1; x = 65; }
    size_t o = (((size_t)ib * PADIMG) + y * 66 + x) * 256 + c4;
    *(unsigned int*)(pads8 + o) = 0u;
  }
}

// ---------------------------------------------------------------------------
// paired GroupNorm apply: fp8 staging [2][M][256] bytes (values x64 from fp8
// W; GN is scale-invariant, stats computed fp32-exact in the GEMM) ->
// normalize+affine+relu -> fp8 K-permuted padded NHWC per tower. grid 8192.
__global__ void __launch_bounds__(256)
gn_apply2(const u8* __restrict__ stage, const float2* __restrict__ st,
          const float* __restrict__ gwc, const float* __restrict__ gbc,
          const float* __restrict__ gwr, const float* __restrict__ gbr,
          u8* __restrict__ cdst8, u8* __restrict__ rdst8) {
  int tid = blockIdx.x * 256 + threadIdx.x;
  int tower = tid >> 20;
  int r = tid & 0xFFFFF;
  int m = r >> 6, c4 = (r & 63) << 2;
  unsigned int v = *(const unsigned int*)(stage + ((size_t)tower << 22)
                                          + (size_t)m * 256 + c4);
  floatx2 lo = __builtin_amdgcn_cvt_pk_f32_fp8(v, false);
  floatx2 hi = __builtin_amdgcn_cvt_pk_f32_fp8(v, true);
  int b = m >> 12, p = m & 4095, y = p >> 6, x = p & 63;
  float2 ss = st[tower * 128 + b * 32 + (c4 >> 3)];
  float mu = ss.x * (1.f / 32768.f);
  float var = ss.y * (1.f / 32768.f) - mu * mu;
  float rinv = rsqrtf(var + 1e-5f);
  const float* gw = tower ? gwr : gwc;
  const float* gb = tower ? gbr : gbc;
  float v0 = fmaxf((lo.x - mu) * rinv * gw[c4 + 0] + gb[c4 + 0], 0.f);
  float v1 = fmaxf((lo.y - mu) * rinv * gw[c4 + 1] + gb[c4 + 1], 0.f);
  float v2 = fmaxf((hi.x - mu) * rinv * gw[c4 + 2] + gb[c4 + 2], 0.f);
  float v3 = fmaxf((hi.y - mu) * rinv * gw[c4 + 3] + gb[c4 + 3], 0.f);
  size_t pixbase = (size_t)((b * 66 + y + 1) * 66 + (x + 1)) * 256;
  int pk = __builtin_amdgcn_cvt_pk_fp8_f32(v0, v1, 0, false);
  pk = __builtin_amdgcn_cvt_pk_fp8_f32(v2, v3, pk, true);
  *(int*)((tower ? rdst8 : cdst8) + pixbase + (c4 & 192) + permw(c4 & 63)) = pk;
}

// ---------------------------------------------------------------------------
// bilinear sample, both towers: fp8 K-permuted feats -> fp8 adcn (position-
// preserving; bilinear is channel-agnostic, dcn weights use the same perm).
// 16 lanes/pixel, 16 ch/lane. grid 2048: blk<1024 -> (featC,AC), else (featR,AR).
__global__ void __launch_bounds__(256)
dcn_sample2(const u8* __restrict__ featC, const u8* __restrict__ featR,
            const float* __restrict__ pts,
            u8* __restrict__ AC, u8* __restrict__ AR) {
  int blk = blockIdx.x;
  const u8* featpad = blk < 1024 ? featC : featR;
  u8* A = blk < 1024 ? AC : AR;
  int mblk = blk & 1023;
  int t = threadIdx.x;
  int m = mblk * 16 + (t >> 4);
  int l = t & 15;
  int b = m >> 12, p = m & 4095, y = p >> 6, x = p & 63;
  const float* pp = pts + (size_t)m * 18;
  const u8* fb = featpad + (size_t)b * PADIMG * 256 + l * 4;
  u8* am = A + (size_t)m * 2304 + l * 4;
  #pragma unroll
  for (int kk = 0; kk < 9; ++kk) {
    float py = (float)y + pp[2 * kk];
    float px = (float)x + pp[2 * kk + 1];
    float fy = floorf(py), fx = floorf(px);
    int y0 = (int)fy, x0 = (int)fx;
    float wy = py - fy, wx = px - fx;
    float w00 = (1.f - wy) * (1.f - wx), w01 = (1.f - wy) * wx;
    float w10 = wy * (1.f - wx), w11 = wy * wx;
    bool yok0 = (unsigned)y0 < 64u, yok1 = (unsigned)(y0 + 1) < 64u;
    bool xok0 = (unsigned)x0 < 64u, xok1 = (unsigned)(x0 + 1) < 64u;
    const u8* base = fb + ((y0 + 1) * 66 + (x0 + 1)) * 256;
    float r[16];
    #pragma unroll
    for (int i = 0; i < 16; ++i) r[i] = 0.f;
    #define ACCUM(OFF, W) { \
      _Pragma("unroll") \
      for (int c = 0; c < 4; ++c) { \
        unsigned int v = *(const unsigned int*)(base + (OFF) + c * 64); \
        floatx2 lo = __builtin_amdgcn_cvt_pk_f32_fp8(v, false); \
        floatx2 hi = __builtin_amdgcn_cvt_pk_f32_fp8(v, true); \
        r[c*4+0] += (W) * lo.x; r[c*4+1] += (W) * lo.y; \
        r[c*4+2] += (W) * hi.x; r[c*4+3] += (W) * hi.y; } }
    if (yok0 & xok0) ACCUM(0, w00)
    if (yok0 & xok1) ACCUM(256, w01)
    if (yok1 & xok0) ACCUM(66 * 256, w10)
    if (yok1 & xok1) ACCUM(67 * 256, w11)
    #undef ACCUM
    #pragma unroll
    for (int c = 0; c < 4; ++c) {
      int pk = __builtin_amdgcn_cvt_pk_fp8_f32(r[c*4+0], r[c*4+1], 0, false);
      pk = __builtin_amdgcn_cvt_pk_fp8_f32(r[c*4+2], r[c*4+3], pk, true);
      *(int*)(am + kk * 256 + c * 64) = pk;
    }
  }
}

// ---------------------------------------------------------------------------
// GEMM: C[M,N] = A[M,K] * W[N,K]^T.  128xBN tile, 4 waves.
// [R6-verified source, single-buffer K-loop; R8-verified fp8 K-perm layout.]
// Block decode: [NPAIR==2: pair=blk&1, blk>>=1]  bm=blk&127, bn=blk>>7.
// AMODE 0: flat A; AMODE 1: implicit conv3x3 (pads NHWC).
// FP8 1 (BK=128 BYTES/step): A/W fp8 e4m3, K-PERMUTED per 64-group (permw).
//   LDS = bf16-BK64 footprint (24KB) but HALF the barriers (18 steps vs 36).
//   Rows of 128 B = 8 x 16B chunks, XOR (row&7); read per (row, h, quad):
//   one b128 -> 2 lanes/chunk per 16-lane group (R8-equivalent, 0 conflicts).
//   MFMA order per step = exactly R9's two consecutive steps -> bit-identical.
// EP 0: fp8 staging + GN (s,s2) atomics (stats fp32-exact from acc);
// EP 1: +bias,relu -> bf16 (FP8: v/64 first, undoing weight x64);
// EP 2: relu -> bf16;
// EP 3: +bias (+addpts) (+ptsout) -> fp32 NCHW d_out slice at cb, gn < nv.
template <int AMODE, int EP, int KSZ, int BN, int BK, int NPAIR, int FP8 = 0>
__global__ void __launch_bounds__(256)
gemm_kernel(const u16* __restrict__ A0, const u16* __restrict__ A1,
            const u16* __restrict__ W0, const u16* __restrict__ W1,
            const float* __restrict__ bias0, const float* __restrict__ bias1,
            u16* __restrict__ outb0, u16* __restrict__ outb1,
            float2* __restrict__ st0, float2* __restrict__ st1,
            float* __restrict__ outf,
            const float* __restrict__ addpts0, const float* __restrict__ addpts1,
            float* __restrict__ ptsout0, float* __restrict__ ptsout1,
            int nv0, int nv1, int cb0, int cb1) {
  constexpr int NJ = BN / 32;                 // 16-col accum tiles per wave
  constexpr int ABYT = (FP8 == 1) ? 128 * 128 : 128 * BK * 2;
  constexpr int BBYT = (FP8 == 1) ? BN * 128 : BN * BK * 2;
  __shared__ __align__(16) u8 AsB[ABYT];
  __shared__ __align__(16) u8 BsB[BBYT];
  u16* As = (u16*)AsB;
  u16* Bs = (u16*)BsB;
  int t = threadIdx.x;
  int blk = blockIdx.x;
  int pair = 0;
  if constexpr (NPAIR == 2) { pair = blk & 1; blk >>= 1; }
  const u16* A        = pair ? A1 : A0;
  const u16* Wp       = pair ? W1 : W0;
  const float* bias   = pair ? bias1 : bias0;
  u16* outb           = pair ? outb1 : outb0;
  float2* st          = pair ? st1 : st0;
  const float* addpts = pair ? addpts1 : addpts0;
  float* ptsout       = pair ? ptsout1 : ptsout0;
  int nv = pair ? nv1 : nv0;
  int cb = pair ? cb1 : cb0;

  int bm = blk & 127, bn = blk >> 7;
  int lane = t & 63, wave = t >> 6;
  int wm = (wave & 1) << 6;
  int wn = (wave >> 1) * (BN / 2);
  int quad = lane >> 4, r16 = lane & 15;

  floatx4 acc[4][NJ];
  #pragma unroll
  for (int i = 0; i < 4; ++i)
    #pragma unroll
    for (int j = 0; j < NJ; ++j)
      acc[i][j] = (floatx4){0.f, 0.f, 0.f, 0.f};

  if constexpr (FP8 == 1) {
    // fp8 path, 128 bytes per K-step (18 steps at KSZ=2304 -> 36 barriers).
    u8* As8 = AsB;                        // [128 rows][128 B]
    u8* Bs8 = BsB;                        // [BN rows][128 B]
    const u8* A8 = (const u8*)A;
    const u8* W8 = (const u8*)Wp;
    int sub = t >> 3;                     // 0..31
    int cq = (t & 7) ^ (sub & 7);         // XOR-swizzled 16B chunk (8/row)
    int abase[4];
    #pragma unroll
    for (int k = 0; k < 4; ++k) {
      int m = bm * 128 + k * 32 + sub;
      if constexpr (AMODE == 1) {
        int b = m >> 12, p = m & 4095;
        abase[k] = ((b * 66 + (p >> 6)) * 66 + (p & 63)) * 256 + cq * 16;
      } else {
        abase[k] = m * KSZ + cq * 16;
      }
    }
    const u8* wg8 = W8 + (size_t)(bn * BN + sub) * KSZ + cq * 16;

    for (int s = 0; s < KSZ / 128; ++s) {
      int d;
      if constexpr (AMODE == 1) {
        int kk = s >> 1;                 // tap 0..8 (2 steps of 128 B each)
        int c0 = (s & 1) << 7;           // byte offset within 256-B pixel block
        int ky = kk / 3, kx = kk - ky * 3;
        d = ((ky * 66 + kx) << 8) + c0;
      } else {
        d = s * 128;
      }
      #pragma unroll
      for (int k = 0; k < 4; ++k)
        gl_lds16(A8 + abase[k] + d, As8 + k * 4096 + t * 16);
      #pragma unroll
      for (int k = 0; k < BN / 32; ++k)
        gl_lds16(wg8 + (size_t)(k * 32) * KSZ + s * 128, Bs8 + k * 4096 + t * 16);
      __syncthreads();
      long af8[2][2][4], bf8[2][2][NJ];   // [half][ks][·]
      #pragma unroll
      for (int h = 0; h < 2; ++h) {
        #pragma unroll
        for (int i = 0; i < 4; ++i) {
          int row = wm + i * 16 + r16;
          longx2 v = *(const longx2*)&As8[row * 128 + (((h * 4 + quad) ^ (row & 7)) << 4)];
          af8[h][0][i] = v.x; af8[h][1][i] = v.y;
        }
        #pragma unroll
        for (int j = 0; j < NJ; ++j) {
          int row = wn + j * 16 + r16;
          longx2 v = *(const longx2*)&Bs8[row * 128 + (((h * 4 + quad) ^ (row & 7)) << 4)];
          bf8[h][0][j] = v.x; bf8[h][1][j] = v.y;
        }
      }
      #pragma unroll
      for (int h = 0; h < 2; ++h)
        #pragma unroll
        for (int ks = 0; ks < 2; ++ks)
          #pragma unroll
          for (int i = 0; i < 4; ++i)
            #pragma unroll
            for (int j = 0; j < NJ; ++j)
              acc[i][j] = __builtin_amdgcn_mfma_f32_16x16x32_fp8_fp8(
                  af8[h][ks][i], bf8[h][ks][j], acc[i][j], 0, 0, 0);
      __syncthreads();
    }
  } else {
    // BK=32 bf16 path (R4-verified): 4 chunks/row (head GEMMs)
    int row = t >> 2;
    int chunkS = (t & 3) ^ ((t >> 3) & 3);
    int m0 = bm * 128 + row, m1 = m0 + 64;
    int abase0, abase1;
    if constexpr (AMODE == 1) {
      int b0 = m0 >> 12, p0 = m0 & 4095;
      int b1 = m1 >> 12, p1 = m1 & 4095;
      abase0 = ((b0 * 66 + (p0 >> 6)) * 66 + (p0 & 63)) * 256 + chunkS * 8;
      abase1 = ((b1 * 66 + (p1 >> 6)) * 66 + (p1 & 63)) * 256 + chunkS * 8;
    } else {
      abase0 = m0 * KSZ + chunkS * 8;
      abase1 = m1 * KSZ + chunkS * 8;
    }
    const u16* wg = Wp + (size_t)(bn * BN + row) * KSZ + chunkS * 8;

    for (int s = 0; s < KSZ / 32; ++s) {
      int d;
      if constexpr (AMODE == 1) {
        int kk = s >> 3;
        int c0 = (s & 7) << 5;
        int ky = kk / 3, kx = kk - ky * 3;
        d = ((ky * 66 + kx) << 8) + c0;
      } else {
        d = s * 32;
      }
      gl_lds16(A + abase0 + d, &As[t * 8]);
      gl_lds16(A + abase1 + d, &As[2048 + t * 8]);
      gl_lds16(wg + s * 32, &Bs[t * 8]);
      if constexpr (BN == 128)
        gl_lds16(wg + (size_t)64 * KSZ + s * 32, &Bs[2048 + t * 8]);
      __syncthreads();
      short8 af[4], bfr[NJ];
      #pragma unroll
      for (int i = 0; i < 4; ++i)
        af[i] = *(const short8*)&As[lds_slot32(wm + i * 16 + r16, quad)];
      #pragma unroll
      for (int j = 0; j < NJ; ++j)
        bfr[j] = *(const short8*)&Bs[lds_slot32(wn + j * 16 + r16, quad)];
      #pragma unroll
      for (int i = 0; i < 4; ++i)
        #pragma unroll
        for (int j = 0; j < NJ; ++j)
          acc[i][j] = __builtin_amdgcn_mfma_f32_16x16x32_bf16(af[i], bfr[j], acc[i][j], 0, 0, 0);
      __syncthreads();
    }
  }

  #pragma unroll
  for (int j = 0; j < NJ; ++j) {
    int gn = bn * BN + wn + j * 16 + r16;
    float s = 0.f, s2 = 0.f;
    #pragma unroll
    for (int i = 0; i < 4; ++i) {
      #pragma unroll
      for (int r = 0; r < 4; ++r) {
        int gm = bm * 128 + wm + i * 16 + quad * 4 + r;
        float v = acc[i][j][r];
        if constexpr (EP == 0) {
          ((u8*)outb)[(size_t)gm * 256 + gn] = f2fp8(v);   // fp8 staging
          s += v; s2 += v * v;                             // stats stay exact
        } else if constexpr (EP == 1) {
          if constexpr (FP8 == 1) v *= (1.f / 64.f);       // undo weight x64
          outb[(size_t)gm * 256 + gn] = f2bf(fmaxf(v + bias[gn], 0.f));
        } else if constexpr (EP == 2) {
          outb[(size_t)gm * 256 + gn] = f2bf(fmaxf(v, 0.f));
        } else {
          if (gn < nv) {
            v += bias[gn];
            if (addpts) v += addpts[(size_t)gm * 18 + gn];
            if (ptsout) ptsout[(size_t)gm * 18 + gn] = v;
            int bb = gm >> 12, p = gm & 4095;
            outf[(size_t)((bb * 116 + cb + gn) << 12) + p] = v;
          }
        }
      }
    }
    if constexpr (EP == 0) {
      // reduce lanes differing in bits {0,1,2,4,5}; keep bit3 (8-ch group)
      s += __shfl_xor(s, 1);  s2 += __shfl_xor(s2, 1);
      s += __shfl_xor(s, 2);  s2 += __shfl_xor(s2, 2);
      s += __shfl_xor(s, 4);  s2 += __shfl_xor(s2, 4);
      s += __shfl_xor(s, 16); s2 += __shfl_xor(s2, 16);
      s += __shfl_xor(s, 32); s2 += __shfl_xor(s2, 32);
      if ((lane & 55) == 0) {
        float2* sp = st + ((bm >> 5) * 32) + (gn >> 3);
        atomicAdd(&sp->x, s);
        atomicAdd(&sp->y, s2);
      }
    }
  }
}

// ---------------------------------------------------------------------------
extern "C" void kernel_launch(void* const* d_in, const int* in_sizes, int n_in,
                              void* d_out, int out_size, void* d_ws, size_t ws_size,
                              hipStream_t stream) {
  (void)in_sizes; (void)n_in; (void)out_size;
  const float* features    = (const float*)d_in[0];
  const float* cls_w       = (const float*)d_in[1];
  const float* reg_w       = (const float*)d_in[2];
  const float* cls_gn_w    = (const float*)d_in[3];
  const float* cls_gn_b    = (const float*)d_in[4];
  const float* reg_gn_w    = (const float*)d_in[5];
  const float* reg_gn_b    = (const float*)d_in[6];
  const float* init_conv_w = (const float*)d_in[7];
  const float* init_conv_b = (const float*)d_in[8];
  const float* init_out_w  = (const float*)d_in[9];
  const float* init_out_b  = (const float*)d_in[10];
  const float* cls_dcn_w   = (const float*)d_in[11];
  const float* cls_out_w   = (const float*)d_in[12];
  const float* cls_out_b   = (const float*)d_in[13];
  const float* ref_dcn_w   = (const float*)d_in[14];
  const float* ref_out_w   = (const float*)d_in[15];
  const float* ref_out_b   = (const float*)d_in[16];
  float* out = (float*)d_out;

  char* ws = (char*)d_ws;
  size_t off = 0;
  auto alloc = [&](size_t bytes) {
    char* p = ws + off;
    off += (bytes + 255) & ~(size_t)255;
    return p;
  };
  u8*  wf8        = (u8*)alloc((size_t)9 * WSTEP);      // fp8 x64: towers 0..5, dcn 6..7, init 8
  u16* w1         = (u16*)alloc((size_t)3 * 32768 * 2);
  // 5 fp8 pads contiguous (halo zeroing indexes across them)
  u8* xpad8       = (u8*)alloc(PADELEM);
  u8* cpadA8      = (u8*)alloc(PADELEM);
  u8* cpadB8      = (u8*)alloc(PADELEM);
  u8* rpadA8      = (u8*)alloc(PADELEM);
  u8* rpadB8      = (u8*)alloc(PADELEM);
  float* ptsbuf   = (float*)alloc((size_t)MTOT * 18 * 4);
  float2* statsAll= (float2*)alloc(3 * 256 * sizeof(float2));
  u16* initf      = (u16*)alloc((size_t)MTOT * 256 * 2);
  u16* dcnout     = (u16*)alloc((size_t)2 * MTOT * 256 * 2);
  // union region: cstage [2][M][256] fp8 (8.4MB) then adcn [M][2304] fp8 (37.7MB)
  char* unionReg  = alloc((size_t)MTOT * 2304);
  u8* cstage8     = (u8*)unionReg;
  u8* adcn        = (u8*)unionReg;
  u8* adcn2       = (u8*)alloc((size_t)MTOT * 2304);    // only used if ws allows
  bool paired_dcn = (off <= ws_size);

  (void)hipMemsetAsync(statsAll, 0, 3 * 256 * sizeof(float2), stream);
  setup_all<<<5012, 256, 0, stream>>>(cls_w, reg_w, init_conv_w, cls_dcn_w, ref_dcn_w,
                                      init_out_w, cls_out_w, ref_out_w, features,
                                      w1, xpad8, wf8);

  // towers, paired (cls=pair0, reg=pair1): 3 layers of fp8 conv3x3 (+GN+relu).
  // fp8 W x64 absorbed by GN scale-invariance; staging is fp8 (stats exact).
  const u8* curC = xpad8; const u8* curR = xpad8;
  u8* nxtC = cpadA8; u8* altC = cpadB8;
  u8* nxtR = rpadA8; u8* altR = rpadB8;
  for (int i = 0; i < 3; ++i) {
    gemm_kernel<1, 0, 2304, 64, 128, 2, 1><<<1024, 256, 0, stream>>>(
        (const u16*)curC, (const u16*)curR,
        (const u16*)(wf8 + (size_t)i * WSTEP), (const u16*)(wf8 + (size_t)(3 + i) * WSTEP),
        nullptr, nullptr, (u16*)cstage8, (u16*)(cstage8 + (size_t)MTOT * 256),
        statsAll + i * 256, statsAll + i * 256 + 128,
        nullptr, nullptr, nullptr, nullptr, nullptr, 0, 0, 0, 0);
    gn_apply2<<<8192, 256, 0, stream>>>(cstage8, statsAll + i * 256,
        cls_gn_w + i * 256, cls_gn_b + i * 256, reg_gn_w + i * 256, reg_gn_b + i * 256,
        nxtC, nxtR);
    curC = nxtC; { u8* tmp = nxtC; nxtC = altC; altC = tmp; }
    curR = nxtR; { u8* tmp = nxtR; nxtR = altR; altR = tmp; }
  }
  const u8* cls_feat8 = curC;   // cpadA8
  const u8* reg_feat8 = curR;   // rpadA8

  // init branch: relu(conv3x3/64 + b) -> initf bf16. fp8 path (weights x64
  // in slot 8; EP1+FP8 rescales). BN=32 -> grid 1024 = 4 blk/CU (R5).
  gemm_kernel<1, 1, 2304, 32, 128, 1, 1><<<1024, 256, 0, stream>>>(
      (const u16*)reg_feat8, nullptr, (const u16*)(wf8 + (size_t)8 * WSTEP), nullptr,
      init_conv_b, nullptr, initf, nullptr, nullptr, nullptr,
      nullptr, nullptr, nullptr, nullptr, nullptr, 0, 0, 0, 0);
  // 1x1 -> pts_init (out ch 80..97 + ptsbuf). BN=64 -> 256 blocks (bf16)
  gemm_kernel<0, 3, 256, 64, 32, 1><<<256, 256, 0, stream>>>(
      initf, nullptr, w1, nullptr, init_out_b, nullptr,
      nullptr, nullptr, nullptr, nullptr, out,
      nullptr, nullptr, ptsbuf, nullptr, 18, 0, 80, 0);

  // dcn conv: fp8 A (sampled fp8 feats) x fp8 W (x64); heads pre-scaled 1/64.
  if (paired_dcn) {
    dcn_sample2<<<2048, 256, 0, stream>>>(cls_feat8, reg_feat8, ptsbuf, adcn, adcn2);
    gemm_kernel<0, 2, 2304, 64, 128, 2, 1><<<1024, 256, 0, stream>>>(
        (const u16*)adcn, (const u16*)adcn2,
        (const u16*)(wf8 + (size_t)6 * WSTEP), (const u16*)(wf8 + (size_t)7 * WSTEP),
        nullptr, nullptr, dcnout, dcnout + (size_t)MTOT * 256, nullptr, nullptr,
        nullptr, nullptr, nullptr, nullptr, nullptr, 0, 0, 0, 0);
  } else {
    dcn_sample2<<<1024, 256, 0, stream>>>(cls_feat8, cls_feat8, ptsbuf, adcn, adcn);
    gemm_kernel<0, 2, 2304, 64, 128, 1, 1><<<512, 256, 0, stream>>>(
        (const u16*)adcn, nullptr, (const u16*)(wf8 + (size_t)6 * WSTEP), nullptr,
        nullptr, nullptr, dcnout, nullptr, nullptr, nullptr,
        nullptr, nullptr, nullptr, nullptr, nullptr, 0, 0, 0, 0);
    dcn_sample2<<<1024, 256, 0, stream>>>(reg_feat8, reg_feat8, ptsbuf, adcn, adcn);
    gemm_kernel<0, 2, 2304, 64, 128, 1, 1><<<512, 256, 0, stream>>>(
        (const u16*)adcn, nullptr, (const u16*)(wf8 + (size_t)7 * WSTEP), nullptr,
        nullptr, nullptr, dcnout + (size_t)MTOT * 256, nullptr, nullptr, nullptr,
        nullptr, nullptr, nullptr, nullptr, nullptr, 0, 0, 0, 0);
  }

  // final heads, paired: cls (80 ch at 0), refine (18 ch at 98, + pts_init)
  gemm_kernel<0, 3, 256, 64, 32, 2><<<512, 256, 0, stream>>>(
      dcnout, dcnout + (size_t)MTOT * 256, w1 + 32768, w1 + 2 * 32768,
      cls_out_b, ref_out_b, nullptr, nullptr, nullptr, nullptr, out,
      nullptr, ptsbuf, nullptr, nullptr, 80, 18, 0, 98);
}

// Round 12
// 335.210 us; speedup vs baseline: 1.6351x; 1.0523x over previous
//
#include <hip/hip_runtime.h>

typedef unsigned short u16;
typedef unsigned char u8;
typedef __attribute__((ext_vector_type(8))) short short8;
typedef __attribute__((ext_vector_type(4))) float floatx4;
typedef __attribute__((ext_vector_type(2))) float floatx2;
typedef __attribute__((ext_vector_type(2))) long longx2;
typedef __attribute__((ext_vector_type(4))) unsigned int uintx4;

#define MTOT    16384          // 4 * 64 * 64
#define PADIMG  (66 * 66)      // padded image pixels per batch
#define PADELEM (4 * PADIMG * 256)      // elems per pad buffer (bytes when fp8)
#define WSTEP   (256 * 2304)

__device__ __forceinline__ float bf2f(u16 u) {
  union { unsigned int i; float f; } c; c.i = ((unsigned int)u) << 16; return c.f;
}
__device__ __forceinline__ u16 f2bf(float f) {
  union { float f; unsigned int i; } c; c.f = f;
  unsigned int r = c.i + 0x7FFFu + ((c.i >> 16) & 1u);
  return (u16)(r >> 16);
}
__device__ __forceinline__ u8 f2fp8(float f) {
  return (u8)(__builtin_amdgcn_cvt_pk_fp8_f32(f, f, 0, false) & 0xFF);
}

__device__ __forceinline__ void gl_lds16(const void* g, void* l) {
  __builtin_amdgcn_global_load_lds(
      (const __attribute__((address_space(1))) void*)g,
      (__attribute__((address_space(3))) void*)l, 16, 0, 0);
}

// BK=32 LDS slot (u16 units): 4 chunks/row, XOR with (row>>1)&3  [R4: 0 conflicts]
__device__ __forceinline__ int lds_slot32(int row, int q) {
  return row * 32 + ((q ^ ((row >> 1) & 3)) << 3);
}
// K-permutation within each 64-channel group: original w = ks*32 + q*8 + j
// stored at pos = q*16 + ks*8 + j (so chunk quad = both ks fragments of quad).
// Applied identically to ALL fp8 operands -> dot products invariant.
__device__ __forceinline__ int permw(int w) {
  return ((w >> 3) & 3) * 16 + ((w >> 5) & 1) * 8 + (w & 7);
}
// channel c (0..255) -> K-permuted byte position
__device__ __forceinline__ int permc(int c) {
  return (c & 192) + permw(c & 63);
}

// ---------------------------------------------------------------------------
// merged setup kernel (all regions disjoint):
//   blk < 2304          : pack ALL conv3x3 weights -> fp8 x64, K-permuted.
//                         slots: towers 0..5, dcn 6..7, init-conv 8.
//   blk < 2688 (384)    : pack 1x1 weights -> fp8 x64 K-permuted,
//                         [128 rows zero-padded][256] x3 (init, cls, ref)
//   blk < 3712 (1024)   : features NCHW fp32 -> fp8 K-permuted padded NHWC
//   blk < 5012 (1300)   : zero halo rings of the 5 fp8 padded buffers
__global__ void setup_all(const float* __restrict__ cls_w, const float* __restrict__ reg_w,
                          const float* __restrict__ initw, const float* __restrict__ clsd,
                          const float* __restrict__ refd,
                          const float* __restrict__ iw, const float* __restrict__ cw,
                          const float* __restrict__ rw,
                          const float* __restrict__ features,
                          u8* __restrict__ wf1,
                          u8* __restrict__ pads8, u8* __restrict__ wf8) {
  int blk = blockIdx.x;
  int t = threadIdx.x;
  if (blk < 2304) {
    int w = blk >> 8;                         // 0..8
    int o = blk & 255;
    const float* src = (w < 3) ? cls_w + (size_t)w * WSTEP
                     : (w < 6) ? reg_w + (size_t)(w - 3) * WSTEP
                     : (w == 6) ? initw : (w == 7) ? clsd : refd;
    __shared__ float wl[2304];
    const float* so = src + (size_t)o * 2304;   // [c][kk] contiguous
    #pragma unroll
    for (int p = 0; p < 9; ++p) wl[p * 256 + t] = so[p * 256 + t];
    __syncthreads();
    if (t < 128) {
      // fp8 e4m3, scaled x64 (std 0.01 is subnormal in e4m3), K-permuted.
      // x64 absorbed by: GN (towers), EP3 rescale (dcn->heads), EP1 (init).
      int slot = (w < 6) ? w : (w == 6) ? 8 : (w - 1);
      u8* dw8 = wf8 + (size_t)slot * WSTEP + (size_t)o * 2304;
      int c = 2 * t;                            // 0..254
      int pos = permc(c);                       // pair stays contiguous (j even)
      #pragma unroll
      for (int p = 0; p < 9; ++p) {
        float f0 = wl[c * 9 + p] * 64.f;
        float f1 = wl[(c + 1) * 9 + p] * 64.f;
        int pk = __builtin_amdgcn_cvt_pk_fp8_f32(f0, f1, 0, false);
        *(u16*)(dw8 + p * 256 + pos) = (u16)(pk & 0xFFFF);
      }
    }
  } else if (blk < 2688) {
    int bb = blk - 2304;                      // 0..383
    int wsel = bb >> 7;
    const float* src = wsel == 0 ? iw : wsel == 1 ? cw : rw;
    int nvalid = wsel == 1 ? 80 : 18;
    int o = bb & 127;
    float v = (o < nvalid) ? src[o * 256 + t] * 64.f : 0.f;
    wf1[(size_t)wsel * 32768 + o * 256 + permc(t)] = f2fp8(v);
  } else if (blk < 3712) {
    __shared__ float tile[64][65];
    int bb = blk - 2688;                      // 0..1023
    int c0 = (bb & 3) * 64;
    int y  = (bb >> 2) & 63;
    int b  = bb >> 8;
    #pragma unroll
    for (int i = 0; i < 16; ++i) {
      int lin = t + i * 256; int c = lin >> 6, x = lin & 63;
      tile[c][x] = features[((b * 256 + c0 + c) * 64 + y) * 64 + x];
    }
    __syncthreads();
    #pragma unroll
    for (int i = 0; i < 8; ++i) {             // 2 fp8 per thread per iter
      int lin = t + i * 256;                  // 0..2047
      int x = lin >> 5, c2 = lin & 31;
      int pk = __builtin_amdgcn_cvt_pk_fp8_f32(tile[2 * c2][x], tile[2 * c2 + 1][x], 0, false);
      *(u16*)(pads8 + (size_t)((b * 66 + y + 1) * 66 + (x + 1)) * 256
              + c0 + permw(2 * c2)) = (u16)pk;
    }
  } else {
    int idx = (blk - 3712) * 256 + t;         // 0..332799 = 5*4*260*64
    int c4 = (idx & 63) << 2;
    int r = idx >> 6;
    int pix = r % 260;
    int ib = r / 260;                         // buf*4 + batch, 0..19
    int y, x;
    if (pix < 66)       { y = 0;  x = pix; }
    else if (pix < 132) { y = 65; x = pix - 66; }
    else if (pix < 196) { y = pix - 132 + 1; x = 0; }
    else                { y = pix - 196 + 1; x = 65; }
    size_t o = (((size_t)ib * PADIMG) + y * 66 + x) * 256 + c4;
    *(unsigned int*)(pads8 + o) = 0u;
  }
}

// ---------------------------------------------------------------------------
// paired GroupNorm apply: fp8 staging [2][M][256] bytes (values x64 from fp8
// W; GN is scale-invariant, stats computed fp32-exact in the GEMM) ->
// normalize+affine+relu -> fp8 K-permuted padded NHWC per tower. grid 8192.
__global__ void __launch_bounds__(256)
gn_apply2(const u8* __restrict__ stage, const float2* __restrict__ st,
          const float* __restrict__ gwc, const float* __restrict__ gbc,
          const float* __restrict__ gwr, const float* __restrict__ gbr,
          u8* __restrict__ cdst8, u8* __restrict__ rdst8) {
  int tid = blockIdx.x * 256 + threadIdx.x;
  int tower = tid >> 20;
  int r = tid & 0xFFFFF;
  int m = r >> 6, c4 = (r & 63) << 2;
  unsigned int v = *(const unsigned int*)(stage + ((size_t)tower << 22)
                                          + (size_t)m * 256 + c4);
  floatx2 lo = __builtin_amdgcn_cvt_pk_f32_fp8(v, false);
  floatx2 hi = __builtin_amdgcn_cvt_pk_f32_fp8(v, true);
  int b = m >> 12, p = m & 4095, y = p >> 6, x = p & 63;
  float2 ss = st[tower * 128 + b * 32 + (c4 >> 3)];
  float mu = ss.x * (1.f / 32768.f);
  float var = ss.y * (1.f / 32768.f) - mu * mu;
  float rinv = rsqrtf(var + 1e-5f);
  const float* gw = tower ? gwr : gwc;
  const float* gb = tower ? gbr : gbc;
  float v0 = fmaxf((lo.x - mu) * rinv * gw[c4 + 0] + gb[c4 + 0], 0.f);
  float v1 = fmaxf((lo.y - mu) * rinv * gw[c4 + 1] + gb[c4 + 1], 0.f);
  float v2 = fmaxf((hi.x - mu) * rinv * gw[c4 + 2] + gb[c4 + 2], 0.f);
  float v3 = fmaxf((hi.y - mu) * rinv * gw[c4 + 3] + gb[c4 + 3], 0.f);
  size_t pixbase = (size_t)((b * 66 + y + 1) * 66 + (x + 1)) * 256;
  int pk = __builtin_amdgcn_cvt_pk_fp8_f32(v0, v1, 0, false);
  pk = __builtin_amdgcn_cvt_pk_fp8_f32(v2, v3, pk, true);
  *(int*)((tower ? rdst8 : cdst8) + pixbase + permc(c4)) = pk;
}

// ---------------------------------------------------------------------------
// bilinear sample, both towers: fp8 K-permuted feats -> fp8 adcn (position-
// preserving; bilinear is channel-agnostic, dcn weights use the same perm).
// 16 lanes/pixel, 16 CONTIGUOUS bytes/lane: one dwordx4 per corner (R11:
// was 4 scalar dwords) + one 16B store per tap. grid 2048.
__global__ void __launch_bounds__(256)
dcn_sample2(const u8* __restrict__ featC, const u8* __restrict__ featR,
            const float* __restrict__ pts,
            u8* __restrict__ AC, u8* __restrict__ AR) {
  int blk = blockIdx.x;
  const u8* featpad = blk < 1024 ? featC : featR;
  u8* A = blk < 1024 ? AC : AR;
  int mblk = blk & 1023;
  int t = threadIdx.x;
  int m = mblk * 16 + (t >> 4);
  int l = t & 15;                       // channels [l*16, l*16+16) (permuted space)
  int b = m >> 12, p = m & 4095, y = p >> 6, x = p & 63;
  const float* pp = pts + (size_t)m * 18;
  const u8* fb = featpad + (size_t)b * PADIMG * 256 + l * 16;
  u8* am = A + (size_t)m * 2304 + l * 16;
  #pragma unroll
  for (int kk = 0; kk < 9; ++kk) {
    float py = (float)y + pp[2 * kk];
    float px = (float)x + pp[2 * kk + 1];
    float fy = floorf(py), fx = floorf(px);
    int y0 = (int)fy, x0 = (int)fx;
    float wy = py - fy, wx = px - fx;
    float w00 = (1.f - wy) * (1.f - wx), w01 = (1.f - wy) * wx;
    float w10 = wy * (1.f - wx), w11 = wy * wx;
    bool yok0 = (unsigned)y0 < 64u, yok1 = (unsigned)(y0 + 1) < 64u;
    bool xok0 = (unsigned)x0 < 64u, xok1 = (unsigned)(x0 + 1) < 64u;
    const u8* base = fb + ((y0 + 1) * 66 + (x0 + 1)) * 256;
    float r[16];
    #pragma unroll
    for (int i = 0; i < 16; ++i) r[i] = 0.f;
    #define ACCUM(OFF, W) { \
      uintx4 v = *(const uintx4*)(base + (OFF)); \
      _Pragma("unroll") \
      for (int e = 0; e < 4; ++e) { \
        floatx2 lo = __builtin_amdgcn_cvt_pk_f32_fp8(v[e], false); \
        floatx2 hi = __builtin_amdgcn_cvt_pk_f32_fp8(v[e], true); \
        r[e*4+0] += (W) * lo.x; r[e*4+1] += (W) * lo.y; \
        r[e*4+2] += (W) * hi.x; r[e*4+3] += (W) * hi.y; } }
    if (yok0 & xok0) ACCUM(0, w00)
    if (yok0 & xok1) ACCUM(256, w01)
    if (yok1 & xok0) ACCUM(66 * 256, w10)
    if (yok1 & xok1) ACCUM(67 * 256, w11)
    #undef ACCUM
    uintx4 o4;
    #pragma unroll
    for (int e = 0; e < 4; ++e) {
      int pk = __builtin_amdgcn_cvt_pk_fp8_f32(r[e*4+0], r[e*4+1], 0, false);
      pk = __builtin_amdgcn_cvt_pk_fp8_f32(r[e*4+2], r[e*4+3], pk, true);
      o4[e] = (unsigned int)pk;
    }
    *(uintx4*)(am + kk * 256) = o4;
  }
}

// ---------------------------------------------------------------------------
// GEMM: C[M,N] = A[M,K] * W[N,K]^T.  128xBN tile, 4 waves.
// [R6-verified source; R8-verified fp8 K-perm layout; R10-verified BK=128.]
// Block decode: [NPAIR==2: pair=blk&1, blk>>=1]  bm=blk&127, bn=blk>>7.
// AMODE 0: flat A; AMODE 1: implicit conv3x3 (pads NHWC).
// FP8 1 (128 BYTES/step): A/W fp8 e4m3, K-PERMUTED per 64-group (permw).
//   Rows of 128 B = 8 x 16B chunks, XOR (row&7); one b128 per (row,h,quad)
//   -> 0 bank conflicts (R8/R10). mfma_f32_16x16x32_fp8_fp8.
// RSH: EP1/EP3 multiply v by 1/(1<<RSH) (undoes fp8 weight x64 chains).
// EP 0: fp8 staging + GN (s,s2) atomics (stats fp32-exact from acc);
// EP 1: relu(v*2^-RSH + bias) -> fp8 K-permuted (init conv -> initf);
// EP 2: relu(v) -> fp8 K-permuted (dcn -> dcnout, keeps x64);
// EP 3: v*2^-RSH + bias (+addpts)(+ptsout) -> fp32 NCHW d_out at cb, gn<nv.
template <int AMODE, int EP, int KSZ, int BN, int BK, int NPAIR, int FP8 = 0, int RSH = 0>
__global__ void __launch_bounds__(256)
gemm_kernel(const u16* __restrict__ A0, const u16* __restrict__ A1,
            const u16* __restrict__ W0, const u16* __restrict__ W1,
            const float* __restrict__ bias0, const float* __restrict__ bias1,
            u16* __restrict__ outb0, u16* __restrict__ outb1,
            float2* __restrict__ st0, float2* __restrict__ st1,
            float* __restrict__ outf,
            const float* __restrict__ addpts0, const float* __restrict__ addpts1,
            float* __restrict__ ptsout0, float* __restrict__ ptsout1,
            int nv0, int nv1, int cb0, int cb1) {
  constexpr int NJ = BN / 32;                 // 16-col accum tiles per wave
  constexpr int ABYT = (FP8 == 1) ? 128 * 128 : 128 * BK * 2;
  constexpr int BBYT = (FP8 == 1) ? BN * 128 : BN * BK * 2;
  __shared__ __align__(16) u8 AsB[ABYT];
  __shared__ __align__(16) u8 BsB[BBYT];
  u16* As = (u16*)AsB;
  u16* Bs = (u16*)BsB;
  int t = threadIdx.x;
  int blk = blockIdx.x;
  int pair = 0;
  if constexpr (NPAIR == 2) { pair = blk & 1; blk >>= 1; }
  const u16* A        = pair ? A1 : A0;
  const u16* Wp       = pair ? W1 : W0;
  const float* bias   = pair ? bias1 : bias0;
  u16* outb           = pair ? outb1 : outb0;
  float2* st          = pair ? st1 : st0;
  const float* addpts = pair ? addpts1 : addpts0;
  float* ptsout       = pair ? ptsout1 : ptsout0;
  int nv = pair ? nv1 : nv0;
  int cb = pair ? cb1 : cb0;

  int bm = blk & 127, bn = blk >> 7;
  int lane = t & 63, wave = t >> 6;
  int wm = (wave & 1) << 6;
  int wn = (wave >> 1) * (BN / 2);
  int quad = lane >> 4, r16 = lane & 15;

  floatx4 acc[4][NJ];
  #pragma unroll
  for (int i = 0; i < 4; ++i)
    #pragma unroll
    for (int j = 0; j < NJ; ++j)
      acc[i][j] = (floatx4){0.f, 0.f, 0.f, 0.f};

  if constexpr (FP8 == 1) {
    // fp8 path, 128 bytes per K-step.
    u8* As8 = AsB;                        // [128 rows][128 B]
    u8* Bs8 = BsB;                        // [BN rows][128 B]
    const u8* A8 = (const u8*)A;
    const u8* W8 = (const u8*)Wp;
    int sub = t >> 3;                     // 0..31
    int cq = (t & 7) ^ (sub & 7);         // XOR-swizzled 16B chunk (8/row)
    int abase[4];
    #pragma unroll
    for (int k = 0; k < 4; ++k) {
      int m = bm * 128 + k * 32 + sub;
      if constexpr (AMODE == 1) {
        int b = m >> 12, p = m & 4095;
        abase[k] = ((b * 66 + (p >> 6)) * 66 + (p & 63)) * 256 + cq * 16;
      } else {
        abase[k] = m * KSZ + cq * 16;
      }
    }
    const u8* wg8 = W8 + (size_t)(bn * BN + sub) * KSZ + cq * 16;

    for (int s = 0; s < KSZ / 128; ++s) {
      int d;
      if constexpr (AMODE == 1) {
        int kk = s >> 1;                 // tap 0..8 (2 steps of 128 B each)
        int c0 = (s & 1) << 7;           // byte offset within 256-B pixel block
        int ky = kk / 3, kx = kk - ky * 3;
        d = ((ky * 66 + kx) << 8) + c0;
      } else {
        d = s * 128;
      }
      #pragma unroll
      for (int k = 0; k < 4; ++k)
        gl_lds16(A8 + abase[k] + d, As8 + k * 4096 + t * 16);
      #pragma unroll
      for (int k = 0; k < BN / 32; ++k)
        gl_lds16(wg8 + (size_t)(k * 32) * KSZ + s * 128, Bs8 + k * 4096 + t * 16);
      __syncthreads();
      long af8[2][2][4], bf8[2][2][NJ];   // [half][ks][·]
      #pragma unroll
      for (int h = 0; h < 2; ++h) {
        #pragma unroll
        for (int i = 0; i < 4; ++i) {
          int row = wm + i * 16 + r16;
          longx2 v = *(const longx2*)&As8[row * 128 + (((h * 4 + quad) ^ (row & 7)) << 4)];
          af8[h][0][i] = v.x; af8[h][1][i] = v.y;
        }
        #pragma unroll
        for (int j = 0; j < NJ; ++j) {
          int row = wn + j * 16 + r16;
          longx2 v = *(const longx2*)&Bs8[row * 128 + (((h * 4 + quad) ^ (row & 7)) << 4)];
          bf8[h][0][j] = v.x; bf8[h][1][j] = v.y;
        }
      }
      #pragma unroll
      for (int h = 0; h < 2; ++h)
        #pragma unroll
        for (int ks = 0; ks < 2; ++ks)
          #pragma unroll
          for (int i = 0; i < 4; ++i)
            #pragma unroll
            for (int j = 0; j < NJ; ++j)
              acc[i][j] = __builtin_amdgcn_mfma_f32_16x16x32_fp8_fp8(
                  af8[h][ks][i], bf8[h][ks][j], acc[i][j], 0, 0, 0);
      __syncthreads();
    }
  } else {
    // BK=32 bf16 path (R4-verified): 4 chunks/row (unused when all-fp8)
    int row = t >> 2;
    int chunkS = (t & 3) ^ ((t >> 3) & 3);
    int m0 = bm * 128 + row, m1 = m0 + 64;
    int abase0, abase1;
    if constexpr (AMODE == 1) {
      int b0 = m0 >> 12, p0 = m0 & 4095;
      int b1 = m1 >> 12, p1 = m1 & 4095;
      abase0 = ((b0 * 66 + (p0 >> 6)) * 66 + (p0 & 63)) * 256 + chunkS * 8;
      abase1 = ((b1 * 66 + (p1 >> 6)) * 66 + (p1 & 63)) * 256 + chunkS * 8;
    } else {
      abase0 = m0 * KSZ + chunkS * 8;
      abase1 = m1 * KSZ + chunkS * 8;
    }
    const u16* wg = Wp + (size_t)(bn * BN + row) * KSZ + chunkS * 8;

    for (int s = 0; s < KSZ / 32; ++s) {
      int d;
      if constexpr (AMODE == 1) {
        int kk = s >> 3;
        int c0 = (s & 7) << 5;
        int ky = kk / 3, kx = kk - ky * 3;
        d = ((ky * 66 + kx) << 8) + c0;
      } else {
        d = s * 32;
      }
      gl_lds16(A + abase0 + d, &As[t * 8]);
      gl_lds16(A + abase1 + d, &As[2048 + t * 8]);
      gl_lds16(wg + s * 32, &Bs[t * 8]);
      if constexpr (BN == 128)
        gl_lds16(wg + (size_t)64 * KSZ + s * 32, &Bs[2048 + t * 8]);
      __syncthreads();
      short8 af[4], bfr[NJ];
      #pragma unroll
      for (int i = 0; i < 4; ++i)
        af[i] = *(const short8*)&As[lds_slot32(wm + i * 16 + r16, quad)];
      #pragma unroll
      for (int j = 0; j < NJ; ++j)
        bfr[j] = *(const short8*)&Bs[lds_slot32(wn + j * 16 + r16, quad)];
      #pragma unroll
      for (int i = 0; i < 4; ++i)
        #pragma unroll
        for (int j = 0; j < NJ; ++j)
          acc[i][j] = __builtin_amdgcn_mfma_f32_16x16x32_bf16(af[i], bfr[j], acc[i][j], 0, 0, 0);
      __syncthreads();
    }
  }

  constexpr float RS = 1.f / (float)(1 << RSH);
  #pragma unroll
  for (int j = 0; j < NJ; ++j) {
    int gn = bn * BN + wn + j * 16 + r16;
    float s = 0.f, s2 = 0.f;
    #pragma unroll
    for (int i = 0; i < 4; ++i) {
      #pragma unroll
      for (int r = 0; r < 4; ++r) {
        int gm = bm * 128 + wm + i * 16 + quad * 4 + r;
        float v = acc[i][j][r];
        if constexpr (EP == 0) {
          ((u8*)outb)[(size_t)gm * 256 + gn] = f2fp8(v);   // fp8 staging
          s += v; s2 += v * v;                             // stats stay exact
        } else if constexpr (EP == 1) {
          if constexpr (RSH > 0) v *= RS;
          float o = fmaxf(v + bias[gn], 0.f);
          if constexpr (FP8 == 1)
            ((u8*)outb)[(size_t)gm * 256 + permc(gn)] = f2fp8(o);
          else
            outb[(size_t)gm * 256 + gn] = f2bf(o);
        } else if constexpr (EP == 2) {
          float o = fmaxf(v, 0.f);
          if constexpr (FP8 == 1)
            ((u8*)outb)[(size_t)gm * 256 + permc(gn)] = f2fp8(o);
          else
            outb[(size_t)gm * 256 + gn] = f2bf(o);
        } else {
          if (gn < nv) {
            if constexpr (RSH > 0) v *= RS;
            v += bias[gn];
            if (addpts) v += addpts[(size_t)gm * 18 + gn];
            if (ptsout) ptsout[(size_t)gm * 18 + gn] = v;
            int bb = gm >> 12, p = gm & 4095;
            outf[(size_t)((bb * 116 + cb + gn) << 12) + p] = v;
          }
        }
      }
    }
    if constexpr (EP == 0) {
      // reduce lanes differing in bits {0,1,2,4,5}; keep bit3 (8-ch group)
      s += __shfl_xor(s, 1);  s2 += __shfl_xor(s2, 1);
      s += __shfl_xor(s, 2);  s2 += __shfl_xor(s2, 2);
      s += __shfl_xor(s, 4);  s2 += __shfl_xor(s2, 4);
      s += __shfl_xor(s, 16); s2 += __shfl_xor(s2, 16);
      s += __shfl_xor(s, 32); s2 += __shfl_xor(s2, 32);
      if ((lane & 55) == 0) {
        float2* sp = st + ((bm >> 5) * 32) + (gn >> 3);
        atomicAdd(&sp->x, s);
        atomicAdd(&sp->y, s2);
      }
    }
  }
}

// ---------------------------------------------------------------------------
extern "C" void kernel_launch(void* const* d_in, const int* in_sizes, int n_in,
                              void* d_out, int out_size, void* d_ws, size_t ws_size,
                              hipStream_t stream) {
  (void)in_sizes; (void)n_in; (void)out_size;
  const float* features    = (const float*)d_in[0];
  const float* cls_w       = (const float*)d_in[1];
  const float* reg_w       = (const float*)d_in[2];
  const float* cls_gn_w    = (const float*)d_in[3];
  const float* cls_gn_b    = (const float*)d_in[4];
  const float* reg_gn_w    = (const float*)d_in[5];
  const float* reg_gn_b    = (const float*)d_in[6];
  const float* init_conv_w = (const float*)d_in[7];
  const float* init_conv_b = (const float*)d_in[8];
  const float* init_out_w  = (const float*)d_in[9];
  const float* init_out_b  = (const float*)d_in[10];
  const float* cls_dcn_w   = (const float*)d_in[11];
  const float* cls_out_w   = (const float*)d_in[12];
  const float* cls_out_b   = (const float*)d_in[13];
  const float* ref_dcn_w   = (const float*)d_in[14];
  const float* ref_out_w   = (const float*)d_in[15];
  const float* ref_out_b   = (const float*)d_in[16];
  float* out = (float*)d_out;

  char* ws = (char*)d_ws;
  size_t off = 0;
  auto alloc = [&](size_t bytes) {
    char* p = ws + off;
    off += (bytes + 255) & ~(size_t)255;
    return p;
  };
  u8*  wf8        = (u8*)alloc((size_t)9 * WSTEP);      // fp8 x64: towers 0..5, dcn 6..7, init 8
  u8*  wf1        = (u8*)alloc((size_t)3 * 32768);      // fp8 x64 K-perm 1x1: init, cls, ref
  // 5 fp8 pads contiguous (halo zeroing indexes across them)
  u8* xpad8       = (u8*)alloc(PADELEM);
  u8* cpadA8      = (u8*)alloc(PADELEM);
  u8* cpadB8      = (u8*)alloc(PADELEM);
  u8* rpadA8      = (u8*)alloc(PADELEM);
  u8* rpadB8      = (u8*)alloc(PADELEM);
  float* ptsbuf   = (float*)alloc((size_t)MTOT * 18 * 4);
  float2* statsAll= (float2*)alloc(3 * 256 * sizeof(float2));
  u8* initf       = (u8*)alloc((size_t)MTOT * 256);     // fp8 K-permuted
  u8* dcnout      = (u8*)alloc((size_t)2 * MTOT * 256); // fp8 K-permuted, x64
  // union region: cstage [2][M][256] fp8 (8.4MB) then adcn [M][2304] fp8 (37.7MB)
  char* unionReg  = alloc((size_t)MTOT * 2304);
  u8* cstage8     = (u8*)unionReg;
  u8* adcn        = (u8*)unionReg;
  u8* adcn2       = (u8*)alloc((size_t)MTOT * 2304);    // only used if ws allows
  bool paired_dcn = (off <= ws_size);

  (void)hipMemsetAsync(statsAll, 0, 3 * 256 * sizeof(float2), stream);
  setup_all<<<5012, 256, 0, stream>>>(cls_w, reg_w, init_conv_w, cls_dcn_w, ref_dcn_w,
                                      init_out_w, cls_out_w, ref_out_w, features,
                                      wf1, xpad8, wf8);

  // towers, paired (cls=pair0, reg=pair1): 3 layers of fp8 conv3x3 (+GN+relu).
  // fp8 W x64 absorbed by GN scale-invariance; staging is fp8 (stats exact).
  const u8* curC = xpad8; const u8* curR = xpad8;
  u8* nxtC = cpadA8; u8* altC = cpadB8;
  u8* nxtR = rpadA8; u8* altR = rpadB8;
  for (int i = 0; i < 3; ++i) {
    gemm_kernel<1, 0, 2304, 64, 128, 2, 1><<<1024, 256, 0, stream>>>(
        (const u16*)curC, (const u16*)curR,
        (const u16*)(wf8 + (size_t)i * WSTEP), (const u16*)(wf8 + (size_t)(3 + i) * WSTEP),
        nullptr, nullptr, (u16*)cstage8, (u16*)(cstage8 + (size_t)MTOT * 256),
        statsAll + i * 256, statsAll + i * 256 + 128,
        nullptr, nullptr, nullptr, nullptr, nullptr, 0, 0, 0, 0);
    gn_apply2<<<8192, 256, 0, stream>>>(cstage8, statsAll + i * 256,
        cls_gn_w + i * 256, cls_gn_b + i * 256, reg_gn_w + i * 256, reg_gn_b + i * 256,
        nxtC, nxtR);
    curC = nxtC; { u8* tmp = nxtC; nxtC = altC; altC = tmp; }
    curR = nxtR; { u8* tmp = nxtR; nxtR = altR; altR = tmp; }
  }
  const u8* cls_feat8 = curC;   // cpadA8
  const u8* reg_feat8 = curR;   // rpadA8

  // init branch: relu(conv3x3 * 2^-6 + b) -> initf fp8 (K-permuted).
  // BN=32 -> grid 1024 = 4 blk/CU (R5).
  gemm_kernel<1, 1, 2304, 32, 128, 1, 1, 6><<<1024, 256, 0, stream>>>(
      (const u16*)reg_feat8, nullptr, (const u16*)(wf8 + (size_t)8 * WSTEP), nullptr,
      init_conv_b, nullptr, (u16*)initf, nullptr, nullptr, nullptr,
      nullptr, nullptr, nullptr, nullptr, nullptr, 0, 0, 0, 0);
  // 1x1 -> pts_init (out ch 80..97 + ptsbuf). fp8, K=256 -> 2 K-steps.
  // A true-scale, W x64 -> RSH=6. BN=32, 128 cols covered -> grid 512.
  gemm_kernel<0, 3, 256, 32, 128, 1, 1, 6><<<512, 256, 0, stream>>>(
      (const u16*)initf, nullptr, (const u16*)wf1, nullptr,
      init_out_b, nullptr, nullptr, nullptr, nullptr, nullptr, out,
      nullptr, nullptr, ptsbuf, nullptr, 18, 0, 80, 0);

  // dcn conv: fp8 A (sampled fp8 feats) x fp8 W (x64) -> dcnout fp8 (x64 kept).
  if (paired_dcn) {
    dcn_sample2<<<2048, 256, 0, stream>>>(cls_feat8, reg_feat8, ptsbuf, adcn, adcn2);
    gemm_kernel<0, 2, 2304, 64, 128, 2, 1><<<1024, 256, 0, stream>>>(
        (const u16*)adcn, (const u16*)adcn2,
        (const u16*)(wf8 + (size_t)6 * WSTEP), (const u16*)(wf8 + (size_t)7 * WSTEP),
        nullptr, nullptr, (u16*)dcnout, (u16*)(dcnout + (size_t)MTOT * 256), nullptr, nullptr,
        nullptr, nullptr, nullptr, nullptr, nullptr, 0, 0, 0, 0);
  } else {
    dcn_sample2<<<1024, 256, 0, stream>>>(cls_feat8, cls_feat8, ptsbuf, adcn, adcn);
    gemm_kernel<0, 2, 2304, 64, 128, 1, 1><<<512, 256, 0, stream>>>(
        (const u16*)adcn, nullptr, (const u16*)(wf8 + (size_t)6 * WSTEP), nullptr,
        nullptr, nullptr, (u16*)dcnout, nullptr, nullptr, nullptr,
        nullptr, nullptr, nullptr, nullptr, nullptr, 0, 0, 0, 0);
    dcn_sample2<<<1024, 256, 0, stream>>>(reg_feat8, reg_feat8, ptsbuf, adcn, adcn);
    gemm_kernel<0, 2, 2304, 64, 128, 1, 1><<<512, 256, 0, stream>>>(
        (const u16*)adcn, nullptr, (const u16*)(wf8 + (size_t)7 * WSTEP), nullptr,
        nullptr, nullptr, (u16*)(dcnout + (size_t)MTOT * 256), nullptr, nullptr, nullptr,
        nullptr, nullptr, nullptr, nullptr, nullptr, 0, 0, 0, 0);
  }

  // final heads, paired: cls (80 ch at 0), refine (18 ch at 98, + pts_init).
  // fp8: A x64, W x64 -> RSH=12. BN=32, 128 cols, 2 K-steps -> grid 1024.
  gemm_kernel<0, 3, 256, 32, 128, 2, 1, 12><<<1024, 256, 0, stream>>>(
      (const u16*)dcnout, (const u16*)(dcnout + (size_t)MTOT * 256),
      (const u16*)(wf1 + 32768), (const u16*)(wf1 + 65536),
      cls_out_b, ref_out_b, nullptr, nullptr, nullptr, nullptr, out,
      nullptr, ptsbuf, nullptr, nullptr, 80, 18, 0, 98);
}